// Round 4
// baseline (2111.218 us; speedup 1.0000x reference)
//
#include <hip/hip_runtime.h>
#include <cstdint>
#include <cstddef>

typedef __attribute__((ext_vector_type(8))) short bf16x8;
typedef __attribute__((ext_vector_type(4))) float f32x4;

static inline int ceil_div(int a, int b){ return (a + b - 1) / b; }

struct HL { short h, l; };
__device__ inline HL split2(float a){
  unsigned u = __float_as_uint(a);
  unsigned hb = (u + 0x8000u) & 0xFFFF0000u;   // round-to-nearest-ish bf16 high part
  float r = a - __uint_as_float(hb);           // exact (nearby subtraction)
  HL o;
  o.h = (short)(hb >> 16);
  o.l = (short)((__float_as_uint(r) + 0x8000u) >> 16);
  return o;
}

__device__ inline unsigned short f2b(float f){            // fp32 -> bf16 (RNE)
  unsigned u = __float_as_uint(f);
  unsigned r = u + 0x7FFFu + ((u >> 16) & 1u);
  return (unsigned short)(r >> 16);
}
__device__ inline float b2f(unsigned short s){
  return __uint_as_float((unsigned)s << 16);
}

// ---------------- dtype detection (int64 vs int32 edge_index) ----------------
__global__ __launch_bounds__(256) void k_detect(const int* __restrict__ ei32, int E, int* __restrict__ flag){
  int t = blockIdx.x * 256 + threadIdx.x;
  if (t < 4096) {
    long long idx = 2LL * t + 1;
    if (idx < 2LL * E && ei32[idx] != 0) atomicOr(flag, 1);
  }
}

// ---------------- CSR build ----------------
__global__ __launch_bounds__(256) void k_count(const void* __restrict__ ei, int E,
                                               const int* __restrict__ flag, int* __restrict__ cnt){
  int e = blockIdx.x * 256 + threadIdx.x;
  if (e >= E) return;
  int dst = (*flag) ? ((const int*)ei)[(size_t)E + e]
                    : (int)((const long long*)ei)[(size_t)E + e];
  atomicAdd(&cnt[dst], 1);
}

__global__ __launch_bounds__(1024) void k_scan(const int* __restrict__ cnt, int* __restrict__ row_ptr, int N){
  __shared__ int sums[1024];
  int t = threadIdx.x;
  int chunk = (N + 1023) >> 10;
  int lo = t * chunk, hi = min(lo + chunk, N);
  int s = 0;
  for (int i = lo; i < hi; ++i) s += cnt[i];
  sums[t] = s; __syncthreads();
  for (int off = 1; off < 1024; off <<= 1){
    int v = 0;
    if (t >= off) v = sums[t - off];
    __syncthreads();
    if (t >= off) sums[t] += v;
    __syncthreads();
  }
  int pre = (t == 0) ? 0 : sums[t - 1];
  for (int i = lo; i < hi; ++i){ row_ptr[i] = pre; pre += cnt[i]; }
  if (t == 1023) row_ptr[N] = sums[1023];
}

__global__ __launch_bounds__(256) void k_copy(const int* __restrict__ a, int* __restrict__ b, int n){
  int i = blockIdx.x * 256 + threadIdx.x;
  if (i < n) b[i] = a[i];
}

__global__ __launch_bounds__(256) void k_fill(const void* __restrict__ ei, const float* __restrict__ ew, int E,
                                              const int* __restrict__ flag, int* __restrict__ cursor,
                                              int* __restrict__ csr_src, float* __restrict__ csr_ew){
  int e = blockIdx.x * 256 + threadIdx.x;
  if (e >= E) return;
  int src, dst;
  if (*flag){ src = ((const int*)ei)[e]; dst = ((const int*)ei)[(size_t)E + e]; }
  else      { src = (int)((const long long*)ei)[e]; dst = (int)((const long long*)ei)[(size_t)E + e]; }
  int pos = atomicAdd(&cursor[dst], 1);
  csr_src[pos] = src;
  csr_ew[pos] = ew[e];
}

__global__ __launch_bounds__(256) void k_degrees(const int* __restrict__ row_ptr, const float* __restrict__ csr_ew,
                                                 float* __restrict__ dis1, float* __restrict__ dis2,
                                                 float* __restrict__ invw, int N){
  int r = blockIdx.x * 256 + threadIdx.x;
  if (r >= N) return;
  int e0 = row_ptr[r], e1 = row_ptr[r + 1];
  float s = 0.f;
  for (int e = e0; e < e1; ++e) s += csr_ew[e];
  dis1[r] = rsqrtf(s + 1.0f);
  dis2[r] = (s > 0.0f) ? rsqrtf(s) : 0.0f;
  invw[r] = 1.0f / (float)(e1 - e0 + 1);
}

// ---------------- weight prep: W [K][N] fp32 -> Wh/Wl [N][K] bf16 split ----------------
__global__ __launch_bounds__(256) void k_prep_w(const float* __restrict__ W, short* __restrict__ Wh,
                                                short* __restrict__ Wl, int K, int N){
  int idx = blockIdx.x * 256 + threadIdx.x;
  if (idx >= K * N) return;
  int n = idx / K, k = idx - n * K;
  HL s = split2(W[(size_t)k * N + n]);
  Wh[idx] = s.h; Wl[idx] = s.l;
}

// ---------------- MFMA GEMM: C = A@B + dscale*D, A fp32 [M][K] (split on the fly),
// ---------------- B pre-split/transposed [N][K] bf16.  128x128 tile, BK=32, 4 waves.
// ---------------- Optional bf16 shadow of C.
__global__ __launch_bounds__(256) void k_gemm_mfma(
    const float* __restrict__ A,
    const short* __restrict__ Bh, const short* __restrict__ Bl,
    const float* __restrict__ D, float dscale,
    float* __restrict__ C, unsigned short* __restrict__ Cb,
    int M, int Ncols, int K)
{
  __shared__ short Ah[128][40];
  __shared__ short Al[128][40];
  __shared__ short Bhs[128][40];
  __shared__ short Bls[128][40];
  int m0 = blockIdx.x * 128, n0 = blockIdx.y * 128;
  int t = threadIdx.x;
  int lane = t & 63, wid = t >> 6;
  int wr = wid >> 1, wc = wid & 1;
  int fr = lane & 15, fq = lane >> 4;
  int srow = t >> 1, skh = (t & 1) << 4;

  f32x4 acc[4][4];
#pragma unroll
  for (int i = 0; i < 4; ++i)
#pragma unroll
    for (int j = 0; j < 4; ++j) acc[i][j] = (f32x4){0.f, 0.f, 0.f, 0.f};

  bool aval = (m0 + srow) < M;
  const float* Aptr = A + (size_t)(m0 + srow) * K + skh;
  const short* Bhp = Bh + (size_t)(n0 + srow) * K + skh;
  const short* Blp = Bl + (size_t)(n0 + srow) * K + skh;

  for (int k0 = 0; k0 < K; k0 += 32){
    __syncthreads();
    float av[16];
    if (aval){
      const float4* ap = (const float4*)(Aptr + k0);
      float4 a0 = ap[0], a1 = ap[1], a2 = ap[2], a3 = ap[3];
      av[0]=a0.x; av[1]=a0.y; av[2]=a0.z; av[3]=a0.w;
      av[4]=a1.x; av[5]=a1.y; av[6]=a1.z; av[7]=a1.w;
      av[8]=a2.x; av[9]=a2.y; av[10]=a2.z; av[11]=a2.w;
      av[12]=a3.x; av[13]=a3.y; av[14]=a3.z; av[15]=a3.w;
    } else {
#pragma unroll
      for (int i = 0; i < 16; ++i) av[i] = 0.f;
    }
    bf16x8 h0, h1, l0, l1;
#pragma unroll
    for (int i = 0; i < 8; ++i){
      HL s = split2(av[i]);
      h0[i] = s.h; l0[i] = s.l;
    }
#pragma unroll
    for (int i = 0; i < 8; ++i){
      HL s = split2(av[8 + i]);
      h1[i] = s.h; l1[i] = s.l;
    }
    *(bf16x8*)&Ah[srow][skh]     = h0;
    *(bf16x8*)&Ah[srow][skh + 8] = h1;
    *(bf16x8*)&Al[srow][skh]     = l0;
    *(bf16x8*)&Al[srow][skh + 8] = l1;
    {
      const bf16x8* bp = (const bf16x8*)(Bhp + k0);
      *(bf16x8*)&Bhs[srow][skh]     = bp[0];
      *(bf16x8*)&Bhs[srow][skh + 8] = bp[1];
      const bf16x8* cp = (const bf16x8*)(Blp + k0);
      *(bf16x8*)&Bls[srow][skh]     = cp[0];
      *(bf16x8*)&Bls[srow][skh + 8] = cp[1];
    }
    __syncthreads();
    bf16x8 afh[4], afl[4], bfh[4], bfl[4];
#pragma unroll
    for (int m = 0; m < 4; ++m){
      int r = wr * 64 + m * 16 + fr;
      afh[m] = *(const bf16x8*)&Ah[r][fq * 8];
      afl[m] = *(const bf16x8*)&Al[r][fq * 8];
    }
#pragma unroll
    for (int n = 0; n < 4; ++n){
      int r = wc * 64 + n * 16 + fr;
      bfh[n] = *(const bf16x8*)&Bhs[r][fq * 8];
      bfl[n] = *(const bf16x8*)&Bls[r][fq * 8];
    }
#pragma unroll
    for (int m = 0; m < 4; ++m)
#pragma unroll
      for (int n = 0; n < 4; ++n){
        acc[m][n] = __builtin_amdgcn_mfma_f32_16x16x32_bf16(afh[m], bfh[n], acc[m][n], 0, 0, 0);
        acc[m][n] = __builtin_amdgcn_mfma_f32_16x16x32_bf16(afl[m], bfh[n], acc[m][n], 0, 0, 0);
        acc[m][n] = __builtin_amdgcn_mfma_f32_16x16x32_bf16(afh[m], bfl[n], acc[m][n], 0, 0, 0);
      }
  }
  // ---- epilogue: C = acc + dscale*D (+ bf16 shadow) ----
#pragma unroll
  for (int m = 0; m < 4; ++m){
#pragma unroll
    for (int n = 0; n < 4; ++n){
      int col = n0 + wc * 64 + n * 16 + fr;
#pragma unroll
      for (int r = 0; r < 4; ++r){
        int row = m0 + wr * 64 + m * 16 + fq * 4 + r;
        if (row < M){
          size_t off = (size_t)row * Ncols + col;
          float v = acc[m][n][r];
          if (dscale != 0.f) v = fmaf(dscale, D[off], v);
          C[off] = v;
          if (Cb) Cb[off] = f2b(v);
        }
      }
    }
  }
}

// ---------------- GCN aggregation (width 256), wave per row, bf16 gather, fused bias+relu ----------------
__global__ __launch_bounds__(256) void k_gcn_agg(const float* __restrict__ h0,
    const unsigned short* __restrict__ h0b,
    const int* __restrict__ csr_src, const float* __restrict__ csr_ew,
    const int* __restrict__ row_ptr, const float* __restrict__ dis1,
    const float* __restrict__ b1, float* __restrict__ h1, int N){
  int lane = threadIdx.x & 63;
  int r = blockIdx.x * 4 + (threadIdx.x >> 6);
  if (r >= N) return;
  float dr = dis1[r];
  float4 self = ((const float4*)(h0 + (size_t)r * 256))[lane];
  float4 inner = make_float4(self.x * dr, self.y * dr, self.z * dr, self.w * dr);
  int e0 = row_ptr[r], e1 = row_ptr[r + 1];
  for (int e = e0; e < e1; ++e){
    int s = csr_src[e];
    float w = csr_ew[e] * dis1[s];
    ushort4 v = ((const ushort4*)(h0b + (size_t)s * 256))[lane];
    inner.x = fmaf(w, b2f(v.x), inner.x);
    inner.y = fmaf(w, b2f(v.y), inner.y);
    inner.z = fmaf(w, b2f(v.z), inner.z);
    inner.w = fmaf(w, b2f(v.w), inner.w);
  }
  float4 bb = ((const float4*)b1)[lane];
  float4 o;
  o.x = fmaxf(fmaf(inner.x, dr, bb.x), 0.f);
  o.y = fmaxf(fmaf(inner.y, dr, bb.y), 0.f);
  o.z = fmaxf(fmaf(inner.z, dr, bb.z), 0.f);
  o.w = fmaxf(fmaf(inner.w, dr, bb.w), 0.f);
  ((float4*)(h1 + (size_t)r * 256))[lane] = o;
}

// ---------------- Cheb spmm (width 128): dst += coef*dis2[r]*sum(ew*dis2[s]*bf16src[s]);
// ---------------- optionally writes bf16 shadow of dst for the next spmm's gather.
__global__ __launch_bounds__(256) void k_cheb_spmm(const unsigned short* __restrict__ srcb,
    float* __restrict__ dst, unsigned short* __restrict__ dstb,
    const int* __restrict__ csr_src, const float* __restrict__ csr_ew,
    const int* __restrict__ row_ptr, const float* __restrict__ dis2, float coef, int N){
  int lane = threadIdx.x & 63;
  int r = blockIdx.x * 4 + (threadIdx.x >> 6);
  if (r >= N) return;
  float2 inner = make_float2(0.f, 0.f);
  int e0 = row_ptr[r], e1 = row_ptr[r + 1];
  for (int e = e0; e < e1; ++e){
    int s = csr_src[e];
    float w = csr_ew[e] * dis2[s];
    unsigned int v = ((const unsigned int*)(srcb + (size_t)s * 128))[lane];
    inner.x = fmaf(w, __uint_as_float(v << 16), inner.x);
    inner.y = fmaf(w, __uint_as_float(v & 0xFFFF0000u), inner.y);
  }
  float c = coef * dis2[r];
  float2* op = (float2*)(dst + (size_t)r * 128) + lane;
  float2 cur = *op;
  cur.x = fmaf(c, inner.x, cur.x);
  cur.y = fmaf(c, inner.y, cur.y);
  *op = cur;
  if (dstb){
    unsigned int pk = (unsigned int)f2b(cur.x) | ((unsigned int)f2b(cur.y) << 16);
    ((unsigned int*)(dstb + (size_t)r * 128))[lane] = pk;
  }
}

// ---------------- features epilogue ----------------
__global__ __launch_bounds__(256) void k_feat(const float* __restrict__ P, const float* __restrict__ bc,
    const float* __restrict__ W_out, const float* __restrict__ W_root,
    float* __restrict__ feat, float* __restrict__ p, float* __restrict__ wr, int N){
  int lane = threadIdx.x & 63;
  int r = blockIdx.x * 4 + (threadIdx.x >> 6);
  if (r >= N) return;
  float2 v = ((const float2*)(P + (size_t)r * 128))[lane];
  float2 bb = ((const float2*)bc)[lane];
  v.x = fmaxf(v.x + bb.x, 0.f);
  v.y = fmaxf(v.y + bb.y, 0.f);
  ((float2*)(feat + (size_t)r * 128))[lane] = v;
  float2 wo = ((const float2*)W_out)[lane];
  float2 wrt = ((const float2*)W_root)[lane];
  float pp = v.x * wo.x + v.y * wo.y;
  float rr = v.x * wrt.x + v.y * wrt.y;
#pragma unroll
  for (int off = 32; off; off >>= 1){
    pp += __shfl_xor(pp, off);
    rr += __shfl_xor(rr, off);
  }
  if (lane == 0){ p[r] = pp; wr[r] = rr; }
}

// ---------------- ClusterGCN output ----------------
__global__ __launch_bounds__(256) void k_out(const float* __restrict__ p, const float* __restrict__ wr,
    const float* __restrict__ invw, const int* __restrict__ csr_src, const int* __restrict__ row_ptr,
    const float* __restrict__ b3, float* __restrict__ out, int N){
  int r = blockIdx.x * 256 + threadIdx.x;
  if (r >= N) return;
  float s = p[r];
  int e0 = row_ptr[r], e1 = row_ptr[r + 1];
  for (int e = e0; e < e1; ++e) s += p[csr_src[e]];
  out[r] = invw[r] * s + wr[r] + b3[0];
}

extern "C" void kernel_launch(void* const* d_in, const int* in_sizes, int n_in,
                              void* d_out, int out_size, void* d_ws, size_t ws_size,
                              hipStream_t stream){
  const float* x      = (const float*)d_in[0];
  const void*  ei     = d_in[1];
  const float* ew     = (const float*)d_in[2];
  const float* W1     = (const float*)d_in[3];
  const float* b1     = (const float*)d_in[4];
  const float* Wc     = (const float*)d_in[5];
  const float* bc     = (const float*)d_in[6];
  const float* W_out  = (const float*)d_in[7];
  const float* W_root = (const float*)d_in[8];
  const float* b3     = (const float*)d_in[9];
  const int N = in_sizes[0] / 512;
  const int E = in_sizes[2];

  char* w = (char*)d_ws;
  auto alloc = [&](size_t bytes)->void*{ void* r = (void*)w; w += (bytes + 255) & ~(size_t)255; return r; };
  float* h0      = (float*)alloc((size_t)N * 256 * 4);   // x@W1; later P0/P1 (fp32)
  float* h1      = (float*)alloc((size_t)N * 256 * 4);   // GCN output (Cheb GEMM A)
  float* P2      = (float*)alloc((size_t)N * 128 * 4);
  unsigned short* h0b = (unsigned short*)alloc((size_t)N * 256 * 2); // bf16 shadow of h0; later Pb0|Pb1
  unsigned short* Pb2 = (unsigned short*)alloc((size_t)N * 128 * 2);
  float* csr_ew  = (float*)alloc((size_t)E * 4);
  int*   csr_src = (int*)  alloc((size_t)E * 4);
  int*   row_ptr = (int*)  alloc((size_t)(N + 1) * 4);
  int*   cursor  = (int*)  alloc((size_t)N * 4);
  int*   cnt     = (int*)  alloc((size_t)N * 4);
  float* dis1    = (float*)alloc((size_t)N * 4);
  float* dis2    = (float*)alloc((size_t)N * 4);
  float* invw    = (float*)alloc((size_t)N * 4);
  float* pbuf    = (float*)alloc((size_t)N * 4);
  float* wrbuf   = (float*)alloc((size_t)N * 4);
  short* W1t_h   = (short*)alloc((size_t)512 * 256 * 2);
  short* W1t_l   = (short*)alloc((size_t)512 * 256 * 2);
  short* Wct_h   = (short*)alloc((size_t)6 * 256 * 128 * 2);
  short* Wct_l   = (short*)alloc((size_t)6 * 256 * 128 * 2);
  int*   flag    = (int*)  alloc(256);
  float* P0 = h0;
  float* P1 = h0 + (size_t)N * 128;
  unsigned short* Pb0 = h0b;
  unsigned short* Pb1 = h0b + (size_t)N * 128;

  hipMemsetAsync(cnt, 0, (size_t)N * 4, stream);
  hipMemsetAsync(flag, 0, 4, stream);

  k_detect<<<16, 256, 0, stream>>>((const int*)ei, E, flag);
  k_count<<<ceil_div(E, 256), 256, 0, stream>>>(ei, E, flag, cnt);
  k_scan<<<1, 1024, 0, stream>>>(cnt, row_ptr, N);
  k_copy<<<ceil_div(N, 256), 256, 0, stream>>>(row_ptr, cursor, N);
  k_fill<<<ceil_div(E, 256), 256, 0, stream>>>(ei, ew, E, flag, cursor, csr_src, csr_ew);
  k_degrees<<<ceil_div(N, 256), 256, 0, stream>>>(row_ptr, csr_ew, dis1, dis2, invw, N);

  // weight prep (transpose + bf16 split)
  k_prep_w<<<ceil_div(512 * 256, 256), 256, 0, stream>>>(W1, W1t_h, W1t_l, 512, 256);
  for (int k = 0; k < 6; ++k)
    k_prep_w<<<ceil_div(256 * 128, 256), 256, 0, stream>>>(Wc + (size_t)k * 256 * 128,
        Wct_h + (size_t)k * 256 * 128, Wct_l + (size_t)k * 256 * 128, 256, 128);

  // ---- GCNConv: h0 = x@W1 (fp32 + bf16 shadow); h1 = relu(agg + b1) ----
  k_gemm_mfma<<<dim3(ceil_div(N, 128), 2), 256, 0, stream>>>(x, W1t_h, W1t_l, nullptr, 0.f, h0, h0b, N, 256, 512);
  k_gcn_agg<<<ceil_div(N, 4), 256, 0, stream>>>(h0, h0b, csr_src, csr_ew, row_ptr, dis1, b1, h1, N);

  // ---- ChebConv via Clenshaw (width 128), bf16 gathers ----
  auto gemm2 = [&](int k, float* dst, unsigned short* dstb, const float* Dm, float ds){
    k_gemm_mfma<<<dim3(ceil_div(N, 128), 1), 256, 0, stream>>>(h1,
        Wct_h + (size_t)k * 256 * 128, Wct_l + (size_t)k * 256 * 128, Dm, ds, dst, dstb, N, 128, 256);
  };
  auto spmm = [&](float* dst, unsigned short* dstb, const unsigned short* srcb, float coef){
    k_cheb_spmm<<<ceil_div(N, 4), 256, 0, stream>>>(srcb, dst, dstb, csr_src, csr_ew, row_ptr, dis2, coef, N);
  };
  gemm2(5, P0, Pb0, nullptr, 0.f);                                  // b5 = C5
  gemm2(4, P1, nullptr, nullptr, 0.f); spmm(P1, Pb1, Pb0, -2.f);    // b4 = C4 + 2L b5
  gemm2(3, P2, nullptr, P0, -1.f);     spmm(P2, Pb2, Pb1, -2.f);    // b3 = C3 - b5 + 2L b4
  gemm2(2, P0, nullptr, P1, -1.f);     spmm(P0, Pb0, Pb2, -2.f);    // b2 = C2 - b4 + 2L b3
  gemm2(1, P1, nullptr, P2, -1.f);     spmm(P1, Pb1, Pb0, -2.f);    // b1 = C1 - b3 + 2L b2
  gemm2(0, P2, nullptr, P0, -1.f);     spmm(P2, nullptr, Pb1, -1.f);// res = C0 - b2 + L b1

  // ---- epilogue ----
  float* out  = (float*)d_out;
  float* feat = out + N;
  k_feat<<<ceil_div(N, 4), 256, 0, stream>>>(P2, bc, W_out, W_root, feat, pbuf, wrbuf, N);
  k_out<<<ceil_div(N, 256), 256, 0, stream>>>(pbuf, wrbuf, invw, csr_src, row_ptr, b3, out, N);
}

// Round 5
// 1556.243 us; speedup vs baseline: 1.3566x; 1.3566x over previous
//
#include <hip/hip_runtime.h>
#include <cstdint>
#include <cstddef>

typedef __attribute__((ext_vector_type(8))) short bf16x8;
typedef __attribute__((ext_vector_type(4))) float f32x4;

static inline int ceil_div(int a, int b){ return (a + b - 1) / b; }

struct HL { short h, l; };
__device__ inline HL split2(float a){
  unsigned u = __float_as_uint(a);
  unsigned hb = (u + 0x8000u) & 0xFFFF0000u;
  float r = a - __uint_as_float(hb);
  HL o;
  o.h = (short)(hb >> 16);
  o.l = (short)((__float_as_uint(r) + 0x8000u) >> 16);
  return o;
}

__device__ inline unsigned short f2b(float f){            // fp32 -> bf16 (RNE)
  unsigned u = __float_as_uint(f);
  unsigned r = u + 0x7FFFu + ((u >> 16) & 1u);
  return (unsigned short)(r >> 16);
}
__device__ inline float b2f(unsigned short s){
  return __uint_as_float((unsigned)s << 16);
}

// ---------------- dtype detection (int64 vs int32 edge_index) ----------------
__global__ __launch_bounds__(256) void k_detect(const int* __restrict__ ei32, int E, int* __restrict__ flag){
  int t = blockIdx.x * 256 + threadIdx.x;
  if (t < 4096) {
    long long idx = 2LL * t + 1;
    if (idx < 2LL * E && ei32[idx] != 0) atomicOr(flag, 1);
  }
}

// ---------------- CSR build ----------------
__global__ __launch_bounds__(256) void k_count(const void* __restrict__ ei, int E,
                                               const int* __restrict__ flag, int* __restrict__ cnt){
  int e = blockIdx.x * 256 + threadIdx.x;
  if (e >= E) return;
  int dst = (*flag) ? ((const int*)ei)[(size_t)E + e]
                    : (int)((const long long*)ei)[(size_t)E + e];
  atomicAdd(&cnt[dst], 1);
}

__global__ __launch_bounds__(1024) void k_scan(const int* __restrict__ cnt, int* __restrict__ row_ptr, int N){
  __shared__ int sums[1024];
  int t = threadIdx.x;
  int chunk = (N + 1023) >> 10;
  int lo = t * chunk, hi = min(lo + chunk, N);
  int s = 0;
  for (int i = lo; i < hi; ++i) s += cnt[i];
  sums[t] = s; __syncthreads();
  for (int off = 1; off < 1024; off <<= 1){
    int v = 0;
    if (t >= off) v = sums[t - off];
    __syncthreads();
    if (t >= off) sums[t] += v;
    __syncthreads();
  }
  int pre = (t == 0) ? 0 : sums[t - 1];
  for (int i = lo; i < hi; ++i){ row_ptr[i] = pre; pre += cnt[i]; }
  if (t == 1023) row_ptr[N] = sums[1023];
}

__global__ __launch_bounds__(256) void k_copy(const int* __restrict__ a, int* __restrict__ b, int n){
  int i = blockIdx.x * 256 + threadIdx.x;
  if (i < n) b[i] = a[i];
}

__global__ __launch_bounds__(256) void k_fill(const void* __restrict__ ei, const float* __restrict__ ew, int E,
                                              const int* __restrict__ flag, int* __restrict__ cursor,
                                              int* __restrict__ csr_src, float* __restrict__ csr_ew){
  int e = blockIdx.x * 256 + threadIdx.x;
  if (e >= E) return;
  int src, dst;
  if (*flag){ src = ((const int*)ei)[e]; dst = ((const int*)ei)[(size_t)E + e]; }
  else      { src = (int)((const long long*)ei)[e]; dst = (int)((const long long*)ei)[(size_t)E + e]; }
  int pos = atomicAdd(&cursor[dst], 1);
  csr_src[pos] = src;
  csr_ew[pos] = ew[e];
}

__global__ __launch_bounds__(256) void k_degrees(const int* __restrict__ row_ptr, const float* __restrict__ csr_ew,
                                                 float* __restrict__ dis1, float* __restrict__ dis2,
                                                 float* __restrict__ invw, int N){
  int r = blockIdx.x * 256 + threadIdx.x;
  if (r >= N) return;
  int e0 = row_ptr[r], e1 = row_ptr[r + 1];
  float s = 0.f;
  for (int e = e0; e < e1; ++e) s += csr_ew[e];
  dis1[r] = rsqrtf(s + 1.0f);
  dis2[r] = (s > 0.0f) ? rsqrtf(s) : 0.0f;
  invw[r] = 1.0f / (float)(e1 - e0 + 1);
}

// ---------------- edge norms: fold dis[src] into the edge weight (kills dependent gather) ----
__global__ __launch_bounds__(256) void k_norm(const int* __restrict__ csr_src, const float* __restrict__ csr_ew,
                                              const float* __restrict__ dis1, const float* __restrict__ dis2,
                                              float* __restrict__ w_gcn, float* __restrict__ w_cheb, int E){
  int e = blockIdx.x * 256 + threadIdx.x;
  if (e >= E) return;
  int s = csr_src[e];
  float w = csr_ew[e];
  w_gcn[e]  = w * dis1[s];
  w_cheb[e] = w * dis2[s];
}

// ---------------- weight prep: W [K][N] fp32 -> Wh/Wl [N][K] bf16 split ----------------
__global__ __launch_bounds__(256) void k_prep_w(const float* __restrict__ W, short* __restrict__ Wh,
                                                short* __restrict__ Wl, int K, int N){
  int idx = blockIdx.x * 256 + threadIdx.x;
  if (idx >= K * N) return;
  int n = idx / K, k = idx - n * K;
  HL s = split2(W[(size_t)k * N + n]);
  Wh[idx] = s.h; Wl[idx] = s.l;
}

// ---------------- MFMA GEMM: C = A@B + dscale*D (C and/or bf16 shadow Cb optional) ----------------
__global__ __launch_bounds__(256) void k_gemm_mfma(
    const float* __restrict__ A,
    const short* __restrict__ Bh, const short* __restrict__ Bl,
    const float* __restrict__ D, float dscale,
    float* __restrict__ C, unsigned short* __restrict__ Cb,
    int M, int Ncols, int K)
{
  __shared__ short Ah[128][40];
  __shared__ short Al[128][40];
  __shared__ short Bhs[128][40];
  __shared__ short Bls[128][40];
  int m0 = blockIdx.x * 128, n0 = blockIdx.y * 128;
  int t = threadIdx.x;
  int lane = t & 63, wid = t >> 6;
  int wr = wid >> 1, wc = wid & 1;
  int fr = lane & 15, fq = lane >> 4;
  int srow = t >> 1, skh = (t & 1) << 4;

  f32x4 acc[4][4];
#pragma unroll
  for (int i = 0; i < 4; ++i)
#pragma unroll
    for (int j = 0; j < 4; ++j) acc[i][j] = (f32x4){0.f, 0.f, 0.f, 0.f};

  bool aval = (m0 + srow) < M;
  const float* Aptr = A + (size_t)(m0 + srow) * K + skh;
  const short* Bhp = Bh + (size_t)(n0 + srow) * K + skh;
  const short* Blp = Bl + (size_t)(n0 + srow) * K + skh;

  for (int k0 = 0; k0 < K; k0 += 32){
    __syncthreads();
    float av[16];
    if (aval){
      const float4* ap = (const float4*)(Aptr + k0);
      float4 a0 = ap[0], a1 = ap[1], a2 = ap[2], a3 = ap[3];
      av[0]=a0.x; av[1]=a0.y; av[2]=a0.z; av[3]=a0.w;
      av[4]=a1.x; av[5]=a1.y; av[6]=a1.z; av[7]=a1.w;
      av[8]=a2.x; av[9]=a2.y; av[10]=a2.z; av[11]=a2.w;
      av[12]=a3.x; av[13]=a3.y; av[14]=a3.z; av[15]=a3.w;
    } else {
#pragma unroll
      for (int i = 0; i < 16; ++i) av[i] = 0.f;
    }
    bf16x8 h0, h1, l0, l1;
#pragma unroll
    for (int i = 0; i < 8; ++i){
      HL s = split2(av[i]);
      h0[i] = s.h; l0[i] = s.l;
    }
#pragma unroll
    for (int i = 0; i < 8; ++i){
      HL s = split2(av[8 + i]);
      h1[i] = s.h; l1[i] = s.l;
    }
    *(bf16x8*)&Ah[srow][skh]     = h0;
    *(bf16x8*)&Ah[srow][skh + 8] = h1;
    *(bf16x8*)&Al[srow][skh]     = l0;
    *(bf16x8*)&Al[srow][skh + 8] = l1;
    {
      const bf16x8* bp = (const bf16x8*)(Bhp + k0);
      *(bf16x8*)&Bhs[srow][skh]     = bp[0];
      *(bf16x8*)&Bhs[srow][skh + 8] = bp[1];
      const bf16x8* cp = (const bf16x8*)(Blp + k0);
      *(bf16x8*)&Bls[srow][skh]     = cp[0];
      *(bf16x8*)&Bls[srow][skh + 8] = cp[1];
    }
    __syncthreads();
    bf16x8 afh[4], afl[4], bfh[4], bfl[4];
#pragma unroll
    for (int m = 0; m < 4; ++m){
      int r = wr * 64 + m * 16 + fr;
      afh[m] = *(const bf16x8*)&Ah[r][fq * 8];
      afl[m] = *(const bf16x8*)&Al[r][fq * 8];
    }
#pragma unroll
    for (int n = 0; n < 4; ++n){
      int r = wc * 64 + n * 16 + fr;
      bfh[n] = *(const bf16x8*)&Bhs[r][fq * 8];
      bfl[n] = *(const bf16x8*)&Bls[r][fq * 8];
    }
#pragma unroll
    for (int m = 0; m < 4; ++m)
#pragma unroll
      for (int n = 0; n < 4; ++n){
        acc[m][n] = __builtin_amdgcn_mfma_f32_16x16x32_bf16(afh[m], bfh[n], acc[m][n], 0, 0, 0);
        acc[m][n] = __builtin_amdgcn_mfma_f32_16x16x32_bf16(afl[m], bfh[n], acc[m][n], 0, 0, 0);
        acc[m][n] = __builtin_amdgcn_mfma_f32_16x16x32_bf16(afh[m], bfl[n], acc[m][n], 0, 0, 0);
      }
  }
#pragma unroll
  for (int m = 0; m < 4; ++m){
#pragma unroll
    for (int n = 0; n < 4; ++n){
      int col = n0 + wc * 64 + n * 16 + fr;
#pragma unroll
      for (int r = 0; r < 4; ++r){
        int row = m0 + wr * 64 + m * 16 + fq * 4 + r;
        if (row < M){
          size_t off = (size_t)row * Ncols + col;
          float v = acc[m][n][r];
          if (dscale != 0.f) v = fmaf(dscale, D[off], v);
          if (C)  C[off] = v;
          if (Cb) Cb[off] = f2b(v);
        }
      }
    }
  }
}

// ---------------- GCN aggregation (width 256), wave/row, bf16 gathers, 4-wide MLP unroll ----------------
__global__ __launch_bounds__(256) void k_gcn_agg(
    const unsigned short* __restrict__ h0b,
    const int* __restrict__ csr_src, const float* __restrict__ w_gcn,
    const int* __restrict__ row_ptr, const float* __restrict__ dis1,
    const float* __restrict__ b1, float* __restrict__ h1, int N){
  int lane = threadIdx.x & 63;
  int r = blockIdx.x * 4 + (threadIdx.x >> 6);
  if (r >= N) return;
  float dr = dis1[r];
  ushort4 sv = ((const ushort4*)(h0b + (size_t)r * 256))[lane];
  float4 inner = make_float4(b2f(sv.x) * dr, b2f(sv.y) * dr, b2f(sv.z) * dr, b2f(sv.w) * dr);
  int e0 = row_ptr[r], e1 = row_ptr[r + 1];
  int e = e0;
  for (; e + 4 <= e1; e += 4){
    int s0 = csr_src[e], s1 = csr_src[e+1], s2 = csr_src[e+2], s3 = csr_src[e+3];
    float w0 = w_gcn[e], w1 = w_gcn[e+1], w2 = w_gcn[e+2], w3 = w_gcn[e+3];
    ushort4 v0 = ((const ushort4*)(h0b + (size_t)s0 * 256))[lane];
    ushort4 v1 = ((const ushort4*)(h0b + (size_t)s1 * 256))[lane];
    ushort4 v2 = ((const ushort4*)(h0b + (size_t)s2 * 256))[lane];
    ushort4 v3 = ((const ushort4*)(h0b + (size_t)s3 * 256))[lane];
    inner.x = fmaf(w0, b2f(v0.x), inner.x); inner.y = fmaf(w0, b2f(v0.y), inner.y);
    inner.z = fmaf(w0, b2f(v0.z), inner.z); inner.w = fmaf(w0, b2f(v0.w), inner.w);
    inner.x = fmaf(w1, b2f(v1.x), inner.x); inner.y = fmaf(w1, b2f(v1.y), inner.y);
    inner.z = fmaf(w1, b2f(v1.z), inner.z); inner.w = fmaf(w1, b2f(v1.w), inner.w);
    inner.x = fmaf(w2, b2f(v2.x), inner.x); inner.y = fmaf(w2, b2f(v2.y), inner.y);
    inner.z = fmaf(w2, b2f(v2.z), inner.z); inner.w = fmaf(w2, b2f(v2.w), inner.w);
    inner.x = fmaf(w3, b2f(v3.x), inner.x); inner.y = fmaf(w3, b2f(v3.y), inner.y);
    inner.z = fmaf(w3, b2f(v3.z), inner.z); inner.w = fmaf(w3, b2f(v3.w), inner.w);
  }
  for (; e < e1; ++e){
    int s = csr_src[e];
    float w = w_gcn[e];
    ushort4 v = ((const ushort4*)(h0b + (size_t)s * 256))[lane];
    inner.x = fmaf(w, b2f(v.x), inner.x); inner.y = fmaf(w, b2f(v.y), inner.y);
    inner.z = fmaf(w, b2f(v.z), inner.z); inner.w = fmaf(w, b2f(v.w), inner.w);
  }
  float4 bb = ((const float4*)b1)[lane];
  float4 o;
  o.x = fmaxf(fmaf(inner.x, dr, bb.x), 0.f);
  o.y = fmaxf(fmaf(inner.y, dr, bb.y), 0.f);
  o.z = fmaxf(fmaf(inner.z, dr, bb.z), 0.f);
  o.w = fmaxf(fmaf(inner.w, dr, bb.w), 0.f);
  ((float4*)(h1 + (size_t)r * 256))[lane] = o;
}

// ---------------- Cheb spmm (width 128), bf16 gathers, 4-wide MLP unroll ----------------
__global__ __launch_bounds__(256) void k_cheb_spmm(const unsigned short* __restrict__ srcb,
    float* __restrict__ dst, unsigned short* __restrict__ dstb,
    const int* __restrict__ csr_src, const float* __restrict__ w_cheb,
    const int* __restrict__ row_ptr, const float* __restrict__ dis2, float coef, int N){
  int lane = threadIdx.x & 63;
  int r = blockIdx.x * 4 + (threadIdx.x >> 6);
  if (r >= N) return;
  float2 inner = make_float2(0.f, 0.f);
  int e0 = row_ptr[r], e1 = row_ptr[r + 1];
  int e = e0;
  for (; e + 4 <= e1; e += 4){
    int s0 = csr_src[e], s1 = csr_src[e+1], s2 = csr_src[e+2], s3 = csr_src[e+3];
    float w0 = w_cheb[e], w1 = w_cheb[e+1], w2 = w_cheb[e+2], w3 = w_cheb[e+3];
    unsigned v0 = ((const unsigned*)(srcb + (size_t)s0 * 128))[lane];
    unsigned v1 = ((const unsigned*)(srcb + (size_t)s1 * 128))[lane];
    unsigned v2 = ((const unsigned*)(srcb + (size_t)s2 * 128))[lane];
    unsigned v3 = ((const unsigned*)(srcb + (size_t)s3 * 128))[lane];
    inner.x = fmaf(w0, __uint_as_float(v0 << 16), inner.x);
    inner.y = fmaf(w0, __uint_as_float(v0 & 0xFFFF0000u), inner.y);
    inner.x = fmaf(w1, __uint_as_float(v1 << 16), inner.x);
    inner.y = fmaf(w1, __uint_as_float(v1 & 0xFFFF0000u), inner.y);
    inner.x = fmaf(w2, __uint_as_float(v2 << 16), inner.x);
    inner.y = fmaf(w2, __uint_as_float(v2 & 0xFFFF0000u), inner.y);
    inner.x = fmaf(w3, __uint_as_float(v3 << 16), inner.x);
    inner.y = fmaf(w3, __uint_as_float(v3 & 0xFFFF0000u), inner.y);
  }
  for (; e < e1; ++e){
    int s = csr_src[e];
    float w = w_cheb[e];
    unsigned v = ((const unsigned*)(srcb + (size_t)s * 128))[lane];
    inner.x = fmaf(w, __uint_as_float(v << 16), inner.x);
    inner.y = fmaf(w, __uint_as_float(v & 0xFFFF0000u), inner.y);
  }
  float c = coef * dis2[r];
  float2* op = (float2*)(dst + (size_t)r * 128) + lane;
  float2 cur = *op;
  cur.x = fmaf(c, inner.x, cur.x);
  cur.y = fmaf(c, inner.y, cur.y);
  *op = cur;
  if (dstb){
    unsigned pk = (unsigned)f2b(cur.x) | ((unsigned)f2b(cur.y) << 16);
    ((unsigned*)(dstb + (size_t)r * 128))[lane] = pk;
  }
}

// ---------------- features epilogue ----------------
__global__ __launch_bounds__(256) void k_feat(const float* __restrict__ P, const float* __restrict__ bc,
    const float* __restrict__ W_out, const float* __restrict__ W_root,
    float* __restrict__ feat, float* __restrict__ p, float* __restrict__ wr, int N){
  int lane = threadIdx.x & 63;
  int r = blockIdx.x * 4 + (threadIdx.x >> 6);
  if (r >= N) return;
  float2 v = ((const float2*)(P + (size_t)r * 128))[lane];
  float2 bb = ((const float2*)bc)[lane];
  v.x = fmaxf(v.x + bb.x, 0.f);
  v.y = fmaxf(v.y + bb.y, 0.f);
  ((float2*)(feat + (size_t)r * 128))[lane] = v;
  float2 wo = ((const float2*)W_out)[lane];
  float2 wrt = ((const float2*)W_root)[lane];
  float pp = v.x * wo.x + v.y * wo.y;
  float rr = v.x * wrt.x + v.y * wrt.y;
#pragma unroll
  for (int off = 32; off; off >>= 1){
    pp += __shfl_xor(pp, off);
    rr += __shfl_xor(rr, off);
  }
  if (lane == 0){ p[r] = pp; wr[r] = rr; }
}

// ---------------- ClusterGCN output ----------------
__global__ __launch_bounds__(256) void k_out(const float* __restrict__ p, const float* __restrict__ wr,
    const float* __restrict__ invw, const int* __restrict__ csr_src, const int* __restrict__ row_ptr,
    const float* __restrict__ b3, float* __restrict__ out, int N){
  int r = blockIdx.x * 256 + threadIdx.x;
  if (r >= N) return;
  float s = p[r];
  int e0 = row_ptr[r], e1 = row_ptr[r + 1];
  int e = e0;
  float s0 = 0.f, s1 = 0.f, s2 = 0.f, s3 = 0.f;
  for (; e + 4 <= e1; e += 4){
    int a = csr_src[e], b = csr_src[e+1], c = csr_src[e+2], d = csr_src[e+3];
    s0 += p[a]; s1 += p[b]; s2 += p[c]; s3 += p[d];
  }
  for (; e < e1; ++e) s0 += p[csr_src[e]];
  s += s0 + s1 + s2 + s3;
  out[r] = invw[r] * s + wr[r] + b3[0];
}

extern "C" void kernel_launch(void* const* d_in, const int* in_sizes, int n_in,
                              void* d_out, int out_size, void* d_ws, size_t ws_size,
                              hipStream_t stream){
  const float* x      = (const float*)d_in[0];
  const void*  ei     = d_in[1];
  const float* ew     = (const float*)d_in[2];
  const float* W1     = (const float*)d_in[3];
  const float* b1     = (const float*)d_in[4];
  const float* Wc     = (const float*)d_in[5];
  const float* bc     = (const float*)d_in[6];
  const float* W_out  = (const float*)d_in[7];
  const float* W_root = (const float*)d_in[8];
  const float* b3     = (const float*)d_in[9];
  const int N = in_sizes[0] / 512;
  const int E = in_sizes[2];

  char* w = (char*)d_ws;
  auto alloc = [&](size_t bytes)->void*{ void* r = (void*)w; w += (bytes + 255) & ~(size_t)255; return r; };
  float* PP      = (float*)alloc((size_t)N * 256 * 4);   // P0|P1 (fp32 Clenshaw)
  float* h1      = (float*)alloc((size_t)N * 256 * 4);   // GCN output (Cheb GEMM A)
  float* P2      = (float*)alloc((size_t)N * 128 * 4);
  unsigned short* h0b = (unsigned short*)alloc((size_t)N * 256 * 2); // bf16 x@W1; later Pb0|Pb1
  unsigned short* Pb2 = (unsigned short*)alloc((size_t)N * 128 * 2);
  float* csr_ew  = (float*)alloc((size_t)E * 4);
  float* w_gcn   = (float*)alloc((size_t)E * 4);
  float* w_cheb  = (float*)alloc((size_t)E * 4);
  int*   csr_src = (int*)  alloc((size_t)E * 4);
  int*   row_ptr = (int*)  alloc((size_t)(N + 1) * 4);
  int*   cursor  = (int*)  alloc((size_t)N * 4);
  int*   cnt     = (int*)  alloc((size_t)N * 4);
  float* dis1    = (float*)alloc((size_t)N * 4);
  float* dis2    = (float*)alloc((size_t)N * 4);
  float* invw    = (float*)alloc((size_t)N * 4);
  float* pbuf    = (float*)alloc((size_t)N * 4);
  float* wrbuf   = (float*)alloc((size_t)N * 4);
  short* W1t_h   = (short*)alloc((size_t)512 * 256 * 2);
  short* W1t_l   = (short*)alloc((size_t)512 * 256 * 2);
  short* Wct_h   = (short*)alloc((size_t)6 * 256 * 128 * 2);
  short* Wct_l   = (short*)alloc((size_t)6 * 256 * 128 * 2);
  int*   flag    = (int*)  alloc(256);
  float* P0 = PP;
  float* P1 = PP + (size_t)N * 128;
  unsigned short* Pb0 = h0b;
  unsigned short* Pb1 = h0b + (size_t)N * 128;

  hipMemsetAsync(cnt, 0, (size_t)N * 4, stream);
  hipMemsetAsync(flag, 0, 4, stream);

  k_detect<<<16, 256, 0, stream>>>((const int*)ei, E, flag);
  k_count<<<ceil_div(E, 256), 256, 0, stream>>>(ei, E, flag, cnt);
  k_scan<<<1, 1024, 0, stream>>>(cnt, row_ptr, N);
  k_copy<<<ceil_div(N, 256), 256, 0, stream>>>(row_ptr, cursor, N);
  k_fill<<<ceil_div(E, 256), 256, 0, stream>>>(ei, ew, E, flag, cursor, csr_src, csr_ew);
  k_degrees<<<ceil_div(N, 256), 256, 0, stream>>>(row_ptr, csr_ew, dis1, dis2, invw, N);
  k_norm<<<ceil_div(E, 256), 256, 0, stream>>>(csr_src, csr_ew, dis1, dis2, w_gcn, w_cheb, E);

  // weight prep (transpose + bf16 split)
  k_prep_w<<<ceil_div(512 * 256, 256), 256, 0, stream>>>(W1, W1t_h, W1t_l, 512, 256);
  for (int k = 0; k < 6; ++k)
    k_prep_w<<<ceil_div(256 * 128, 256), 256, 0, stream>>>(Wc + (size_t)k * 256 * 128,
        Wct_h + (size_t)k * 256 * 128, Wct_l + (size_t)k * 256 * 128, 256, 128);

  // ---- GCNConv: h0b = bf16(x@W1); h1 = relu(agg + b1) ----
  k_gemm_mfma<<<dim3(ceil_div(N, 128), 2), 256, 0, stream>>>(x, W1t_h, W1t_l, nullptr, 0.f, nullptr, h0b, N, 256, 512);
  k_gcn_agg<<<ceil_div(N, 4), 256, 0, stream>>>(h0b, csr_src, w_gcn, row_ptr, dis1, b1, h1, N);

  // ---- ChebConv via Clenshaw (width 128), bf16 gathers ----
  auto gemm2 = [&](int k, float* dst, unsigned short* dstb, const float* Dm, float ds){
    k_gemm_mfma<<<dim3(ceil_div(N, 128), 1), 256, 0, stream>>>(h1,
        Wct_h + (size_t)k * 256 * 128, Wct_l + (size_t)k * 256 * 128, Dm, ds, dst, dstb, N, 128, 256);
  };
  auto spmm = [&](float* dst, unsigned short* dstb, const unsigned short* srcb, float coef){
    k_cheb_spmm<<<ceil_div(N, 4), 256, 0, stream>>>(srcb, dst, dstb, csr_src, w_cheb, row_ptr, dis2, coef, N);
  };
  gemm2(5, P0, Pb0, nullptr, 0.f);                                  // b5 = C5
  gemm2(4, P1, nullptr, nullptr, 0.f); spmm(P1, Pb1, Pb0, -2.f);    // b4 = C4 + 2L b5
  gemm2(3, P2, nullptr, P0, -1.f);     spmm(P2, Pb2, Pb1, -2.f);    // b3 = C3 - b5 + 2L b4
  gemm2(2, P0, nullptr, P1, -1.f);     spmm(P0, Pb0, Pb2, -2.f);    // b2 = C2 - b4 + 2L b3
  gemm2(1, P1, nullptr, P2, -1.f);     spmm(P1, Pb1, Pb0, -2.f);    // b1 = C1 - b3 + 2L b2
  gemm2(0, P2, nullptr, P0, -1.f);     spmm(P2, nullptr, Pb1, -1.f);// res = C0 - b2 + L b1

  // ---- epilogue ----
  float* out  = (float*)d_out;
  float* feat = out + N;
  k_feat<<<ceil_div(N, 4), 256, 0, stream>>>(P2, bc, W_out, W_root, feat, pbuf, wrbuf, N);
  k_out<<<ceil_div(N, 256), 256, 0, stream>>>(pbuf, wrbuf, invw, csr_src, row_ptr, b3, out, N);
}

// Round 6
// 1408.575 us; speedup vs baseline: 1.4988x; 1.1048x over previous
//
#include <hip/hip_runtime.h>
#include <cstdint>
#include <cstddef>

typedef __attribute__((ext_vector_type(8))) short bf16x8;
typedef __attribute__((ext_vector_type(4))) float f32x4;

static inline int ceil_div(int a, int b){ return (a + b - 1) / b; }

struct HL { short h, l; };
__device__ inline HL split2(float a){
  unsigned u = __float_as_uint(a);
  unsigned hb = (u + 0x8000u) & 0xFFFF0000u;
  float r = a - __uint_as_float(hb);
  HL o;
  o.h = (short)(hb >> 16);
  o.l = (short)((__float_as_uint(r) + 0x8000u) >> 16);
  return o;
}

__device__ inline unsigned short f2b(float f){            // fp32 -> bf16 (RNE)
  unsigned u = __float_as_uint(f);
  unsigned r = u + 0x7FFFu + ((u >> 16) & 1u);
  return (unsigned short)(r >> 16);
}
__device__ inline float b2f(unsigned short s){
  return __uint_as_float((unsigned)s << 16);
}

// ---------------- dtype detection (int64 vs int32 edge_index) ----------------
__global__ __launch_bounds__(256) void k_detect(const int* __restrict__ ei32, int E, int* __restrict__ flag){
  int t = blockIdx.x * 256 + threadIdx.x;
  if (t < 4096) {
    long long idx = 2LL * t + 1;
    if (idx < 2LL * E && ei32[idx] != 0) atomicOr(flag, 1);
  }
}

// ---------------- CSR build ----------------
__global__ __launch_bounds__(256) void k_count(const void* __restrict__ ei, int E,
                                               const int* __restrict__ flag, int* __restrict__ cnt){
  int e = blockIdx.x * 256 + threadIdx.x;
  if (e >= E) return;
  int dst = (*flag) ? ((const int*)ei)[(size_t)E + e]
                    : (int)((const long long*)ei)[(size_t)E + e];
  atomicAdd(&cnt[dst], 1);
}

// ---- 3-pass device-wide exclusive scan over cnt[N] -> row_ptr (+cursor copy) ----
// pass 1: per-block (1024-element) sums
__global__ __launch_bounds__(256) void k_scan_part(const int* __restrict__ cnt, int* __restrict__ bsum, int N){
  int base = blockIdx.x * 1024 + threadIdx.x * 4;
  int s = 0;
  if (base + 4 <= N){
    int4 v = *(const int4*)(cnt + base);
    s = v.x + v.y + v.z + v.w;
  } else {
    for (int i = base; i < N; ++i) s += cnt[i];
  }
#pragma unroll
  for (int off = 32; off; off >>= 1) s += __shfl_xor(s, off);
  __shared__ int ws[4];
  if ((threadIdx.x & 63) == 0) ws[threadIdx.x >> 6] = s;
  __syncthreads();
  if (threadIdx.x == 0) bsum[blockIdx.x] = ws[0] + ws[1] + ws[2] + ws[3];
}

// pass 2: one block scans the block sums (exclusive), nb <= 1024
__global__ __launch_bounds__(1024) void k_scan_bsum(int* __restrict__ bsum, int nb){
  __shared__ int sh[1024];
  int t = threadIdx.x;
  int v = (t < nb) ? bsum[t] : 0;
  sh[t] = v; __syncthreads();
  for (int off = 1; off < 1024; off <<= 1){
    int u = (t >= off) ? sh[t - off] : 0;
    __syncthreads();
    sh[t] += u;
    __syncthreads();
  }
  if (t < nb) bsum[t] = sh[t] - v;   // exclusive
}

// pass 3: per-block exclusive scan + block offset -> row_ptr and cursor
__global__ __launch_bounds__(256) void k_scan_write(const int* __restrict__ cnt, const int* __restrict__ bsum,
                                                    int* __restrict__ row_ptr, int* __restrict__ cursor,
                                                    int N, int E){
  int t = threadIdx.x;
  int base = blockIdx.x * 1024 + t * 4;
  int v0 = 0, v1 = 0, v2 = 0, v3 = 0;
  if (base + 4 <= N){
    int4 v = *(const int4*)(cnt + base);
    v0 = v.x; v1 = v.y; v2 = v.z; v3 = v.w;
  } else {
    if (base + 0 < N) v0 = cnt[base + 0];
    if (base + 1 < N) v1 = cnt[base + 1];
    if (base + 2 < N) v2 = cnt[base + 2];
    if (base + 3 < N) v3 = cnt[base + 3];
  }
  int s = v0 + v1 + v2 + v3;
  int lane = t & 63;
  int inc = s;
#pragma unroll
  for (int off = 1; off < 64; off <<= 1){
    int u = __shfl_up(inc, off);
    if (lane >= off) inc += u;
  }
  __shared__ int ws[4];
  if (lane == 63) ws[t >> 6] = inc;
  __syncthreads();
  int wid = t >> 6;
  int woff = 0;
  for (int i = 0; i < wid; ++i) woff += ws[i];
  int exc = bsum[blockIdx.x] + woff + inc - s;
  int p0 = exc, p1 = p0 + v0, p2 = p1 + v1, p3 = p2 + v2;
  if (base + 0 < N){ row_ptr[base + 0] = p0; cursor[base + 0] = p0; }
  if (base + 1 < N){ row_ptr[base + 1] = p1; cursor[base + 1] = p1; }
  if (base + 2 < N){ row_ptr[base + 2] = p2; cursor[base + 2] = p2; }
  if (base + 3 < N){ row_ptr[base + 3] = p3; cursor[base + 3] = p3; }
  if (blockIdx.x == 0 && t == 0) row_ptr[N] = E;
}

__global__ __launch_bounds__(256) void k_fill(const void* __restrict__ ei, const float* __restrict__ ew, int E,
                                              const int* __restrict__ flag, int* __restrict__ cursor,
                                              int* __restrict__ csr_src, float* __restrict__ csr_ew){
  int e = blockIdx.x * 256 + threadIdx.x;
  if (e >= E) return;
  int src, dst;
  if (*flag){ src = ((const int*)ei)[e]; dst = ((const int*)ei)[(size_t)E + e]; }
  else      { src = (int)((const long long*)ei)[e]; dst = (int)((const long long*)ei)[(size_t)E + e]; }
  int pos = atomicAdd(&cursor[dst], 1);
  csr_src[pos] = src;
  csr_ew[pos] = ew[e];
}

__global__ __launch_bounds__(256) void k_degrees(const int* __restrict__ row_ptr, const float* __restrict__ csr_ew,
                                                 float* __restrict__ dis1, float* __restrict__ dis2,
                                                 float* __restrict__ invw, int N){
  int r = blockIdx.x * 256 + threadIdx.x;
  if (r >= N) return;
  int e0 = row_ptr[r], e1 = row_ptr[r + 1];
  float s = 0.f;
  for (int e = e0; e < e1; ++e) s += csr_ew[e];
  dis1[r] = rsqrtf(s + 1.0f);
  dis2[r] = (s > 0.0f) ? rsqrtf(s) : 0.0f;
  invw[r] = 1.0f / (float)(e1 - e0 + 1);
}

// ---------------- edge norms: fold dis[src] into the edge weight ----------------
__global__ __launch_bounds__(256) void k_norm(const int* __restrict__ csr_src, const float* __restrict__ csr_ew,
                                              const float* __restrict__ dis1, const float* __restrict__ dis2,
                                              float* __restrict__ w_gcn, float* __restrict__ w_cheb, int E){
  int e = blockIdx.x * 256 + threadIdx.x;
  if (e >= E) return;
  int s = csr_src[e];
  float w = csr_ew[e];
  w_gcn[e]  = w * dis1[s];
  w_cheb[e] = w * dis2[s];
}

// ---------------- weight prep: W [K][N] fp32 -> Wh/Wl [N][K] bf16 split ----------------
__global__ __launch_bounds__(256) void k_prep_w(const float* __restrict__ W, short* __restrict__ Wh,
                                                short* __restrict__ Wl, int K, int N){
  int idx = blockIdx.x * 256 + threadIdx.x;
  if (idx >= K * N) return;
  int n = idx / K, k = idx - n * K;
  HL s = split2(W[(size_t)k * N + n]);
  Wh[idx] = s.h; Wl[idx] = s.l;
}

// ---------------- MFMA GEMM: C = A@B + dscale*D (C and/or bf16 shadow Cb optional) ----------------
__global__ __launch_bounds__(256) void k_gemm_mfma(
    const float* __restrict__ A,
    const short* __restrict__ Bh, const short* __restrict__ Bl,
    const float* __restrict__ D, float dscale,
    float* __restrict__ C, unsigned short* __restrict__ Cb,
    int M, int Ncols, int K)
{
  __shared__ short Ah[128][40];
  __shared__ short Al[128][40];
  __shared__ short Bhs[128][40];
  __shared__ short Bls[128][40];
  int m0 = blockIdx.x * 128, n0 = blockIdx.y * 128;
  int t = threadIdx.x;
  int lane = t & 63, wid = t >> 6;
  int wr = wid >> 1, wc = wid & 1;
  int fr = lane & 15, fq = lane >> 4;
  int srow = t >> 1, skh = (t & 1) << 4;

  f32x4 acc[4][4];
#pragma unroll
  for (int i = 0; i < 4; ++i)
#pragma unroll
    for (int j = 0; j < 4; ++j) acc[i][j] = (f32x4){0.f, 0.f, 0.f, 0.f};

  bool aval = (m0 + srow) < M;
  const float* Aptr = A + (size_t)(m0 + srow) * K + skh;
  const short* Bhp = Bh + (size_t)(n0 + srow) * K + skh;
  const short* Blp = Bl + (size_t)(n0 + srow) * K + skh;

  for (int k0 = 0; k0 < K; k0 += 32){
    __syncthreads();
    float av[16];
    if (aval){
      const float4* ap = (const float4*)(Aptr + k0);
      float4 a0 = ap[0], a1 = ap[1], a2 = ap[2], a3 = ap[3];
      av[0]=a0.x; av[1]=a0.y; av[2]=a0.z; av[3]=a0.w;
      av[4]=a1.x; av[5]=a1.y; av[6]=a1.z; av[7]=a1.w;
      av[8]=a2.x; av[9]=a2.y; av[10]=a2.z; av[11]=a2.w;
      av[12]=a3.x; av[13]=a3.y; av[14]=a3.z; av[15]=a3.w;
    } else {
#pragma unroll
      for (int i = 0; i < 16; ++i) av[i] = 0.f;
    }
    bf16x8 h0, h1, l0, l1;
#pragma unroll
    for (int i = 0; i < 8; ++i){
      HL s = split2(av[i]);
      h0[i] = s.h; l0[i] = s.l;
    }
#pragma unroll
    for (int i = 0; i < 8; ++i){
      HL s = split2(av[8 + i]);
      h1[i] = s.h; l1[i] = s.l;
    }
    *(bf16x8*)&Ah[srow][skh]     = h0;
    *(bf16x8*)&Ah[srow][skh + 8] = h1;
    *(bf16x8*)&Al[srow][skh]     = l0;
    *(bf16x8*)&Al[srow][skh + 8] = l1;
    {
      const bf16x8* bp = (const bf16x8*)(Bhp + k0);
      *(bf16x8*)&Bhs[srow][skh]     = bp[0];
      *(bf16x8*)&Bhs[srow][skh + 8] = bp[1];
      const bf16x8* cp = (const bf16x8*)(Blp + k0);
      *(bf16x8*)&Bls[srow][skh]     = cp[0];
      *(bf16x8*)&Bls[srow][skh + 8] = cp[1];
    }
    __syncthreads();
    bf16x8 afh[4], afl[4], bfh[4], bfl[4];
#pragma unroll
    for (int m = 0; m < 4; ++m){
      int r = wr * 64 + m * 16 + fr;
      afh[m] = *(const bf16x8*)&Ah[r][fq * 8];
      afl[m] = *(const bf16x8*)&Al[r][fq * 8];
    }
#pragma unroll
    for (int n = 0; n < 4; ++n){
      int r = wc * 64 + n * 16 + fr;
      bfh[n] = *(const bf16x8*)&Bhs[r][fq * 8];
      bfl[n] = *(const bf16x8*)&Bls[r][fq * 8];
    }
#pragma unroll
    for (int m = 0; m < 4; ++m)
#pragma unroll
      for (int n = 0; n < 4; ++n){
        acc[m][n] = __builtin_amdgcn_mfma_f32_16x16x32_bf16(afh[m], bfh[n], acc[m][n], 0, 0, 0);
        acc[m][n] = __builtin_amdgcn_mfma_f32_16x16x32_bf16(afl[m], bfh[n], acc[m][n], 0, 0, 0);
        acc[m][n] = __builtin_amdgcn_mfma_f32_16x16x32_bf16(afh[m], bfl[n], acc[m][n], 0, 0, 0);
      }
  }
#pragma unroll
  for (int m = 0; m < 4; ++m){
#pragma unroll
    for (int n = 0; n < 4; ++n){
      int col = n0 + wc * 64 + n * 16 + fr;
#pragma unroll
      for (int r = 0; r < 4; ++r){
        int row = m0 + wr * 64 + m * 16 + fq * 4 + r;
        if (row < M){
          size_t off = (size_t)row * Ncols + col;
          float v = acc[m][n][r];
          if (dscale != 0.f) v = fmaf(dscale, D[off], v);
          if (C)  C[off] = v;
          if (Cb) Cb[off] = f2b(v);
        }
      }
    }
  }
}

// ---------------- GCN aggregation (width 256), wave/row, bf16 gathers, 4-wide MLP unroll ----------------
__global__ __launch_bounds__(256) void k_gcn_agg(
    const unsigned short* __restrict__ h0b,
    const int* __restrict__ csr_src, const float* __restrict__ w_gcn,
    const int* __restrict__ row_ptr, const float* __restrict__ dis1,
    const float* __restrict__ b1, float* __restrict__ h1, int N){
  int lane = threadIdx.x & 63;
  int r = blockIdx.x * 4 + (threadIdx.x >> 6);
  if (r >= N) return;
  float dr = dis1[r];
  ushort4 sv = ((const ushort4*)(h0b + (size_t)r * 256))[lane];
  float4 inner = make_float4(b2f(sv.x) * dr, b2f(sv.y) * dr, b2f(sv.z) * dr, b2f(sv.w) * dr);
  int e0 = row_ptr[r], e1 = row_ptr[r + 1];
  int e = e0;
  for (; e + 4 <= e1; e += 4){
    int s0 = csr_src[e], s1 = csr_src[e+1], s2 = csr_src[e+2], s3 = csr_src[e+3];
    float w0 = w_gcn[e], w1 = w_gcn[e+1], w2 = w_gcn[e+2], w3 = w_gcn[e+3];
    ushort4 v0 = ((const ushort4*)(h0b + (size_t)s0 * 256))[lane];
    ushort4 v1 = ((const ushort4*)(h0b + (size_t)s1 * 256))[lane];
    ushort4 v2 = ((const ushort4*)(h0b + (size_t)s2 * 256))[lane];
    ushort4 v3 = ((const ushort4*)(h0b + (size_t)s3 * 256))[lane];
    inner.x = fmaf(w0, b2f(v0.x), inner.x); inner.y = fmaf(w0, b2f(v0.y), inner.y);
    inner.z = fmaf(w0, b2f(v0.z), inner.z); inner.w = fmaf(w0, b2f(v0.w), inner.w);
    inner.x = fmaf(w1, b2f(v1.x), inner.x); inner.y = fmaf(w1, b2f(v1.y), inner.y);
    inner.z = fmaf(w1, b2f(v1.z), inner.z); inner.w = fmaf(w1, b2f(v1.w), inner.w);
    inner.x = fmaf(w2, b2f(v2.x), inner.x); inner.y = fmaf(w2, b2f(v2.y), inner.y);
    inner.z = fmaf(w2, b2f(v2.z), inner.z); inner.w = fmaf(w2, b2f(v2.w), inner.w);
    inner.x = fmaf(w3, b2f(v3.x), inner.x); inner.y = fmaf(w3, b2f(v3.y), inner.y);
    inner.z = fmaf(w3, b2f(v3.z), inner.z); inner.w = fmaf(w3, b2f(v3.w), inner.w);
  }
  for (; e < e1; ++e){
    int s = csr_src[e];
    float w = w_gcn[e];
    ushort4 v = ((const ushort4*)(h0b + (size_t)s * 256))[lane];
    inner.x = fmaf(w, b2f(v.x), inner.x); inner.y = fmaf(w, b2f(v.y), inner.y);
    inner.z = fmaf(w, b2f(v.z), inner.z); inner.w = fmaf(w, b2f(v.w), inner.w);
  }
  float4 bb = ((const float4*)b1)[lane];
  float4 o;
  o.x = fmaxf(fmaf(inner.x, dr, bb.x), 0.f);
  o.y = fmaxf(fmaf(inner.y, dr, bb.y), 0.f);
  o.z = fmaxf(fmaf(inner.z, dr, bb.z), 0.f);
  o.w = fmaxf(fmaf(inner.w, dr, bb.w), 0.f);
  ((float4*)(h1 + (size_t)r * 256))[lane] = o;
}

// ---------------- Cheb spmm (width 128), bf16 gathers, 4-wide MLP unroll ----------------
__global__ __launch_bounds__(256) void k_cheb_spmm(const unsigned short* __restrict__ srcb,
    float* __restrict__ dst, unsigned short* __restrict__ dstb,
    const int* __restrict__ csr_src, const float* __restrict__ w_cheb,
    const int* __restrict__ row_ptr, const float* __restrict__ dis2, float coef, int N){
  int lane = threadIdx.x & 63;
  int r = blockIdx.x * 4 + (threadIdx.x >> 6);
  if (r >= N) return;
  float2 inner = make_float2(0.f, 0.f);
  int e0 = row_ptr[r], e1 = row_ptr[r + 1];
  int e = e0;
  for (; e + 4 <= e1; e += 4){
    int s0 = csr_src[e], s1 = csr_src[e+1], s2 = csr_src[e+2], s3 = csr_src[e+3];
    float w0 = w_cheb[e], w1 = w_cheb[e+1], w2 = w_cheb[e+2], w3 = w_cheb[e+3];
    unsigned v0 = ((const unsigned*)(srcb + (size_t)s0 * 128))[lane];
    unsigned v1 = ((const unsigned*)(srcb + (size_t)s1 * 128))[lane];
    unsigned v2 = ((const unsigned*)(srcb + (size_t)s2 * 128))[lane];
    unsigned v3 = ((const unsigned*)(srcb + (size_t)s3 * 128))[lane];
    inner.x = fmaf(w0, __uint_as_float(v0 << 16), inner.x);
    inner.y = fmaf(w0, __uint_as_float(v0 & 0xFFFF0000u), inner.y);
    inner.x = fmaf(w1, __uint_as_float(v1 << 16), inner.x);
    inner.y = fmaf(w1, __uint_as_float(v1 & 0xFFFF0000u), inner.y);
    inner.x = fmaf(w2, __uint_as_float(v2 << 16), inner.x);
    inner.y = fmaf(w2, __uint_as_float(v2 & 0xFFFF0000u), inner.y);
    inner.x = fmaf(w3, __uint_as_float(v3 << 16), inner.x);
    inner.y = fmaf(w3, __uint_as_float(v3 & 0xFFFF0000u), inner.y);
  }
  for (; e < e1; ++e){
    int s = csr_src[e];
    float w = w_cheb[e];
    unsigned v = ((const unsigned*)(srcb + (size_t)s * 128))[lane];
    inner.x = fmaf(w, __uint_as_float(v << 16), inner.x);
    inner.y = fmaf(w, __uint_as_float(v & 0xFFFF0000u), inner.y);
  }
  float c = coef * dis2[r];
  float2* op = (float2*)(dst + (size_t)r * 128) + lane;
  float2 cur = *op;
  cur.x = fmaf(c, inner.x, cur.x);
  cur.y = fmaf(c, inner.y, cur.y);
  *op = cur;
  if (dstb){
    unsigned pk = (unsigned)f2b(cur.x) | ((unsigned)f2b(cur.y) << 16);
    ((unsigned*)(dstb + (size_t)r * 128))[lane] = pk;
  }
}

// ---------------- features epilogue ----------------
__global__ __launch_bounds__(256) void k_feat(const float* __restrict__ P, const float* __restrict__ bc,
    const float* __restrict__ W_out, const float* __restrict__ W_root,
    float* __restrict__ feat, float* __restrict__ p, float* __restrict__ wr, int N){
  int lane = threadIdx.x & 63;
  int r = blockIdx.x * 4 + (threadIdx.x >> 6);
  if (r >= N) return;
  float2 v = ((const float2*)(P + (size_t)r * 128))[lane];
  float2 bb = ((const float2*)bc)[lane];
  v.x = fmaxf(v.x + bb.x, 0.f);
  v.y = fmaxf(v.y + bb.y, 0.f);
  ((float2*)(feat + (size_t)r * 128))[lane] = v;
  float2 wo = ((const float2*)W_out)[lane];
  float2 wrt = ((const float2*)W_root)[lane];
  float pp = v.x * wo.x + v.y * wo.y;
  float rr = v.x * wrt.x + v.y * wrt.y;
#pragma unroll
  for (int off = 32; off; off >>= 1){
    pp += __shfl_xor(pp, off);
    rr += __shfl_xor(rr, off);
  }
  if (lane == 0){ p[r] = pp; wr[r] = rr; }
}

// ---------------- ClusterGCN output ----------------
__global__ __launch_bounds__(256) void k_out(const float* __restrict__ p, const float* __restrict__ wr,
    const float* __restrict__ invw, const int* __restrict__ csr_src, const int* __restrict__ row_ptr,
    const float* __restrict__ b3, float* __restrict__ out, int N){
  int r = blockIdx.x * 256 + threadIdx.x;
  if (r >= N) return;
  float s = p[r];
  int e0 = row_ptr[r], e1 = row_ptr[r + 1];
  int e = e0;
  float s0 = 0.f, s1 = 0.f, s2 = 0.f, s3 = 0.f;
  for (; e + 4 <= e1; e += 4){
    int a = csr_src[e], b = csr_src[e+1], c = csr_src[e+2], d = csr_src[e+3];
    s0 += p[a]; s1 += p[b]; s2 += p[c]; s3 += p[d];
  }
  for (; e < e1; ++e) s0 += p[csr_src[e]];
  s += s0 + s1 + s2 + s3;
  out[r] = invw[r] * s + wr[r] + b3[0];
}

extern "C" void kernel_launch(void* const* d_in, const int* in_sizes, int n_in,
                              void* d_out, int out_size, void* d_ws, size_t ws_size,
                              hipStream_t stream){
  const float* x      = (const float*)d_in[0];
  const void*  ei     = d_in[1];
  const float* ew     = (const float*)d_in[2];
  const float* W1     = (const float*)d_in[3];
  const float* b1     = (const float*)d_in[4];
  const float* Wc     = (const float*)d_in[5];
  const float* bc     = (const float*)d_in[6];
  const float* W_out  = (const float*)d_in[7];
  const float* W_root = (const float*)d_in[8];
  const float* b3     = (const float*)d_in[9];
  const int N = in_sizes[0] / 512;
  const int E = in_sizes[2];

  char* w = (char*)d_ws;
  auto alloc = [&](size_t bytes)->void*{ void* r = (void*)w; w += (bytes + 255) & ~(size_t)255; return r; };
  float* PP      = (float*)alloc((size_t)N * 256 * 4);   // P0|P1 (fp32 Clenshaw)
  float* h1      = (float*)alloc((size_t)N * 256 * 4);   // GCN output (Cheb GEMM A)
  float* P2      = (float*)alloc((size_t)N * 128 * 4);
  unsigned short* h0b = (unsigned short*)alloc((size_t)N * 256 * 2); // bf16 x@W1; later Pb0|Pb1
  unsigned short* Pb2 = (unsigned short*)alloc((size_t)N * 128 * 2);
  float* csr_ew  = (float*)alloc((size_t)E * 4);
  float* w_gcn   = (float*)alloc((size_t)E * 4);
  float* w_cheb  = (float*)alloc((size_t)E * 4);
  int*   csr_src = (int*)  alloc((size_t)E * 4);
  int*   row_ptr = (int*)  alloc((size_t)(N + 1) * 4);
  int*   cursor  = (int*)  alloc((size_t)N * 4);
  int*   cnt     = (int*)  alloc((size_t)N * 4);
  int*   bsum    = (int*)  alloc((size_t)1024 * 4);
  float* dis1    = (float*)alloc((size_t)N * 4);
  float* dis2    = (float*)alloc((size_t)N * 4);
  float* invw    = (float*)alloc((size_t)N * 4);
  float* pbuf    = (float*)alloc((size_t)N * 4);
  float* wrbuf   = (float*)alloc((size_t)N * 4);
  short* W1t_h   = (short*)alloc((size_t)512 * 256 * 2);
  short* W1t_l   = (short*)alloc((size_t)512 * 256 * 2);
  short* Wct_h   = (short*)alloc((size_t)6 * 256 * 128 * 2);
  short* Wct_l   = (short*)alloc((size_t)6 * 256 * 128 * 2);
  int*   flag    = (int*)  alloc(256);
  float* P0 = PP;
  float* P1 = PP + (size_t)N * 128;
  unsigned short* Pb0 = h0b;
  unsigned short* Pb1 = h0b + (size_t)N * 128;

  hipMemsetAsync(cnt, 0, (size_t)N * 4, stream);
  hipMemsetAsync(flag, 0, 4, stream);

  k_detect<<<16, 256, 0, stream>>>((const int*)ei, E, flag);
  k_count<<<ceil_div(E, 256), 256, 0, stream>>>(ei, E, flag, cnt);
  int nb = ceil_div(N, 1024);
  k_scan_part<<<nb, 256, 0, stream>>>(cnt, bsum, N);
  k_scan_bsum<<<1, 1024, 0, stream>>>(bsum, nb);
  k_scan_write<<<nb, 256, 0, stream>>>(cnt, bsum, row_ptr, cursor, N, E);
  k_fill<<<ceil_div(E, 256), 256, 0, stream>>>(ei, ew, E, flag, cursor, csr_src, csr_ew);
  k_degrees<<<ceil_div(N, 256), 256, 0, stream>>>(row_ptr, csr_ew, dis1, dis2, invw, N);
  k_norm<<<ceil_div(E, 256), 256, 0, stream>>>(csr_src, csr_ew, dis1, dis2, w_gcn, w_cheb, E);

  // weight prep (transpose + bf16 split)
  k_prep_w<<<ceil_div(512 * 256, 256), 256, 0, stream>>>(W1, W1t_h, W1t_l, 512, 256);
  for (int k = 0; k < 6; ++k)
    k_prep_w<<<ceil_div(256 * 128, 256), 256, 0, stream>>>(Wc + (size_t)k * 256 * 128,
        Wct_h + (size_t)k * 256 * 128, Wct_l + (size_t)k * 256 * 128, 256, 128);

  // ---- GCNConv: h0b = bf16(x@W1); h1 = relu(agg + b1) ----
  k_gemm_mfma<<<dim3(ceil_div(N, 128), 2), 256, 0, stream>>>(x, W1t_h, W1t_l, nullptr, 0.f, nullptr, h0b, N, 256, 512);
  k_gcn_agg<<<ceil_div(N, 4), 256, 0, stream>>>(h0b, csr_src, w_gcn, row_ptr, dis1, b1, h1, N);

  // ---- ChebConv via Clenshaw (width 128), bf16 gathers ----
  auto gemm2 = [&](int k, float* dst, unsigned short* dstb, const float* Dm, float ds){
    k_gemm_mfma<<<dim3(ceil_div(N, 128), 1), 256, 0, stream>>>(h1,
        Wct_h + (size_t)k * 256 * 128, Wct_l + (size_t)k * 256 * 128, Dm, ds, dst, dstb, N, 128, 256);
  };
  auto spmm = [&](float* dst, unsigned short* dstb, const unsigned short* srcb, float coef){
    k_cheb_spmm<<<ceil_div(N, 4), 256, 0, stream>>>(srcb, dst, dstb, csr_src, w_cheb, row_ptr, dis2, coef, N);
  };
  gemm2(5, P0, Pb0, nullptr, 0.f);                                  // b5 = C5
  gemm2(4, P1, nullptr, nullptr, 0.f); spmm(P1, Pb1, Pb0, -2.f);    // b4 = C4 + 2L b5
  gemm2(3, P2, nullptr, P0, -1.f);     spmm(P2, Pb2, Pb1, -2.f);    // b3 = C3 - b5 + 2L b4
  gemm2(2, P0, nullptr, P1, -1.f);     spmm(P0, Pb0, Pb2, -2.f);    // b2 = C2 - b4 + 2L b3
  gemm2(1, P1, nullptr, P2, -1.f);     spmm(P1, Pb1, Pb0, -2.f);    // b1 = C1 - b3 + 2L b2
  gemm2(0, P2, nullptr, P0, -1.f);     spmm(P2, nullptr, Pb1, -1.f);// res = C0 - b2 + L b1

  // ---- epilogue ----
  float* out  = (float*)d_out;
  float* feat = out + N;
  k_feat<<<ceil_div(N, 4), 256, 0, stream>>>(P2, bc, W_out, W_root, feat, pbuf, wrbuf, N);
  k_out<<<ceil_div(N, 256), 256, 0, stream>>>(pbuf, wrbuf, invw, csr_src, row_ptr, b3, out, N);
}

// Round 7
// 1127.328 us; speedup vs baseline: 1.8728x; 1.2495x over previous
//
#include <hip/hip_runtime.h>
#include <cstdint>
#include <cstddef>

typedef __attribute__((ext_vector_type(8))) short bf16x8;
typedef __attribute__((ext_vector_type(4))) float f32x4;

static inline int ceil_div(int a, int b){ return (a + b - 1) / b; }

struct HL { short h, l; };
__device__ inline HL split2(float a){
  unsigned u = __float_as_uint(a);
  unsigned hb = (u + 0x8000u) & 0xFFFF0000u;
  float r = a - __uint_as_float(hb);
  HL o;
  o.h = (short)(hb >> 16);
  o.l = (short)((__float_as_uint(r) + 0x8000u) >> 16);
  return o;
}

__device__ inline unsigned short f2b(float f){            // fp32 -> bf16 (RNE)
  unsigned u = __float_as_uint(f);
  unsigned r = u + 0x7FFFu + ((u >> 16) & 1u);
  return (unsigned short)(r >> 16);
}
__device__ inline float b2f(unsigned short s){
  return __uint_as_float((unsigned)s << 16);
}

// ---------------- dtype detection (int64 vs int32 edge_index) ----------------
__global__ __launch_bounds__(256) void k_detect(const int* __restrict__ ei32, int E, int* __restrict__ flag){
  int t = blockIdx.x * 256 + threadIdx.x;
  if (t < 4096) {
    long long idx = 2LL * t + 1;
    if (idx < 2LL * E && ei32[idx] != 0) atomicOr(flag, 1);
  }
}

// ---------------- CSR build ----------------
__global__ __launch_bounds__(256) void k_count(const void* __restrict__ ei, int E,
                                               const int* __restrict__ flag, int* __restrict__ cnt){
  int e = blockIdx.x * 256 + threadIdx.x;
  if (e >= E) return;
  int dst = (*flag) ? ((const int*)ei)[(size_t)E + e]
                    : (int)((const long long*)ei)[(size_t)E + e];
  atomicAdd(&cnt[dst], 1);
}

// ---- 3-pass device-wide exclusive scan over cnt[N] -> row_ptr (+cursor copy) ----
__global__ __launch_bounds__(256) void k_scan_part(const int* __restrict__ cnt, int* __restrict__ bsum, int N){
  int base = blockIdx.x * 1024 + threadIdx.x * 4;
  int s = 0;
  if (base + 4 <= N){
    int4 v = *(const int4*)(cnt + base);
    s = v.x + v.y + v.z + v.w;
  } else {
    for (int i = base; i < N; ++i) s += cnt[i];
  }
#pragma unroll
  for (int off = 32; off; off >>= 1) s += __shfl_xor(s, off);
  __shared__ int ws[4];
  if ((threadIdx.x & 63) == 0) ws[threadIdx.x >> 6] = s;
  __syncthreads();
  if (threadIdx.x == 0) bsum[blockIdx.x] = ws[0] + ws[1] + ws[2] + ws[3];
}

__global__ __launch_bounds__(1024) void k_scan_bsum(int* __restrict__ bsum, int nb){
  __shared__ int sh[1024];
  int t = threadIdx.x;
  int v = (t < nb) ? bsum[t] : 0;
  sh[t] = v; __syncthreads();
  for (int off = 1; off < 1024; off <<= 1){
    int u = (t >= off) ? sh[t - off] : 0;
    __syncthreads();
    sh[t] += u;
    __syncthreads();
  }
  if (t < nb) bsum[t] = sh[t] - v;   // exclusive
}

__global__ __launch_bounds__(256) void k_scan_write(const int* __restrict__ cnt, const int* __restrict__ bsum,
                                                    int* __restrict__ row_ptr, int* __restrict__ cursor,
                                                    int N, int E){
  int t = threadIdx.x;
  int base = blockIdx.x * 1024 + t * 4;
  int v0 = 0, v1 = 0, v2 = 0, v3 = 0;
  if (base + 4 <= N){
    int4 v = *(const int4*)(cnt + base);
    v0 = v.x; v1 = v.y; v2 = v.z; v3 = v.w;
  } else {
    if (base + 0 < N) v0 = cnt[base + 0];
    if (base + 1 < N) v1 = cnt[base + 1];
    if (base + 2 < N) v2 = cnt[base + 2];
    if (base + 3 < N) v3 = cnt[base + 3];
  }
  int s = v0 + v1 + v2 + v3;
  int lane = t & 63;
  int inc = s;
#pragma unroll
  for (int off = 1; off < 64; off <<= 1){
    int u = __shfl_up(inc, off);
    if (lane >= off) inc += u;
  }
  __shared__ int ws[4];
  if (lane == 63) ws[t >> 6] = inc;
  __syncthreads();
  int wid = t >> 6;
  int woff = 0;
  for (int i = 0; i < wid; ++i) woff += ws[i];
  int exc = bsum[blockIdx.x] + woff + inc - s;
  int p0 = exc, p1 = p0 + v0, p2 = p1 + v1, p3 = p2 + v2;
  if (base + 0 < N){ row_ptr[base + 0] = p0; cursor[base + 0] = p0; }
  if (base + 1 < N){ row_ptr[base + 1] = p1; cursor[base + 1] = p1; }
  if (base + 2 < N){ row_ptr[base + 2] = p2; cursor[base + 2] = p2; }
  if (base + 3 < N){ row_ptr[base + 3] = p3; cursor[base + 3] = p3; }
  if (blockIdx.x == 0 && t == 0) row_ptr[N] = E;
}

__global__ __launch_bounds__(256) void k_fill(const void* __restrict__ ei, const float* __restrict__ ew, int E,
                                              const int* __restrict__ flag, int* __restrict__ cursor,
                                              int* __restrict__ csr_src, float* __restrict__ csr_ew){
  int e = blockIdx.x * 256 + threadIdx.x;
  if (e >= E) return;
  int src, dst;
  if (*flag){ src = ((const int*)ei)[e]; dst = ((const int*)ei)[(size_t)E + e]; }
  else      { src = (int)((const long long*)ei)[e]; dst = (int)((const long long*)ei)[(size_t)E + e]; }
  int pos = atomicAdd(&cursor[dst], 1);
  csr_src[pos] = src;
  csr_ew[pos] = ew[e];
}

__global__ __launch_bounds__(256) void k_degrees(const int* __restrict__ row_ptr, const float* __restrict__ csr_ew,
                                                 float* __restrict__ dis1, float* __restrict__ dis2,
                                                 float* __restrict__ invw, int N){
  int r = blockIdx.x * 256 + threadIdx.x;
  if (r >= N) return;
  int e0 = row_ptr[r], e1 = row_ptr[r + 1];
  float s = 0.f;
  for (int e = e0; e < e1; ++e) s += csr_ew[e];
  dis1[r] = rsqrtf(s + 1.0f);
  dis2[r] = (s > 0.0f) ? rsqrtf(s) : 0.0f;
  invw[r] = 1.0f / (float)(e1 - e0 + 1);
}

// ---------------- edge norms ----------------
__global__ __launch_bounds__(256) void k_norm(const int* __restrict__ csr_src, const float* __restrict__ csr_ew,
                                              const float* __restrict__ dis1, const float* __restrict__ dis2,
                                              float* __restrict__ w_gcn, float* __restrict__ w_cheb, int E){
  int e = blockIdx.x * 256 + threadIdx.x;
  if (e >= E) return;
  int s = csr_src[e];
  float w = csr_ew[e];
  w_gcn[e]  = w * dis1[s];
  w_cheb[e] = w * dis2[s];
}

// ---------------- weight prep: W [K][N] fp32 -> Wh/Wl [N][K] bf16 split ----------------
__global__ __launch_bounds__(256) void k_prep_w(const float* __restrict__ W, short* __restrict__ Wh,
                                                short* __restrict__ Wl, int K, int N){
  int idx = blockIdx.x * 256 + threadIdx.x;
  if (idx >= K * N) return;
  int n = idx / K, k = idx - n * K;
  HL s = split2(W[(size_t)k * N + n]);
  Wh[idx] = s.h; Wl[idx] = s.l;
}

// ---------------- Wc prep: Wc [6][256][128] -> [768][256] bf16 split (n = kk*128 + c) ------
__global__ __launch_bounds__(256) void k_prep_wc(const float* __restrict__ Wc, short* __restrict__ Wh,
                                                 short* __restrict__ Wl){
  int idx = blockIdx.x * 256 + threadIdx.x;
  if (idx >= 768 * 256) return;
  int n = idx >> 8, k = idx & 255;
  HL s = split2(Wc[(size_t)(n >> 7) * 256 * 128 + (size_t)k * 128 + (n & 127)]);
  Wh[idx] = s.h; Wl[idx] = s.l;
}

// ---------------- MFMA GEMM 1: A fp32 (on-the-fly split), writes bf16 shadow only ----------------
__global__ __launch_bounds__(256) void k_gemm_mfma(
    const float* __restrict__ A,
    const short* __restrict__ Bh, const short* __restrict__ Bl,
    unsigned short* __restrict__ Cb,
    int M, int Ncols, int K)
{
  __shared__ short Ah[128][40];
  __shared__ short Al[128][40];
  __shared__ short Bhs[128][40];
  __shared__ short Bls[128][40];
  int m0 = blockIdx.x * 128, n0 = blockIdx.y * 128;
  int t = threadIdx.x;
  int lane = t & 63, wid = t >> 6;
  int wr = wid >> 1, wc = wid & 1;
  int fr = lane & 15, fq = lane >> 4;
  int srow = t >> 1, skh = (t & 1) << 4;

  f32x4 acc[4][4];
#pragma unroll
  for (int i = 0; i < 4; ++i)
#pragma unroll
    for (int j = 0; j < 4; ++j) acc[i][j] = (f32x4){0.f, 0.f, 0.f, 0.f};

  bool aval = (m0 + srow) < M;
  const float* Aptr = A + (size_t)(m0 + srow) * K + skh;
  const short* Bhp = Bh + (size_t)(n0 + srow) * K + skh;
  const short* Blp = Bl + (size_t)(n0 + srow) * K + skh;

  for (int k0 = 0; k0 < K; k0 += 32){
    __syncthreads();
    float av[16];
    if (aval){
      const float4* ap = (const float4*)(Aptr + k0);
      float4 a0 = ap[0], a1 = ap[1], a2 = ap[2], a3 = ap[3];
      av[0]=a0.x; av[1]=a0.y; av[2]=a0.z; av[3]=a0.w;
      av[4]=a1.x; av[5]=a1.y; av[6]=a1.z; av[7]=a1.w;
      av[8]=a2.x; av[9]=a2.y; av[10]=a2.z; av[11]=a2.w;
      av[12]=a3.x; av[13]=a3.y; av[14]=a3.z; av[15]=a3.w;
    } else {
#pragma unroll
      for (int i = 0; i < 16; ++i) av[i] = 0.f;
    }
    bf16x8 h0, h1, l0, l1;
#pragma unroll
    for (int i = 0; i < 8; ++i){
      HL s = split2(av[i]);
      h0[i] = s.h; l0[i] = s.l;
    }
#pragma unroll
    for (int i = 0; i < 8; ++i){
      HL s = split2(av[8 + i]);
      h1[i] = s.h; l1[i] = s.l;
    }
    *(bf16x8*)&Ah[srow][skh]     = h0;
    *(bf16x8*)&Ah[srow][skh + 8] = h1;
    *(bf16x8*)&Al[srow][skh]     = l0;
    *(bf16x8*)&Al[srow][skh + 8] = l1;
    {
      const bf16x8* bp = (const bf16x8*)(Bhp + k0);
      *(bf16x8*)&Bhs[srow][skh]     = bp[0];
      *(bf16x8*)&Bhs[srow][skh + 8] = bp[1];
      const bf16x8* cp = (const bf16x8*)(Blp + k0);
      *(bf16x8*)&Bls[srow][skh]     = cp[0];
      *(bf16x8*)&Bls[srow][skh + 8] = cp[1];
    }
    __syncthreads();
    bf16x8 afh[4], afl[4], bfh[4], bfl[4];
#pragma unroll
    for (int m = 0; m < 4; ++m){
      int r = wr * 64 + m * 16 + fr;
      afh[m] = *(const bf16x8*)&Ah[r][fq * 8];
      afl[m] = *(const bf16x8*)&Al[r][fq * 8];
    }
#pragma unroll
    for (int n = 0; n < 4; ++n){
      int r = wc * 64 + n * 16 + fr;
      bfh[n] = *(const bf16x8*)&Bhs[r][fq * 8];
      bfl[n] = *(const bf16x8*)&Bls[r][fq * 8];
    }
#pragma unroll
    for (int m = 0; m < 4; ++m)
#pragma unroll
      for (int n = 0; n < 4; ++n){
        acc[m][n] = __builtin_amdgcn_mfma_f32_16x16x32_bf16(afh[m], bfh[n], acc[m][n], 0, 0, 0);
        acc[m][n] = __builtin_amdgcn_mfma_f32_16x16x32_bf16(afl[m], bfh[n], acc[m][n], 0, 0, 0);
        acc[m][n] = __builtin_amdgcn_mfma_f32_16x16x32_bf16(afh[m], bfl[n], acc[m][n], 0, 0, 0);
      }
  }
#pragma unroll
  for (int m = 0; m < 4; ++m){
#pragma unroll
    for (int n = 0; n < 4; ++n){
      int col = n0 + wc * 64 + n * 16 + fr;
#pragma unroll
      for (int r = 0; r < 4; ++r){
        int row = m0 + wr * 64 + m * 16 + fq * 4 + r;
        if (row < M){
          Cb[(size_t)row * Ncols + col] = f2b(acc[m][n][r]);
        }
      }
    }
  }
}

// ---------------- MFMA GEMM 2: A pre-split bf16 pair, B pre-split; writes bf16 C only -------
__global__ __launch_bounds__(256) void k_gemm_mfma2(
    const unsigned short* __restrict__ Ahg, const unsigned short* __restrict__ Alg,
    const short* __restrict__ Bh, const short* __restrict__ Bl,
    unsigned short* __restrict__ Cb,
    int M, int Ncols, int K)
{
  __shared__ short Ah[128][40];
  __shared__ short Al[128][40];
  __shared__ short Bhs[128][40];
  __shared__ short Bls[128][40];
  int m0 = blockIdx.x * 128, n0 = blockIdx.y * 128;
  int t = threadIdx.x;
  int lane = t & 63, wid = t >> 6;
  int wr = wid >> 1, wc = wid & 1;
  int fr = lane & 15, fq = lane >> 4;
  int srow = t >> 1, skh = (t & 1) << 4;

  f32x4 acc[4][4];
#pragma unroll
  for (int i = 0; i < 4; ++i)
#pragma unroll
    for (int j = 0; j < 4; ++j) acc[i][j] = (f32x4){0.f, 0.f, 0.f, 0.f};

  bool aval = (m0 + srow) < M;
  const unsigned short* Ahp = Ahg + (size_t)(m0 + srow) * K + skh;
  const unsigned short* Alp = Alg + (size_t)(m0 + srow) * K + skh;
  const short* Bhp = Bh + (size_t)(n0 + srow) * K + skh;
  const short* Blp = Bl + (size_t)(n0 + srow) * K + skh;

  for (int k0 = 0; k0 < K; k0 += 32){
    __syncthreads();
    if (aval){
      const bf16x8* ah = (const bf16x8*)(Ahp + k0);
      *(bf16x8*)&Ah[srow][skh]     = ah[0];
      *(bf16x8*)&Ah[srow][skh + 8] = ah[1];
      const bf16x8* al = (const bf16x8*)(Alp + k0);
      *(bf16x8*)&Al[srow][skh]     = al[0];
      *(bf16x8*)&Al[srow][skh + 8] = al[1];
    } else {
      bf16x8 z = (bf16x8){0,0,0,0,0,0,0,0};
      *(bf16x8*)&Ah[srow][skh] = z; *(bf16x8*)&Ah[srow][skh + 8] = z;
      *(bf16x8*)&Al[srow][skh] = z; *(bf16x8*)&Al[srow][skh + 8] = z;
    }
    {
      const bf16x8* bp = (const bf16x8*)(Bhp + k0);
      *(bf16x8*)&Bhs[srow][skh]     = bp[0];
      *(bf16x8*)&Bhs[srow][skh + 8] = bp[1];
      const bf16x8* cp = (const bf16x8*)(Blp + k0);
      *(bf16x8*)&Bls[srow][skh]     = cp[0];
      *(bf16x8*)&Bls[srow][skh + 8] = cp[1];
    }
    __syncthreads();
    bf16x8 afh[4], afl[4], bfh[4], bfl[4];
#pragma unroll
    for (int m = 0; m < 4; ++m){
      int r = wr * 64 + m * 16 + fr;
      afh[m] = *(const bf16x8*)&Ah[r][fq * 8];
      afl[m] = *(const bf16x8*)&Al[r][fq * 8];
    }
#pragma unroll
    for (int n = 0; n < 4; ++n){
      int r = wc * 64 + n * 16 + fr;
      bfh[n] = *(const bf16x8*)&Bhs[r][fq * 8];
      bfl[n] = *(const bf16x8*)&Bls[r][fq * 8];
    }
#pragma unroll
    for (int m = 0; m < 4; ++m)
#pragma unroll
      for (int n = 0; n < 4; ++n){
        acc[m][n] = __builtin_amdgcn_mfma_f32_16x16x32_bf16(afh[m], bfh[n], acc[m][n], 0, 0, 0);
        acc[m][n] = __builtin_amdgcn_mfma_f32_16x16x32_bf16(afl[m], bfh[n], acc[m][n], 0, 0, 0);
        acc[m][n] = __builtin_amdgcn_mfma_f32_16x16x32_bf16(afh[m], bfl[n], acc[m][n], 0, 0, 0);
      }
  }
#pragma unroll
  for (int m = 0; m < 4; ++m){
#pragma unroll
    for (int n = 0; n < 4; ++n){
      int col = n0 + wc * 64 + n * 16 + fr;
#pragma unroll
      for (int r = 0; r < 4; ++r){
        int row = m0 + wr * 64 + m * 16 + fq * 4 + r;
        if (row < M){
          Cb[(size_t)row * Ncols + col] = f2b(acc[m][n][r]);
        }
      }
    }
  }
}

// ---------------- GCN aggregation: bf16 gathers, writes h1 as bf16 hi/lo split pair ----------------
__global__ __launch_bounds__(256) void k_gcn_agg(
    const unsigned short* __restrict__ h0b,
    const int* __restrict__ csr_src, const float* __restrict__ w_gcn,
    const int* __restrict__ row_ptr, const float* __restrict__ dis1,
    const float* __restrict__ b1,
    unsigned short* __restrict__ h1h, unsigned short* __restrict__ h1l, int N){
  int lane = threadIdx.x & 63;
  int r = blockIdx.x * 4 + (threadIdx.x >> 6);
  if (r >= N) return;
  float dr = dis1[r];
  ushort4 sv = ((const ushort4*)(h0b + (size_t)r * 256))[lane];
  float4 inner = make_float4(b2f(sv.x) * dr, b2f(sv.y) * dr, b2f(sv.z) * dr, b2f(sv.w) * dr);
  int e0 = row_ptr[r], e1 = row_ptr[r + 1];
  int e = e0;
  for (; e + 4 <= e1; e += 4){
    int s0 = csr_src[e], s1 = csr_src[e+1], s2 = csr_src[e+2], s3 = csr_src[e+3];
    float w0 = w_gcn[e], w1 = w_gcn[e+1], w2 = w_gcn[e+2], w3 = w_gcn[e+3];
    ushort4 v0 = ((const ushort4*)(h0b + (size_t)s0 * 256))[lane];
    ushort4 v1 = ((const ushort4*)(h0b + (size_t)s1 * 256))[lane];
    ushort4 v2 = ((const ushort4*)(h0b + (size_t)s2 * 256))[lane];
    ushort4 v3 = ((const ushort4*)(h0b + (size_t)s3 * 256))[lane];
    inner.x = fmaf(w0, b2f(v0.x), inner.x); inner.y = fmaf(w0, b2f(v0.y), inner.y);
    inner.z = fmaf(w0, b2f(v0.z), inner.z); inner.w = fmaf(w0, b2f(v0.w), inner.w);
    inner.x = fmaf(w1, b2f(v1.x), inner.x); inner.y = fmaf(w1, b2f(v1.y), inner.y);
    inner.z = fmaf(w1, b2f(v1.z), inner.z); inner.w = fmaf(w1, b2f(v1.w), inner.w);
    inner.x = fmaf(w2, b2f(v2.x), inner.x); inner.y = fmaf(w2, b2f(v2.y), inner.y);
    inner.z = fmaf(w2, b2f(v2.z), inner.z); inner.w = fmaf(w2, b2f(v2.w), inner.w);
    inner.x = fmaf(w3, b2f(v3.x), inner.x); inner.y = fmaf(w3, b2f(v3.y), inner.y);
    inner.z = fmaf(w3, b2f(v3.z), inner.z); inner.w = fmaf(w3, b2f(v3.w), inner.w);
  }
  for (; e < e1; ++e){
    int s = csr_src[e];
    float w = w_gcn[e];
    ushort4 v = ((const ushort4*)(h0b + (size_t)s * 256))[lane];
    inner.x = fmaf(w, b2f(v.x), inner.x); inner.y = fmaf(w, b2f(v.y), inner.y);
    inner.z = fmaf(w, b2f(v.z), inner.z); inner.w = fmaf(w, b2f(v.w), inner.w);
  }
  float4 bb = ((const float4*)b1)[lane];
  float4 o;
  o.x = fmaxf(fmaf(inner.x, dr, bb.x), 0.f);
  o.y = fmaxf(fmaf(inner.y, dr, bb.y), 0.f);
  o.z = fmaxf(fmaf(inner.z, dr, bb.z), 0.f);
  o.w = fmaxf(fmaf(inner.w, dr, bb.w), 0.f);
  HL sx = split2(o.x), sy = split2(o.y), sz = split2(o.z), sw = split2(o.w);
  ushort4 hi; hi.x = (unsigned short)sx.h; hi.y = (unsigned short)sy.h; hi.z = (unsigned short)sz.h; hi.w = (unsigned short)sw.h;
  ushort4 lo; lo.x = (unsigned short)sx.l; lo.y = (unsigned short)sy.l; lo.z = (unsigned short)sz.l; lo.w = (unsigned short)sw.l;
  ((ushort4*)(h1h + (size_t)r * 256))[lane] = hi;
  ((ushort4*)(h1l + (size_t)r * 256))[lane] = lo;
}

// ---------------- Cheb spmm v2: dst = Ck - sub + coef*dis2[r]*Σ w*src[s]  (all bf16 gathers) ----
__global__ __launch_bounds__(256) void k_cheb_spmm2(
    const unsigned short* __restrict__ Ck, int ckstride,
    const unsigned short* __restrict__ sub16, int substride,
    const float* __restrict__ subf,
    const unsigned short* __restrict__ srcb, int sstride,
    float* __restrict__ dst, unsigned short* __restrict__ dstb,
    const int* __restrict__ csr_src, const float* __restrict__ w_cheb,
    const int* __restrict__ row_ptr, const float* __restrict__ dis2, float coef, int N){
  int lane = threadIdx.x & 63;
  int r = blockIdx.x * 4 + (threadIdx.x >> 6);
  if (r >= N) return;
  float2 inner = make_float2(0.f, 0.f);
  int e0 = row_ptr[r], e1 = row_ptr[r + 1];
  int e = e0;
  for (; e + 4 <= e1; e += 4){
    int s0 = csr_src[e], s1 = csr_src[e+1], s2 = csr_src[e+2], s3 = csr_src[e+3];
    float w0 = w_cheb[e], w1 = w_cheb[e+1], w2 = w_cheb[e+2], w3 = w_cheb[e+3];
    unsigned v0 = ((const unsigned*)(srcb + (size_t)s0 * sstride))[lane];
    unsigned v1 = ((const unsigned*)(srcb + (size_t)s1 * sstride))[lane];
    unsigned v2 = ((const unsigned*)(srcb + (size_t)s2 * sstride))[lane];
    unsigned v3 = ((const unsigned*)(srcb + (size_t)s3 * sstride))[lane];
    inner.x = fmaf(w0, __uint_as_float(v0 << 16), inner.x);
    inner.y = fmaf(w0, __uint_as_float(v0 & 0xFFFF0000u), inner.y);
    inner.x = fmaf(w1, __uint_as_float(v1 << 16), inner.x);
    inner.y = fmaf(w1, __uint_as_float(v1 & 0xFFFF0000u), inner.y);
    inner.x = fmaf(w2, __uint_as_float(v2 << 16), inner.x);
    inner.y = fmaf(w2, __uint_as_float(v2 & 0xFFFF0000u), inner.y);
    inner.x = fmaf(w3, __uint_as_float(v3 << 16), inner.x);
    inner.y = fmaf(w3, __uint_as_float(v3 & 0xFFFF0000u), inner.y);
  }
  for (; e < e1; ++e){
    int s = csr_src[e];
    float w = w_cheb[e];
    unsigned v = ((const unsigned*)(srcb + (size_t)s * sstride))[lane];
    inner.x = fmaf(w, __uint_as_float(v << 16), inner.x);
    inner.y = fmaf(w, __uint_as_float(v & 0xFFFF0000u), inner.y);
  }
  float c = coef * dis2[r];
  unsigned ckv = ((const unsigned*)(Ck + (size_t)r * ckstride))[lane];
  float rx = fmaf(c, inner.x, __uint_as_float(ckv << 16));
  float ry = fmaf(c, inner.y, __uint_as_float(ckv & 0xFFFF0000u));
  if (sub16){
    unsigned sv = ((const unsigned*)(sub16 + (size_t)r * substride))[lane];
    rx -= __uint_as_float(sv << 16);
    ry -= __uint_as_float(sv & 0xFFFF0000u);
  }
  if (subf){
    float2 s2 = ((const float2*)(subf + (size_t)r * 128))[lane];
    rx -= s2.x;
    ry -= s2.y;
  }
  ((float2*)(dst + (size_t)r * 128))[lane] = make_float2(rx, ry);
  if (dstb){
    unsigned pk = (unsigned)f2b(rx) | ((unsigned)f2b(ry) << 16);
    ((unsigned*)(dstb + (size_t)r * 128))[lane] = pk;
  }
}

// ---------------- features epilogue ----------------
__global__ __launch_bounds__(256) void k_feat(const float* __restrict__ P, const float* __restrict__ bc,
    const float* __restrict__ W_out, const float* __restrict__ W_root,
    float* __restrict__ feat, float* __restrict__ p, float* __restrict__ wr, int N){
  int lane = threadIdx.x & 63;
  int r = blockIdx.x * 4 + (threadIdx.x >> 6);
  if (r >= N) return;
  float2 v = ((const float2*)(P + (size_t)r * 128))[lane];
  float2 bb = ((const float2*)bc)[lane];
  v.x = fmaxf(v.x + bb.x, 0.f);
  v.y = fmaxf(v.y + bb.y, 0.f);
  ((float2*)(feat + (size_t)r * 128))[lane] = v;
  float2 wo = ((const float2*)W_out)[lane];
  float2 wrt = ((const float2*)W_root)[lane];
  float pp = v.x * wo.x + v.y * wo.y;
  float rr = v.x * wrt.x + v.y * wrt.y;
#pragma unroll
  for (int off = 32; off; off >>= 1){
    pp += __shfl_xor(pp, off);
    rr += __shfl_xor(rr, off);
  }
  if (lane == 0){ p[r] = pp; wr[r] = rr; }
}

// ---------------- ClusterGCN output ----------------
__global__ __launch_bounds__(256) void k_out(const float* __restrict__ p, const float* __restrict__ wr,
    const float* __restrict__ invw, const int* __restrict__ csr_src, const int* __restrict__ row_ptr,
    const float* __restrict__ b3, float* __restrict__ out, int N){
  int r = blockIdx.x * 256 + threadIdx.x;
  if (r >= N) return;
  float s = p[r];
  int e0 = row_ptr[r], e1 = row_ptr[r + 1];
  int e = e0;
  float s0 = 0.f, s1 = 0.f, s2 = 0.f, s3 = 0.f;
  for (; e + 4 <= e1; e += 4){
    int a = csr_src[e], b = csr_src[e+1], c = csr_src[e+2], d = csr_src[e+3];
    s0 += p[a]; s1 += p[b]; s2 += p[c]; s3 += p[d];
  }
  for (; e < e1; ++e) s0 += p[csr_src[e]];
  s += s0 + s1 + s2 + s3;
  out[r] = invw[r] * s + wr[r] + b3[0];
}

extern "C" void kernel_launch(void* const* d_in, const int* in_sizes, int n_in,
                              void* d_out, int out_size, void* d_ws, size_t ws_size,
                              hipStream_t stream){
  const float* x      = (const float*)d_in[0];
  const void*  ei     = d_in[1];
  const float* ew     = (const float*)d_in[2];
  const float* W1     = (const float*)d_in[3];
  const float* b1     = (const float*)d_in[4];
  const float* Wc     = (const float*)d_in[5];
  const float* bc     = (const float*)d_in[6];
  const float* W_out  = (const float*)d_in[7];
  const float* W_root = (const float*)d_in[8];
  const float* b3     = (const float*)d_in[9];
  const int N = in_sizes[0] / 512;
  const int E = in_sizes[2];

  char* w = (char*)d_ws;
  auto alloc = [&](size_t bytes)->void*{ void* r = (void*)w; w += (bytes + 255) & ~(size_t)255; return r; };
  // h1 region (102.4 MB): first h1h|h1l bf16 split of GCN output; later B0|B1 fp32 Clenshaw
  unsigned short* h1h = (unsigned short*)alloc((size_t)N * 256 * 2 * 2);
  unsigned short* h1l = h1h + (size_t)N * 256;
  float* B0 = (float*)h1h;
  float* B1 = B0 + (size_t)N * 128;
  float* B2 = (float*)alloc((size_t)N * 128 * 4);
  unsigned short* CC  = (unsigned short*)alloc((size_t)N * 768 * 2);  // all 6 C_k, bf16
  unsigned short* h0b = (unsigned short*)alloc((size_t)N * 256 * 2);  // bf16 x@W1; later Bb0|Bb1
  unsigned short* Bb0 = h0b;
  unsigned short* Bb1 = h0b + (size_t)N * 128;
  float* csr_ew  = (float*)alloc((size_t)E * 4);
  float* w_gcn   = (float*)alloc((size_t)E * 4);
  float* w_cheb  = (float*)alloc((size_t)E * 4);
  int*   csr_src = (int*)  alloc((size_t)E * 4);
  int*   row_ptr = (int*)  alloc((size_t)(N + 1) * 4);
  int*   cursor  = (int*)  alloc((size_t)N * 4);
  int*   cnt     = (int*)  alloc((size_t)N * 4);
  int*   bsum    = (int*)  alloc((size_t)1024 * 4);
  float* dis1    = (float*)alloc((size_t)N * 4);
  float* dis2    = (float*)alloc((size_t)N * 4);
  float* invw    = (float*)alloc((size_t)N * 4);
  float* pbuf    = (float*)alloc((size_t)N * 4);
  float* wrbuf   = (float*)alloc((size_t)N * 4);
  short* W1t_h   = (short*)alloc((size_t)512 * 256 * 2);
  short* W1t_l   = (short*)alloc((size_t)512 * 256 * 2);
  short* Wct_h   = (short*)alloc((size_t)768 * 256 * 2);
  short* Wct_l   = (short*)alloc((size_t)768 * 256 * 2);
  int*   flag    = (int*)  alloc(256);

  hipMemsetAsync(cnt, 0, (size_t)N * 4, stream);
  hipMemsetAsync(flag, 0, 4, stream);

  k_detect<<<16, 256, 0, stream>>>((const int*)ei, E, flag);
  k_count<<<ceil_div(E, 256), 256, 0, stream>>>(ei, E, flag, cnt);
  int nb = ceil_div(N, 1024);
  k_scan_part<<<nb, 256, 0, stream>>>(cnt, bsum, N);
  k_scan_bsum<<<1, 1024, 0, stream>>>(bsum, nb);
  k_scan_write<<<nb, 256, 0, stream>>>(cnt, bsum, row_ptr, cursor, N, E);
  k_fill<<<ceil_div(E, 256), 256, 0, stream>>>(ei, ew, E, flag, cursor, csr_src, csr_ew);
  k_degrees<<<ceil_div(N, 256), 256, 0, stream>>>(row_ptr, csr_ew, dis1, dis2, invw, N);
  k_norm<<<ceil_div(E, 256), 256, 0, stream>>>(csr_src, csr_ew, dis1, dis2, w_gcn, w_cheb, E);

  // weight prep (transpose + bf16 split)
  k_prep_w<<<ceil_div(512 * 256, 256), 256, 0, stream>>>(W1, W1t_h, W1t_l, 512, 256);
  k_prep_wc<<<ceil_div(768 * 256, 256), 256, 0, stream>>>(Wc, Wct_h, Wct_l);

  // ---- GCNConv: h0b = bf16(x@W1); h1(hi/lo) = split(relu(agg + b1)) ----
  k_gemm_mfma<<<dim3(ceil_div(N, 128), 2), 256, 0, stream>>>(x, W1t_h, W1t_l, h0b, N, 256, 512);
  k_gcn_agg<<<ceil_div(N, 4), 256, 0, stream>>>(h0b, csr_src, w_gcn, row_ptr, dis1, b1, h1h, h1l, N);

  // ---- fused Cheb projection: CC[N][768] = bf16(h1 @ [Wc0|..|Wc5]) ----
  k_gemm_mfma2<<<dim3(ceil_div(N, 128), 6), 256, 0, stream>>>(h1h, h1l, Wct_h, Wct_l, CC, N, 768, 256);

  // ---- Clenshaw (width 128): b_k = C_k - b_{k+2} + 2L b_{k+1}  (L via coef=-2/-1) ----
  auto spmm = [&](const unsigned short* Ck, const unsigned short* s16, int s16s, const float* sf,
                  const unsigned short* src, int ss, float* dst, unsigned short* dstb, float coef){
    k_cheb_spmm2<<<ceil_div(N, 4), 256, 0, stream>>>(Ck, 768, s16, s16s, sf, src, ss, dst, dstb,
        csr_src, w_cheb, row_ptr, dis2, coef, N);
  };
  // b5 = CC5 (in place). b4 = C4 + 2L b5
  spmm(CC + 4*128, nullptr, 0, nullptr, CC + 5*128, 768, B0, Bb0, -2.f);
  // b3 = C3 - b5 + 2L b4
  spmm(CC + 3*128, CC + 5*128, 768, nullptr, Bb0, 128, B1, Bb1, -2.f);
  // b2 = C2 - b4 + 2L b3
  spmm(CC + 2*128, nullptr, 0, B0, Bb1, 128, B2, Bb0, -2.f);
  // b1 = C1 - b3 + 2L b2
  spmm(CC + 1*128, nullptr, 0, B1, Bb0, 128, B0, Bb1, -2.f);
  // res = C0 - b2 + L b1
  spmm(CC + 0*128, nullptr, 0, B2, Bb1, 128, B1, nullptr, -1.f);

  // ---- epilogue ----
  float* out  = (float*)d_out;
  float* feat = out + N;
  k_feat<<<ceil_div(N, 4), 256, 0, stream>>>(B1, bc, W_out, W_root, feat, pbuf, wrbuf, N);
  k_out<<<ceil_div(N, 256), 256, 0, stream>>>(pbuf, wrbuf, invw, csr_src, row_ptr, b3, out, N);
}

// Round 8
// 1103.986 us; speedup vs baseline: 1.9124x; 1.0211x over previous
//
#include <hip/hip_runtime.h>
#include <cstdint>
#include <cstddef>

typedef __attribute__((ext_vector_type(8))) short bf16x8;
typedef __attribute__((ext_vector_type(4))) float f32x4;

static inline int ceil_div(int a, int b){ return (a + b - 1) / b; }

struct HL { short h, l; };
__device__ inline HL split2(float a){
  unsigned u = __float_as_uint(a);
  unsigned hb = (u + 0x8000u) & 0xFFFF0000u;
  float r = a - __uint_as_float(hb);
  HL o;
  o.h = (short)(hb >> 16);
  o.l = (short)((__float_as_uint(r) + 0x8000u) >> 16);
  return o;
}

__device__ inline unsigned short f2b(float f){            // fp32 -> bf16 (RNE)
  unsigned u = __float_as_uint(f);
  unsigned r = u + 0x7FFFu + ((u >> 16) & 1u);
  return (unsigned short)(r >> 16);
}
__device__ inline float b2f(unsigned short s){
  return __uint_as_float((unsigned)s << 16);
}

// ---------------- dtype detection (int64 vs int32 edge_index) ----------------
__global__ __launch_bounds__(256) void k_detect(const int* __restrict__ ei32, int E, int* __restrict__ flag){
  int t = blockIdx.x * 256 + threadIdx.x;
  if (t < 4096) {
    long long idx = 2LL * t + 1;
    if (idx < 2LL * E && ei32[idx] != 0) atomicOr(flag, 1);
  }
}

// ---------------- CSR build ----------------
__global__ __launch_bounds__(256) void k_count(const void* __restrict__ ei, int E,
                                               const int* __restrict__ flag, int* __restrict__ cnt){
  int e = blockIdx.x * 256 + threadIdx.x;
  if (e >= E) return;
  int dst = (*flag) ? ((const int*)ei)[(size_t)E + e]
                    : (int)((const long long*)ei)[(size_t)E + e];
  atomicAdd(&cnt[dst], 1);
}

// ---- 3-pass device-wide exclusive scan over cnt[N] -> row_ptr (+cursor copy) ----
__global__ __launch_bounds__(256) void k_scan_part(const int* __restrict__ cnt, int* __restrict__ bsum, int N){
  int base = blockIdx.x * 1024 + threadIdx.x * 4;
  int s = 0;
  if (base + 4 <= N){
    int4 v = *(const int4*)(cnt + base);
    s = v.x + v.y + v.z + v.w;
  } else {
    for (int i = base; i < N; ++i) s += cnt[i];
  }
#pragma unroll
  for (int off = 32; off; off >>= 1) s += __shfl_xor(s, off);
  __shared__ int ws[4];
  if ((threadIdx.x & 63) == 0) ws[threadIdx.x >> 6] = s;
  __syncthreads();
  if (threadIdx.x == 0) bsum[blockIdx.x] = ws[0] + ws[1] + ws[2] + ws[3];
}

__global__ __launch_bounds__(1024) void k_scan_bsum(int* __restrict__ bsum, int nb){
  __shared__ int sh[1024];
  int t = threadIdx.x;
  int v = (t < nb) ? bsum[t] : 0;
  sh[t] = v; __syncthreads();
  for (int off = 1; off < 1024; off <<= 1){
    int u = (t >= off) ? sh[t - off] : 0;
    __syncthreads();
    sh[t] += u;
    __syncthreads();
  }
  if (t < nb) bsum[t] = sh[t] - v;   // exclusive
}

__global__ __launch_bounds__(256) void k_scan_write(const int* __restrict__ cnt, const int* __restrict__ bsum,
                                                    int* __restrict__ row_ptr, int* __restrict__ cursor,
                                                    int N, int E){
  int t = threadIdx.x;
  int base = blockIdx.x * 1024 + t * 4;
  int v0 = 0, v1 = 0, v2 = 0, v3 = 0;
  if (base + 4 <= N){
    int4 v = *(const int4*)(cnt + base);
    v0 = v.x; v1 = v.y; v2 = v.z; v3 = v.w;
  } else {
    if (base + 0 < N) v0 = cnt[base + 0];
    if (base + 1 < N) v1 = cnt[base + 1];
    if (base + 2 < N) v2 = cnt[base + 2];
    if (base + 3 < N) v3 = cnt[base + 3];
  }
  int s = v0 + v1 + v2 + v3;
  int lane = t & 63;
  int inc = s;
#pragma unroll
  for (int off = 1; off < 64; off <<= 1){
    int u = __shfl_up(inc, off);
    if (lane >= off) inc += u;
  }
  __shared__ int ws[4];
  if (lane == 63) ws[t >> 6] = inc;
  __syncthreads();
  int wid = t >> 6;
  int woff = 0;
  for (int i = 0; i < wid; ++i) woff += ws[i];
  int exc = bsum[blockIdx.x] + woff + inc - s;
  int p0 = exc, p1 = p0 + v0, p2 = p1 + v1, p3 = p2 + v2;
  if (base + 0 < N){ row_ptr[base + 0] = p0; cursor[base + 0] = p0; }
  if (base + 1 < N){ row_ptr[base + 1] = p1; cursor[base + 1] = p1; }
  if (base + 2 < N){ row_ptr[base + 2] = p2; cursor[base + 2] = p2; }
  if (base + 3 < N){ row_ptr[base + 3] = p3; cursor[base + 3] = p3; }
  if (blockIdx.x == 0 && t == 0) row_ptr[N] = E;
}

__global__ __launch_bounds__(256) void k_fill(const void* __restrict__ ei, const float* __restrict__ ew, int E,
                                              const int* __restrict__ flag, int* __restrict__ cursor,
                                              int* __restrict__ csr_src, float* __restrict__ csr_ew){
  int e = blockIdx.x * 256 + threadIdx.x;
  if (e >= E) return;
  int src, dst;
  if (*flag){ src = ((const int*)ei)[e]; dst = ((const int*)ei)[(size_t)E + e]; }
  else      { src = (int)((const long long*)ei)[e]; dst = (int)((const long long*)ei)[(size_t)E + e]; }
  int pos = atomicAdd(&cursor[dst], 1);
  csr_src[pos] = src;
  csr_ew[pos] = ew[e];
}

__global__ __launch_bounds__(256) void k_degrees(const int* __restrict__ row_ptr, const float* __restrict__ csr_ew,
                                                 float* __restrict__ dis1, float* __restrict__ dis2,
                                                 float* __restrict__ invw, int N){
  int r = blockIdx.x * 256 + threadIdx.x;
  if (r >= N) return;
  int e0 = row_ptr[r], e1 = row_ptr[r + 1];
  float s = 0.f;
  for (int e = e0; e < e1; ++e) s += csr_ew[e];
  dis1[r] = rsqrtf(s + 1.0f);
  dis2[r] = (s > 0.0f) ? rsqrtf(s) : 0.0f;
  invw[r] = 1.0f / (float)(e1 - e0 + 1);
}

// ---------------- edge norms ----------------
__global__ __launch_bounds__(256) void k_norm(const int* __restrict__ csr_src, const float* __restrict__ csr_ew,
                                              const float* __restrict__ dis1, const float* __restrict__ dis2,
                                              float* __restrict__ w_gcn, float* __restrict__ w_cheb, int E){
  int e = blockIdx.x * 256 + threadIdx.x;
  if (e >= E) return;
  int s = csr_src[e];
  float w = csr_ew[e];
  w_gcn[e]  = w * dis1[s];
  w_cheb[e] = w * dis2[s];
}

// ---------------- weight prep: W [K][N] fp32 -> Wh/Wl [N][K] bf16 split ----------------
__global__ __launch_bounds__(256) void k_prep_w(const float* __restrict__ W, short* __restrict__ Wh,
                                                short* __restrict__ Wl, int K, int N){
  int idx = blockIdx.x * 256 + threadIdx.x;
  if (idx >= K * N) return;
  int n = idx / K, k = idx - n * K;
  HL s = split2(W[(size_t)k * N + n]);
  Wh[idx] = s.h; Wl[idx] = s.l;
}

// ---------------- Wc prep: Wc [6][256][128] -> [768][256] bf16 split ----------------
__global__ __launch_bounds__(256) void k_prep_wc(const float* __restrict__ Wc, short* __restrict__ Wh,
                                                 short* __restrict__ Wl){
  int idx = blockIdx.x * 256 + threadIdx.x;
  if (idx >= 768 * 256) return;
  int n = idx >> 8, k = idx & 255;
  HL s = split2(Wc[(size_t)(n >> 7) * 256 * 128 + (size_t)k * 128 + (n & 127)]);
  Wh[idx] = s.h; Wl[idx] = s.l;
}

// ---------------- MFMA GEMM 1: A fp32 (on-the-fly split), writes bf16 shadow only ----------------
__global__ __launch_bounds__(256) void k_gemm_mfma(
    const float* __restrict__ A,
    const short* __restrict__ Bh, const short* __restrict__ Bl,
    unsigned short* __restrict__ Cb,
    int M, int Ncols, int K)
{
  __shared__ short Ah[128][40];
  __shared__ short Al[128][40];
  __shared__ short Bhs[128][40];
  __shared__ short Bls[128][40];
  int m0 = blockIdx.x * 128, n0 = blockIdx.y * 128;
  int t = threadIdx.x;
  int lane = t & 63, wid = t >> 6;
  int wr = wid >> 1, wc = wid & 1;
  int fr = lane & 15, fq = lane >> 4;
  int srow = t >> 1, skh = (t & 1) << 4;

  f32x4 acc[4][4];
#pragma unroll
  for (int i = 0; i < 4; ++i)
#pragma unroll
    for (int j = 0; j < 4; ++j) acc[i][j] = (f32x4){0.f, 0.f, 0.f, 0.f};

  bool aval = (m0 + srow) < M;
  const float* Aptr = A + (size_t)(m0 + srow) * K + skh;
  const short* Bhp = Bh + (size_t)(n0 + srow) * K + skh;
  const short* Blp = Bl + (size_t)(n0 + srow) * K + skh;

  for (int k0 = 0; k0 < K; k0 += 32){
    __syncthreads();
    float av[16];
    if (aval){
      const float4* ap = (const float4*)(Aptr + k0);
      float4 a0 = ap[0], a1 = ap[1], a2 = ap[2], a3 = ap[3];
      av[0]=a0.x; av[1]=a0.y; av[2]=a0.z; av[3]=a0.w;
      av[4]=a1.x; av[5]=a1.y; av[6]=a1.z; av[7]=a1.w;
      av[8]=a2.x; av[9]=a2.y; av[10]=a2.z; av[11]=a2.w;
      av[12]=a3.x; av[13]=a3.y; av[14]=a3.z; av[15]=a3.w;
    } else {
#pragma unroll
      for (int i = 0; i < 16; ++i) av[i] = 0.f;
    }
    bf16x8 h0, h1, l0, l1;
#pragma unroll
    for (int i = 0; i < 8; ++i){
      HL s = split2(av[i]);
      h0[i] = s.h; l0[i] = s.l;
    }
#pragma unroll
    for (int i = 0; i < 8; ++i){
      HL s = split2(av[8 + i]);
      h1[i] = s.h; l1[i] = s.l;
    }
    *(bf16x8*)&Ah[srow][skh]     = h0;
    *(bf16x8*)&Ah[srow][skh + 8] = h1;
    *(bf16x8*)&Al[srow][skh]     = l0;
    *(bf16x8*)&Al[srow][skh + 8] = l1;
    {
      const bf16x8* bp = (const bf16x8*)(Bhp + k0);
      *(bf16x8*)&Bhs[srow][skh]     = bp[0];
      *(bf16x8*)&Bhs[srow][skh + 8] = bp[1];
      const bf16x8* cp = (const bf16x8*)(Blp + k0);
      *(bf16x8*)&Bls[srow][skh]     = cp[0];
      *(bf16x8*)&Bls[srow][skh + 8] = cp[1];
    }
    __syncthreads();
    bf16x8 afh[4], afl[4], bfh[4], bfl[4];
#pragma unroll
    for (int m = 0; m < 4; ++m){
      int r = wr * 64 + m * 16 + fr;
      afh[m] = *(const bf16x8*)&Ah[r][fq * 8];
      afl[m] = *(const bf16x8*)&Al[r][fq * 8];
    }
#pragma unroll
    for (int n = 0; n < 4; ++n){
      int r = wc * 64 + n * 16 + fr;
      bfh[n] = *(const bf16x8*)&Bhs[r][fq * 8];
      bfl[n] = *(const bf16x8*)&Bls[r][fq * 8];
    }
#pragma unroll
    for (int m = 0; m < 4; ++m)
#pragma unroll
      for (int n = 0; n < 4; ++n){
        acc[m][n] = __builtin_amdgcn_mfma_f32_16x16x32_bf16(afh[m], bfh[n], acc[m][n], 0, 0, 0);
        acc[m][n] = __builtin_amdgcn_mfma_f32_16x16x32_bf16(afl[m], bfh[n], acc[m][n], 0, 0, 0);
        acc[m][n] = __builtin_amdgcn_mfma_f32_16x16x32_bf16(afh[m], bfl[n], acc[m][n], 0, 0, 0);
      }
  }
#pragma unroll
  for (int m = 0; m < 4; ++m){
#pragma unroll
    for (int n = 0; n < 4; ++n){
      int col = n0 + wc * 64 + n * 16 + fr;
#pragma unroll
      for (int r = 0; r < 4; ++r){
        int row = m0 + wr * 64 + m * 16 + fq * 4 + r;
        if (row < M){
          Cb[(size_t)row * Ncols + col] = f2b(acc[m][n][r]);
        }
      }
    }
  }
}

// ---------------- MFMA GEMM 2: A pre-split bf16 pair; grid = (n-tiles, m-tiles) for L2 A-reuse ----
__global__ __launch_bounds__(256) void k_gemm_mfma2(
    const unsigned short* __restrict__ Ahg, const unsigned short* __restrict__ Alg,
    const short* __restrict__ Bh, const short* __restrict__ Bl,
    unsigned short* __restrict__ Cb,
    int M, int Ncols, int K)
{
  __shared__ short Ah[128][40];
  __shared__ short Al[128][40];
  __shared__ short Bhs[128][40];
  __shared__ short Bls[128][40];
  int m0 = blockIdx.y * 128, n0 = blockIdx.x * 128;   // swapped: n-tiles vary fastest
  int t = threadIdx.x;
  int lane = t & 63, wid = t >> 6;
  int wr = wid >> 1, wc = wid & 1;
  int fr = lane & 15, fq = lane >> 4;
  int srow = t >> 1, skh = (t & 1) << 4;

  f32x4 acc[4][4];
#pragma unroll
  for (int i = 0; i < 4; ++i)
#pragma unroll
    for (int j = 0; j < 4; ++j) acc[i][j] = (f32x4){0.f, 0.f, 0.f, 0.f};

  bool aval = (m0 + srow) < M;
  const unsigned short* Ahp = Ahg + (size_t)(m0 + srow) * K + skh;
  const unsigned short* Alp = Alg + (size_t)(m0 + srow) * K + skh;
  const short* Bhp = Bh + (size_t)(n0 + srow) * K + skh;
  const short* Blp = Bl + (size_t)(n0 + srow) * K + skh;

  for (int k0 = 0; k0 < K; k0 += 32){
    __syncthreads();
    if (aval){
      const bf16x8* ah = (const bf16x8*)(Ahp + k0);
      *(bf16x8*)&Ah[srow][skh]     = ah[0];
      *(bf16x8*)&Ah[srow][skh + 8] = ah[1];
      const bf16x8* al = (const bf16x8*)(Alp + k0);
      *(bf16x8*)&Al[srow][skh]     = al[0];
      *(bf16x8*)&Al[srow][skh + 8] = al[1];
    } else {
      bf16x8 z = (bf16x8){0,0,0,0,0,0,0,0};
      *(bf16x8*)&Ah[srow][skh] = z; *(bf16x8*)&Ah[srow][skh + 8] = z;
      *(bf16x8*)&Al[srow][skh] = z; *(bf16x8*)&Al[srow][skh + 8] = z;
    }
    {
      const bf16x8* bp = (const bf16x8*)(Bhp + k0);
      *(bf16x8*)&Bhs[srow][skh]     = bp[0];
      *(bf16x8*)&Bhs[srow][skh + 8] = bp[1];
      const bf16x8* cp = (const bf16x8*)(Blp + k0);
      *(bf16x8*)&Bls[srow][skh]     = cp[0];
      *(bf16x8*)&Bls[srow][skh + 8] = cp[1];
    }
    __syncthreads();
    bf16x8 afh[4], afl[4], bfh[4], bfl[4];
#pragma unroll
    for (int m = 0; m < 4; ++m){
      int r = wr * 64 + m * 16 + fr;
      afh[m] = *(const bf16x8*)&Ah[r][fq * 8];
      afl[m] = *(const bf16x8*)&Al[r][fq * 8];
    }
#pragma unroll
    for (int n = 0; n < 4; ++n){
      int r = wc * 64 + n * 16 + fr;
      bfh[n] = *(const bf16x8*)&Bhs[r][fq * 8];
      bfl[n] = *(const bf16x8*)&Bls[r][fq * 8];
    }
#pragma unroll
    for (int m = 0; m < 4; ++m)
#pragma unroll
      for (int n = 0; n < 4; ++n){
        acc[m][n] = __builtin_amdgcn_mfma_f32_16x16x32_bf16(afh[m], bfh[n], acc[m][n], 0, 0, 0);
        acc[m][n] = __builtin_amdgcn_mfma_f32_16x16x32_bf16(afl[m], bfh[n], acc[m][n], 0, 0, 0);
        acc[m][n] = __builtin_amdgcn_mfma_f32_16x16x32_bf16(afh[m], bfl[n], acc[m][n], 0, 0, 0);
      }
  }
#pragma unroll
  for (int m = 0; m < 4; ++m){
#pragma unroll
    for (int n = 0; n < 4; ++n){
      int col = n0 + wc * 64 + n * 16 + fr;
#pragma unroll
      for (int r = 0; r < 4; ++r){
        int row = m0 + wr * 64 + m * 16 + fq * 4 + r;
        if (row < M){
          Cb[(size_t)row * Ncols + col] = f2b(acc[m][n][r]);
        }
      }
    }
  }
}

// ---------------- GCN aggregation: bf16 gathers, writes h1 as bf16 hi/lo split pair ----------------
__global__ __launch_bounds__(256) void k_gcn_agg(
    const unsigned short* __restrict__ h0b,
    const int* __restrict__ csr_src, const float* __restrict__ w_gcn,
    const int* __restrict__ row_ptr, const float* __restrict__ dis1,
    const float* __restrict__ b1,
    unsigned short* __restrict__ h1h, unsigned short* __restrict__ h1l, int N){
  int lane = threadIdx.x & 63;
  int r = blockIdx.x * 4 + (threadIdx.x >> 6);
  if (r >= N) return;
  float dr = dis1[r];
  ushort4 sv = ((const ushort4*)(h0b + (size_t)r * 256))[lane];
  float4 inner = make_float4(b2f(sv.x) * dr, b2f(sv.y) * dr, b2f(sv.z) * dr, b2f(sv.w) * dr);
  int e0 = row_ptr[r], e1 = row_ptr[r + 1];
  int e = e0;
  for (; e + 4 <= e1; e += 4){
    int s0 = csr_src[e], s1 = csr_src[e+1], s2 = csr_src[e+2], s3 = csr_src[e+3];
    float w0 = w_gcn[e], w1 = w_gcn[e+1], w2 = w_gcn[e+2], w3 = w_gcn[e+3];
    ushort4 v0 = ((const ushort4*)(h0b + (size_t)s0 * 256))[lane];
    ushort4 v1 = ((const ushort4*)(h0b + (size_t)s1 * 256))[lane];
    ushort4 v2 = ((const ushort4*)(h0b + (size_t)s2 * 256))[lane];
    ushort4 v3 = ((const ushort4*)(h0b + (size_t)s3 * 256))[lane];
    inner.x = fmaf(w0, b2f(v0.x), inner.x); inner.y = fmaf(w0, b2f(v0.y), inner.y);
    inner.z = fmaf(w0, b2f(v0.z), inner.z); inner.w = fmaf(w0, b2f(v0.w), inner.w);
    inner.x = fmaf(w1, b2f(v1.x), inner.x); inner.y = fmaf(w1, b2f(v1.y), inner.y);
    inner.z = fmaf(w1, b2f(v1.z), inner.z); inner.w = fmaf(w1, b2f(v1.w), inner.w);
    inner.x = fmaf(w2, b2f(v2.x), inner.x); inner.y = fmaf(w2, b2f(v2.y), inner.y);
    inner.z = fmaf(w2, b2f(v2.z), inner.z); inner.w = fmaf(w2, b2f(v2.w), inner.w);
    inner.x = fmaf(w3, b2f(v3.x), inner.x); inner.y = fmaf(w3, b2f(v3.y), inner.y);
    inner.z = fmaf(w3, b2f(v3.z), inner.z); inner.w = fmaf(w3, b2f(v3.w), inner.w);
  }
  for (; e < e1; ++e){
    int s = csr_src[e];
    float w = w_gcn[e];
    ushort4 v = ((const ushort4*)(h0b + (size_t)s * 256))[lane];
    inner.x = fmaf(w, b2f(v.x), inner.x); inner.y = fmaf(w, b2f(v.y), inner.y);
    inner.z = fmaf(w, b2f(v.z), inner.z); inner.w = fmaf(w, b2f(v.w), inner.w);
  }
  float4 bb = ((const float4*)b1)[lane];
  float4 o;
  o.x = fmaxf(fmaf(inner.x, dr, bb.x), 0.f);
  o.y = fmaxf(fmaf(inner.y, dr, bb.y), 0.f);
  o.z = fmaxf(fmaf(inner.z, dr, bb.z), 0.f);
  o.w = fmaxf(fmaf(inner.w, dr, bb.w), 0.f);
  HL sx = split2(o.x), sy = split2(o.y), sz = split2(o.z), sw = split2(o.w);
  ushort4 hi; hi.x = (unsigned short)sx.h; hi.y = (unsigned short)sy.h; hi.z = (unsigned short)sz.h; hi.w = (unsigned short)sw.h;
  ushort4 lo; lo.x = (unsigned short)sx.l; lo.y = (unsigned short)sy.l; lo.z = (unsigned short)sz.l; lo.w = (unsigned short)sw.l;
  ((ushort4*)(h1h + (size_t)r * 256))[lane] = hi;
  ((ushort4*)(h1l + (size_t)r * 256))[lane] = lo;
}

// ---------------- Cheb spmm v2: dst = Ck - sub + coef*dis2[r]*Σ w*src[s] ----------------
__global__ __launch_bounds__(256) void k_cheb_spmm2(
    const unsigned short* __restrict__ Ck, int ckstride,
    const unsigned short* __restrict__ sub16, int substride,
    const float* __restrict__ subf,
    const unsigned short* __restrict__ srcb, int sstride,
    float* __restrict__ dst, unsigned short* __restrict__ dstb,
    const int* __restrict__ csr_src, const float* __restrict__ w_cheb,
    const int* __restrict__ row_ptr, const float* __restrict__ dis2, float coef, int N){
  int lane = threadIdx.x & 63;
  int r = blockIdx.x * 4 + (threadIdx.x >> 6);
  if (r >= N) return;
  float2 inner = make_float2(0.f, 0.f);
  int e0 = row_ptr[r], e1 = row_ptr[r + 1];
  int e = e0;
  for (; e + 4 <= e1; e += 4){
    int s0 = csr_src[e], s1 = csr_src[e+1], s2 = csr_src[e+2], s3 = csr_src[e+3];
    float w0 = w_cheb[e], w1 = w_cheb[e+1], w2 = w_cheb[e+2], w3 = w_cheb[e+3];
    unsigned v0 = ((const unsigned*)(srcb + (size_t)s0 * sstride))[lane];
    unsigned v1 = ((const unsigned*)(srcb + (size_t)s1 * sstride))[lane];
    unsigned v2 = ((const unsigned*)(srcb + (size_t)s2 * sstride))[lane];
    unsigned v3 = ((const unsigned*)(srcb + (size_t)s3 * sstride))[lane];
    inner.x = fmaf(w0, __uint_as_float(v0 << 16), inner.x);
    inner.y = fmaf(w0, __uint_as_float(v0 & 0xFFFF0000u), inner.y);
    inner.x = fmaf(w1, __uint_as_float(v1 << 16), inner.x);
    inner.y = fmaf(w1, __uint_as_float(v1 & 0xFFFF0000u), inner.y);
    inner.x = fmaf(w2, __uint_as_float(v2 << 16), inner.x);
    inner.y = fmaf(w2, __uint_as_float(v2 & 0xFFFF0000u), inner.y);
    inner.x = fmaf(w3, __uint_as_float(v3 << 16), inner.x);
    inner.y = fmaf(w3, __uint_as_float(v3 & 0xFFFF0000u), inner.y);
  }
  for (; e < e1; ++e){
    int s = csr_src[e];
    float w = w_cheb[e];
    unsigned v = ((const unsigned*)(srcb + (size_t)s * sstride))[lane];
    inner.x = fmaf(w, __uint_as_float(v << 16), inner.x);
    inner.y = fmaf(w, __uint_as_float(v & 0xFFFF0000u), inner.y);
  }
  float c = coef * dis2[r];
  unsigned ckv = ((const unsigned*)(Ck + (size_t)r * ckstride))[lane];
  float rx = fmaf(c, inner.x, __uint_as_float(ckv << 16));
  float ry = fmaf(c, inner.y, __uint_as_float(ckv & 0xFFFF0000u));
  if (sub16){
    unsigned sv = ((const unsigned*)(sub16 + (size_t)r * substride))[lane];
    rx -= __uint_as_float(sv << 16);
    ry -= __uint_as_float(sv & 0xFFFF0000u);
  }
  if (subf){
    float2 s2 = ((const float2*)(subf + (size_t)r * 128))[lane];
    rx -= s2.x;
    ry -= s2.y;
  }
  ((float2*)(dst + (size_t)r * 128))[lane] = make_float2(rx, ry);
  if (dstb){
    unsigned pk = (unsigned)f2b(rx) | ((unsigned)f2b(ry) << 16);
    ((unsigned*)(dstb + (size_t)r * 128))[lane] = pk;
  }
}

// ---------------- final spmm fused with feat epilogue:
// res = C0 - sub + coef*L-gather; feat = relu(res+bc); p = feat.W_out; wr = feat.W_root ------
__global__ __launch_bounds__(256) void k_spmm_final(
    const unsigned short* __restrict__ Ck, int ckstride,
    const float* __restrict__ subf,
    const unsigned short* __restrict__ srcb, int sstride,
    const float* __restrict__ bc, const float* __restrict__ W_out, const float* __restrict__ W_root,
    float* __restrict__ feat, float* __restrict__ p, float* __restrict__ wr,
    const int* __restrict__ csr_src, const float* __restrict__ w_cheb,
    const int* __restrict__ row_ptr, const float* __restrict__ dis2, float coef, int N){
  int lane = threadIdx.x & 63;
  int r = blockIdx.x * 4 + (threadIdx.x >> 6);
  if (r >= N) return;
  float2 inner = make_float2(0.f, 0.f);
  int e0 = row_ptr[r], e1 = row_ptr[r + 1];
  int e = e0;
  for (; e + 4 <= e1; e += 4){
    int s0 = csr_src[e], s1 = csr_src[e+1], s2 = csr_src[e+2], s3 = csr_src[e+3];
    float w0 = w_cheb[e], w1 = w_cheb[e+1], w2 = w_cheb[e+2], w3 = w_cheb[e+3];
    unsigned v0 = ((const unsigned*)(srcb + (size_t)s0 * sstride))[lane];
    unsigned v1 = ((const unsigned*)(srcb + (size_t)s1 * sstride))[lane];
    unsigned v2 = ((const unsigned*)(srcb + (size_t)s2 * sstride))[lane];
    unsigned v3 = ((const unsigned*)(srcb + (size_t)s3 * sstride))[lane];
    inner.x = fmaf(w0, __uint_as_float(v0 << 16), inner.x);
    inner.y = fmaf(w0, __uint_as_float(v0 & 0xFFFF0000u), inner.y);
    inner.x = fmaf(w1, __uint_as_float(v1 << 16), inner.x);
    inner.y = fmaf(w1, __uint_as_float(v1 & 0xFFFF0000u), inner.y);
    inner.x = fmaf(w2, __uint_as_float(v2 << 16), inner.x);
    inner.y = fmaf(w2, __uint_as_float(v2 & 0xFFFF0000u), inner.y);
    inner.x = fmaf(w3, __uint_as_float(v3 << 16), inner.x);
    inner.y = fmaf(w3, __uint_as_float(v3 & 0xFFFF0000u), inner.y);
  }
  for (; e < e1; ++e){
    int s = csr_src[e];
    float w = w_cheb[e];
    unsigned v = ((const unsigned*)(srcb + (size_t)s * sstride))[lane];
    inner.x = fmaf(w, __uint_as_float(v << 16), inner.x);
    inner.y = fmaf(w, __uint_as_float(v & 0xFFFF0000u), inner.y);
  }
  float c = coef * dis2[r];
  unsigned ckv = ((const unsigned*)(Ck + (size_t)r * ckstride))[lane];
  float rx = fmaf(c, inner.x, __uint_as_float(ckv << 16));
  float ry = fmaf(c, inner.y, __uint_as_float(ckv & 0xFFFF0000u));
  float2 s2 = ((const float2*)(subf + (size_t)r * 128))[lane];
  rx -= s2.x;
  ry -= s2.y;
  float2 bb = ((const float2*)bc)[lane];
  rx = fmaxf(rx + bb.x, 0.f);
  ry = fmaxf(ry + bb.y, 0.f);
  ((float2*)(feat + (size_t)r * 128))[lane] = make_float2(rx, ry);
  float2 wo = ((const float2*)W_out)[lane];
  float2 wrt = ((const float2*)W_root)[lane];
  float pp = rx * wo.x + ry * wo.y;
  float rr = rx * wrt.x + ry * wrt.y;
#pragma unroll
  for (int off = 32; off; off >>= 1){
    pp += __shfl_xor(pp, off);
    rr += __shfl_xor(rr, off);
  }
  if (lane == 0){ p[r] = pp; wr[r] = rr; }
}

// ---------------- ClusterGCN output ----------------
__global__ __launch_bounds__(256) void k_out(const float* __restrict__ p, const float* __restrict__ wr,
    const float* __restrict__ invw, const int* __restrict__ csr_src, const int* __restrict__ row_ptr,
    const float* __restrict__ b3, float* __restrict__ out, int N){
  int r = blockIdx.x * 256 + threadIdx.x;
  if (r >= N) return;
  float s = p[r];
  int e0 = row_ptr[r], e1 = row_ptr[r + 1];
  int e = e0;
  float s0 = 0.f, s1 = 0.f, s2 = 0.f, s3 = 0.f;
  for (; e + 4 <= e1; e += 4){
    int a = csr_src[e], b = csr_src[e+1], c = csr_src[e+2], d = csr_src[e+3];
    s0 += p[a]; s1 += p[b]; s2 += p[c]; s3 += p[d];
  }
  for (; e < e1; ++e) s0 += p[csr_src[e]];
  s += s0 + s1 + s2 + s3;
  out[r] = invw[r] * s + wr[r] + b3[0];
}

extern "C" void kernel_launch(void* const* d_in, const int* in_sizes, int n_in,
                              void* d_out, int out_size, void* d_ws, size_t ws_size,
                              hipStream_t stream){
  const float* x      = (const float*)d_in[0];
  const void*  ei     = d_in[1];
  const float* ew     = (const float*)d_in[2];
  const float* W1     = (const float*)d_in[3];
  const float* b1     = (const float*)d_in[4];
  const float* Wc     = (const float*)d_in[5];
  const float* bc     = (const float*)d_in[6];
  const float* W_out  = (const float*)d_in[7];
  const float* W_root = (const float*)d_in[8];
  const float* b3     = (const float*)d_in[9];
  const int N = in_sizes[0] / 512;
  const int E = in_sizes[2];

  char* w = (char*)d_ws;
  auto alloc = [&](size_t bytes)->void*{ void* r = (void*)w; w += (bytes + 255) & ~(size_t)255; return r; };
  // h1 region (102.4 MB): first h1h|h1l bf16 split of GCN output; later B0|B1 fp32 Clenshaw
  unsigned short* h1h = (unsigned short*)alloc((size_t)N * 256 * 2 * 2);
  unsigned short* h1l = h1h + (size_t)N * 256;
  float* B0 = (float*)h1h;
  float* B1 = B0 + (size_t)N * 128;
  float* B2 = (float*)alloc((size_t)N * 128 * 4);
  unsigned short* CC  = (unsigned short*)alloc((size_t)N * 768 * 2);  // all 6 C_k, bf16
  unsigned short* h0b = (unsigned short*)alloc((size_t)N * 256 * 2);  // bf16 x@W1; later Bb0|Bb1
  unsigned short* Bb0 = h0b;
  unsigned short* Bb1 = h0b + (size_t)N * 128;
  float* csr_ew  = (float*)alloc((size_t)E * 4);
  float* w_gcn   = (float*)alloc((size_t)E * 4);
  float* w_cheb  = (float*)alloc((size_t)E * 4);
  int*   csr_src = (int*)  alloc((size_t)E * 4);
  int*   row_ptr = (int*)  alloc((size_t)(N + 1) * 4);
  int*   cursor  = (int*)  alloc((size_t)N * 4);
  int*   cnt     = (int*)  alloc((size_t)N * 4);
  int*   bsum    = (int*)  alloc((size_t)1024 * 4);
  float* dis1    = (float*)alloc((size_t)N * 4);
  float* dis2    = (float*)alloc((size_t)N * 4);
  float* invw    = (float*)alloc((size_t)N * 4);
  float* pbuf    = (float*)alloc((size_t)N * 4);
  float* wrbuf   = (float*)alloc((size_t)N * 4);
  short* W1t_h   = (short*)alloc((size_t)512 * 256 * 2);
  short* W1t_l   = (short*)alloc((size_t)512 * 256 * 2);
  short* Wct_h   = (short*)alloc((size_t)768 * 256 * 2);
  short* Wct_l   = (short*)alloc((size_t)768 * 256 * 2);
  int*   flag    = (int*)  alloc(256);

  hipMemsetAsync(cnt, 0, (size_t)N * 4, stream);
  hipMemsetAsync(flag, 0, 4, stream);

  k_detect<<<16, 256, 0, stream>>>((const int*)ei, E, flag);
  k_count<<<ceil_div(E, 256), 256, 0, stream>>>(ei, E, flag, cnt);
  int nb = ceil_div(N, 1024);
  k_scan_part<<<nb, 256, 0, stream>>>(cnt, bsum, N);
  k_scan_bsum<<<1, 1024, 0, stream>>>(bsum, nb);
  k_scan_write<<<nb, 256, 0, stream>>>(cnt, bsum, row_ptr, cursor, N, E);
  k_fill<<<ceil_div(E, 256), 256, 0, stream>>>(ei, ew, E, flag, cursor, csr_src, csr_ew);
  k_degrees<<<ceil_div(N, 256), 256, 0, stream>>>(row_ptr, csr_ew, dis1, dis2, invw, N);
  k_norm<<<ceil_div(E, 256), 256, 0, stream>>>(csr_src, csr_ew, dis1, dis2, w_gcn, w_cheb, E);

  // weight prep (transpose + bf16 split)
  k_prep_w<<<ceil_div(512 * 256, 256), 256, 0, stream>>>(W1, W1t_h, W1t_l, 512, 256);
  k_prep_wc<<<ceil_div(768 * 256, 256), 256, 0, stream>>>(Wc, Wct_h, Wct_l);

  // ---- GCNConv: h0b = bf16(x@W1); h1(hi/lo) = split(relu(agg + b1)) ----
  k_gemm_mfma<<<dim3(ceil_div(N, 128), 2), 256, 0, stream>>>(x, W1t_h, W1t_l, h0b, N, 256, 512);
  k_gcn_agg<<<ceil_div(N, 4), 256, 0, stream>>>(h0b, csr_src, w_gcn, row_ptr, dis1, b1, h1h, h1l, N);

  // ---- fused Cheb projection: CC[N][768] = bf16(h1 @ [Wc0|..|Wc5]) (n-tiles inner for L2 A-reuse) ----
  k_gemm_mfma2<<<dim3(6, ceil_div(N, 128)), 256, 0, stream>>>(h1h, h1l, Wct_h, Wct_l, CC, N, 768, 256);

  // ---- Clenshaw (width 128): b_k = C_k - b_{k+2} + 2L b_{k+1} ----
  auto spmm = [&](const unsigned short* Ck, const unsigned short* s16, int s16s, const float* sf,
                  const unsigned short* src, int ss, float* dst, unsigned short* dstb, float coef){
    k_cheb_spmm2<<<ceil_div(N, 4), 256, 0, stream>>>(Ck, 768, s16, s16s, sf, src, ss, dst, dstb,
        csr_src, w_cheb, row_ptr, dis2, coef, N);
  };
  // b4 = C4 + 2L b5   (b5 = CC5 in place)
  spmm(CC + 4*128, nullptr, 0, nullptr, CC + 5*128, 768, B0, Bb0, -2.f);
  // b3 = C3 - b5 + 2L b4
  spmm(CC + 3*128, CC + 5*128, 768, nullptr, Bb0, 128, B1, Bb1, -2.f);
  // b2 = C2 - b4 + 2L b3
  spmm(CC + 2*128, nullptr, 0, B0, Bb1, 128, B2, Bb0, -2.f);
  // b1 = C1 - b3 + 2L b2
  spmm(CC + 1*128, nullptr, 0, B1, Bb0, 128, B0, Bb1, -2.f);

  // ---- final: res = C0 - b2 + L b1, fused with feat/p/wr epilogue ----
  float* out  = (float*)d_out;
  float* feat = out + N;
  k_spmm_final<<<ceil_div(N, 4), 256, 0, stream>>>(CC + 0*128, 768, B2, Bb1, 128,
      bc, W_out, W_root, feat, pbuf, wrbuf, csr_src, w_cheb, row_ptr, dis2, -1.f, N);
  k_out<<<ceil_div(N, 256), 256, 0, stream>>>(pbuf, wrbuf, invw, csr_src, row_ptr, b3, out, N);
}

// Round 9
// 1085.245 us; speedup vs baseline: 1.9454x; 1.0173x over previous
//
#include <hip/hip_runtime.h>
#include <cstdint>
#include <cstddef>

typedef __attribute__((ext_vector_type(8))) short bf16x8;
typedef __attribute__((ext_vector_type(4))) float f32x4;

static inline int ceil_div(int a, int b){ return (a + b - 1) / b; }

struct HL { short h, l; };
__device__ inline HL split2(float a){
  unsigned u = __float_as_uint(a);
  unsigned hb = (u + 0x8000u) & 0xFFFF0000u;
  float r = a - __uint_as_float(hb);
  HL o;
  o.h = (short)(hb >> 16);
  o.l = (short)((__float_as_uint(r) + 0x8000u) >> 16);
  return o;
}

__device__ inline unsigned short f2b(float f){            // fp32 -> bf16 (RNE)
  unsigned u = __float_as_uint(f);
  unsigned r = u + 0x7FFFu + ((u >> 16) & 1u);
  return (unsigned short)(r >> 16);
}
__device__ inline float b2f(unsigned short s){
  return __uint_as_float((unsigned)s << 16);
}

// ---------------- dtype detection (int64 vs int32 edge_index) ----------------
__global__ __launch_bounds__(256) void k_detect(const int* __restrict__ ei32, int E, int* __restrict__ flag){
  int t = blockIdx.x * 256 + threadIdx.x;
  if (t < 4096) {
    long long idx = 2LL * t + 1;
    if (idx < 2LL * E && ei32[idx] != 0) atomicOr(flag, 1);
  }
}

// ---------------- CSR build ----------------
__global__ __launch_bounds__(256) void k_count(const void* __restrict__ ei, int E,
                                               const int* __restrict__ flag, int* __restrict__ cnt){
  int e = blockIdx.x * 256 + threadIdx.x;
  if (e >= E) return;
  int dst = (*flag) ? ((const int*)ei)[(size_t)E + e]
                    : (int)((const long long*)ei)[(size_t)E + e];
  atomicAdd(&cnt[dst], 1);
}

// ---- 3-pass device-wide exclusive scan over cnt[N] -> row_ptr (+cursor copy) ----
__global__ __launch_bounds__(256) void k_scan_part(const int* __restrict__ cnt, int* __restrict__ bsum, int N){
  int base = blockIdx.x * 1024 + threadIdx.x * 4;
  int s = 0;
  if (base + 4 <= N){
    int4 v = *(const int4*)(cnt + base);
    s = v.x + v.y + v.z + v.w;
  } else {
    for (int i = base; i < N; ++i) s += cnt[i];
  }
#pragma unroll
  for (int off = 32; off; off >>= 1) s += __shfl_xor(s, off);
  __shared__ int ws[4];
  if ((threadIdx.x & 63) == 0) ws[threadIdx.x >> 6] = s;
  __syncthreads();
  if (threadIdx.x == 0) bsum[blockIdx.x] = ws[0] + ws[1] + ws[2] + ws[3];
}

__global__ __launch_bounds__(1024) void k_scan_bsum(int* __restrict__ bsum, int nb){
  __shared__ int sh[1024];
  int t = threadIdx.x;
  int v = (t < nb) ? bsum[t] : 0;
  sh[t] = v; __syncthreads();
  for (int off = 1; off < 1024; off <<= 1){
    int u = (t >= off) ? sh[t - off] : 0;
    __syncthreads();
    sh[t] += u;
    __syncthreads();
  }
  if (t < nb) bsum[t] = sh[t] - v;   // exclusive
}

__global__ __launch_bounds__(256) void k_scan_write(const int* __restrict__ cnt, const int* __restrict__ bsum,
                                                    int* __restrict__ row_ptr, int* __restrict__ cursor,
                                                    int N, int E){
  int t = threadIdx.x;
  int base = blockIdx.x * 1024 + t * 4;
  int v0 = 0, v1 = 0, v2 = 0, v3 = 0;
  if (base + 4 <= N){
    int4 v = *(const int4*)(cnt + base);
    v0 = v.x; v1 = v.y; v2 = v.z; v3 = v.w;
  } else {
    if (base + 0 < N) v0 = cnt[base + 0];
    if (base + 1 < N) v1 = cnt[base + 1];
    if (base + 2 < N) v2 = cnt[base + 2];
    if (base + 3 < N) v3 = cnt[base + 3];
  }
  int s = v0 + v1 + v2 + v3;
  int lane = t & 63;
  int inc = s;
#pragma unroll
  for (int off = 1; off < 64; off <<= 1){
    int u = __shfl_up(inc, off);
    if (lane >= off) inc += u;
  }
  __shared__ int ws[4];
  if (lane == 63) ws[t >> 6] = inc;
  __syncthreads();
  int wid = t >> 6;
  int woff = 0;
  for (int i = 0; i < wid; ++i) woff += ws[i];
  int exc = bsum[blockIdx.x] + woff + inc - s;
  int p0 = exc, p1 = p0 + v0, p2 = p1 + v1, p3 = p2 + v2;
  if (base + 0 < N){ row_ptr[base + 0] = p0; cursor[base + 0] = p0; }
  if (base + 1 < N){ row_ptr[base + 1] = p1; cursor[base + 1] = p1; }
  if (base + 2 < N){ row_ptr[base + 2] = p2; cursor[base + 2] = p2; }
  if (base + 3 < N){ row_ptr[base + 3] = p3; cursor[base + 3] = p3; }
  if (blockIdx.x == 0 && t == 0) row_ptr[N] = E;
}

__global__ __launch_bounds__(256) void k_fill(const void* __restrict__ ei, const float* __restrict__ ew, int E,
                                              const int* __restrict__ flag, int* __restrict__ cursor,
                                              int* __restrict__ csr_src, float* __restrict__ csr_ew){
  int e = blockIdx.x * 256 + threadIdx.x;
  if (e >= E) return;
  int src, dst;
  if (*flag){ src = ((const int*)ei)[e]; dst = ((const int*)ei)[(size_t)E + e]; }
  else      { src = (int)((const long long*)ei)[e]; dst = (int)((const long long*)ei)[(size_t)E + e]; }
  int pos = atomicAdd(&cursor[dst], 1);
  csr_src[pos] = src;
  csr_ew[pos] = ew[e];
}

__global__ __launch_bounds__(256) void k_degrees(const int* __restrict__ row_ptr, const float* __restrict__ csr_ew,
                                                 float* __restrict__ dis1, float* __restrict__ dis2,
                                                 float* __restrict__ invw, int N){
  int r = blockIdx.x * 256 + threadIdx.x;
  if (r >= N) return;
  int e0 = row_ptr[r], e1 = row_ptr[r + 1];
  float s = 0.f;
  for (int e = e0; e < e1; ++e) s += csr_ew[e];
  dis1[r] = rsqrtf(s + 1.0f);
  dis2[r] = (s > 0.0f) ? rsqrtf(s) : 0.0f;
  invw[r] = 1.0f / (float)(e1 - e0 + 1);
}

// ---------------- edge norms ----------------
__global__ __launch_bounds__(256) void k_norm(const int* __restrict__ csr_src, const float* __restrict__ csr_ew,
                                              const float* __restrict__ dis1, const float* __restrict__ dis2,
                                              float* __restrict__ w_gcn, float* __restrict__ w_cheb, int E){
  int e = blockIdx.x * 256 + threadIdx.x;
  if (e >= E) return;
  int s = csr_src[e];
  float w = csr_ew[e];
  w_gcn[e]  = w * dis1[s];
  w_cheb[e] = w * dis2[s];
}

// ---------------- weight prep: W [K][N] fp32 -> Wh/Wl [N][K] bf16 split ----------------
__global__ __launch_bounds__(256) void k_prep_w(const float* __restrict__ W, short* __restrict__ Wh,
                                                short* __restrict__ Wl, int K, int N){
  int idx = blockIdx.x * 256 + threadIdx.x;
  if (idx >= K * N) return;
  int n = idx / K, k = idx - n * K;
  HL s = split2(W[(size_t)k * N + n]);
  Wh[idx] = s.h; Wl[idx] = s.l;
}

// ---------------- Wc prep: Wc [6][256][128] -> [768][256] bf16 split ----------------
__global__ __launch_bounds__(256) void k_prep_wc(const float* __restrict__ Wc, short* __restrict__ Wh,
                                                 short* __restrict__ Wl){
  int idx = blockIdx.x * 256 + threadIdx.x;
  if (idx >= 768 * 256) return;
  int n = idx >> 8, k = idx & 255;
  HL s = split2(Wc[(size_t)(n >> 7) * 256 * 128 + (size_t)k * 128 + (n & 127)]);
  Wh[idx] = s.h; Wl[idx] = s.l;
}

// ---------------- MFMA GEMM 1: A fp32 (on-the-fly split), writes bf16 shadow only ----------------
__global__ __launch_bounds__(256) void k_gemm_mfma(
    const float* __restrict__ A,
    const short* __restrict__ Bh, const short* __restrict__ Bl,
    unsigned short* __restrict__ Cb,
    int M, int Ncols, int K)
{
  __shared__ short Ah[128][40];
  __shared__ short Al[128][40];
  __shared__ short Bhs[128][40];
  __shared__ short Bls[128][40];
  int m0 = blockIdx.x * 128, n0 = blockIdx.y * 128;
  int t = threadIdx.x;
  int lane = t & 63, wid = t >> 6;
  int wr = wid >> 1, wc = wid & 1;
  int fr = lane & 15, fq = lane >> 4;
  int srow = t >> 1, skh = (t & 1) << 4;

  f32x4 acc[4][4];
#pragma unroll
  for (int i = 0; i < 4; ++i)
#pragma unroll
    for (int j = 0; j < 4; ++j) acc[i][j] = (f32x4){0.f, 0.f, 0.f, 0.f};

  bool aval = (m0 + srow) < M;
  const float* Aptr = A + (size_t)(m0 + srow) * K + skh;
  const short* Bhp = Bh + (size_t)(n0 + srow) * K + skh;
  const short* Blp = Bl + (size_t)(n0 + srow) * K + skh;

  for (int k0 = 0; k0 < K; k0 += 32){
    __syncthreads();
    float av[16];
    if (aval){
      const float4* ap = (const float4*)(Aptr + k0);
      float4 a0 = ap[0], a1 = ap[1], a2 = ap[2], a3 = ap[3];
      av[0]=a0.x; av[1]=a0.y; av[2]=a0.z; av[3]=a0.w;
      av[4]=a1.x; av[5]=a1.y; av[6]=a1.z; av[7]=a1.w;
      av[8]=a2.x; av[9]=a2.y; av[10]=a2.z; av[11]=a2.w;
      av[12]=a3.x; av[13]=a3.y; av[14]=a3.z; av[15]=a3.w;
    } else {
#pragma unroll
      for (int i = 0; i < 16; ++i) av[i] = 0.f;
    }
    bf16x8 h0, h1, l0, l1;
#pragma unroll
    for (int i = 0; i < 8; ++i){
      HL s = split2(av[i]);
      h0[i] = s.h; l0[i] = s.l;
    }
#pragma unroll
    for (int i = 0; i < 8; ++i){
      HL s = split2(av[8 + i]);
      h1[i] = s.h; l1[i] = s.l;
    }
    *(bf16x8*)&Ah[srow][skh]     = h0;
    *(bf16x8*)&Ah[srow][skh + 8] = h1;
    *(bf16x8*)&Al[srow][skh]     = l0;
    *(bf16x8*)&Al[srow][skh + 8] = l1;
    {
      const bf16x8* bp = (const bf16x8*)(Bhp + k0);
      *(bf16x8*)&Bhs[srow][skh]     = bp[0];
      *(bf16x8*)&Bhs[srow][skh + 8] = bp[1];
      const bf16x8* cp = (const bf16x8*)(Blp + k0);
      *(bf16x8*)&Bls[srow][skh]     = cp[0];
      *(bf16x8*)&Bls[srow][skh + 8] = cp[1];
    }
    __syncthreads();
    bf16x8 afh[4], afl[4], bfh[4], bfl[4];
#pragma unroll
    for (int m = 0; m < 4; ++m){
      int r = wr * 64 + m * 16 + fr;
      afh[m] = *(const bf16x8*)&Ah[r][fq * 8];
      afl[m] = *(const bf16x8*)&Al[r][fq * 8];
    }
#pragma unroll
    for (int n = 0; n < 4; ++n){
      int r = wc * 64 + n * 16 + fr;
      bfh[n] = *(const bf16x8*)&Bhs[r][fq * 8];
      bfl[n] = *(const bf16x8*)&Bls[r][fq * 8];
    }
#pragma unroll
    for (int m = 0; m < 4; ++m)
#pragma unroll
      for (int n = 0; n < 4; ++n){
        acc[m][n] = __builtin_amdgcn_mfma_f32_16x16x32_bf16(afh[m], bfh[n], acc[m][n], 0, 0, 0);
        acc[m][n] = __builtin_amdgcn_mfma_f32_16x16x32_bf16(afl[m], bfh[n], acc[m][n], 0, 0, 0);
        acc[m][n] = __builtin_amdgcn_mfma_f32_16x16x32_bf16(afh[m], bfl[n], acc[m][n], 0, 0, 0);
      }
  }
#pragma unroll
  for (int m = 0; m < 4; ++m){
#pragma unroll
    for (int n = 0; n < 4; ++n){
      int col = n0 + wc * 64 + n * 16 + fr;
#pragma unroll
      for (int r = 0; r < 4; ++r){
        int row = m0 + wr * 64 + m * 16 + fq * 4 + r;
        if (row < M){
          Cb[(size_t)row * Ncols + col] = f2b(acc[m][n][r]);
        }
      }
    }
  }
}

// ---------------- MFMA GEMM 2: A pre-split bf16 pair; 1D grid, XCD-aware swizzle ----------------
// bid -> g = bid&7 (XCD), j = bid>>3; m_tile = g + 8*(j/6), n_tile = j%6.
// All 6 n-tiles of one m-tile run consecutively on the SAME XCD -> A-tile L2-resident.
__global__ __launch_bounds__(256) void k_gemm_mfma2(
    const unsigned short* __restrict__ Ahg, const unsigned short* __restrict__ Alg,
    const short* __restrict__ Bh, const short* __restrict__ Bl,
    unsigned short* __restrict__ Cb,
    int M, int Ncols, int K, int nbm)
{
  __shared__ short Ah[128][40];
  __shared__ short Al[128][40];
  __shared__ short Bhs[128][40];
  __shared__ short Bls[128][40];
  int bid = blockIdx.x;
  int g = bid & 7, j = bid >> 3;
  int m_tile = g + 8 * (j / 6);
  int n_tile = j - 6 * (j / 6);
  if (m_tile >= nbm) return;
  int m0 = m_tile * 128, n0 = n_tile * 128;
  int t = threadIdx.x;
  int lane = t & 63, wid = t >> 6;
  int wr = wid >> 1, wc = wid & 1;
  int fr = lane & 15, fq = lane >> 4;
  int srow = t >> 1, skh = (t & 1) << 4;

  f32x4 acc[4][4];
#pragma unroll
  for (int i = 0; i < 4; ++i)
#pragma unroll
    for (int jj = 0; jj < 4; ++jj) acc[i][jj] = (f32x4){0.f, 0.f, 0.f, 0.f};

  bool aval = (m0 + srow) < M;
  const unsigned short* Ahp = Ahg + (size_t)(m0 + srow) * K + skh;
  const unsigned short* Alp = Alg + (size_t)(m0 + srow) * K + skh;
  const short* Bhp = Bh + (size_t)(n0 + srow) * K + skh;
  const short* Blp = Bl + (size_t)(n0 + srow) * K + skh;

  for (int k0 = 0; k0 < K; k0 += 32){
    __syncthreads();
    if (aval){
      const bf16x8* ah = (const bf16x8*)(Ahp + k0);
      *(bf16x8*)&Ah[srow][skh]     = ah[0];
      *(bf16x8*)&Ah[srow][skh + 8] = ah[1];
      const bf16x8* al = (const bf16x8*)(Alp + k0);
      *(bf16x8*)&Al[srow][skh]     = al[0];
      *(bf16x8*)&Al[srow][skh + 8] = al[1];
    } else {
      bf16x8 z = (bf16x8){0,0,0,0,0,0,0,0};
      *(bf16x8*)&Ah[srow][skh] = z; *(bf16x8*)&Ah[srow][skh + 8] = z;
      *(bf16x8*)&Al[srow][skh] = z; *(bf16x8*)&Al[srow][skh + 8] = z;
    }
    {
      const bf16x8* bp = (const bf16x8*)(Bhp + k0);
      *(bf16x8*)&Bhs[srow][skh]     = bp[0];
      *(bf16x8*)&Bhs[srow][skh + 8] = bp[1];
      const bf16x8* cp = (const bf16x8*)(Blp + k0);
      *(bf16x8*)&Bls[srow][skh]     = cp[0];
      *(bf16x8*)&Bls[srow][skh + 8] = cp[1];
    }
    __syncthreads();
    bf16x8 afh[4], afl[4], bfh[4], bfl[4];
#pragma unroll
    for (int m = 0; m < 4; ++m){
      int r = wr * 64 + m * 16 + fr;
      afh[m] = *(const bf16x8*)&Ah[r][fq * 8];
      afl[m] = *(const bf16x8*)&Al[r][fq * 8];
    }
#pragma unroll
    for (int n = 0; n < 4; ++n){
      int r = wc * 64 + n * 16 + fr;
      bfh[n] = *(const bf16x8*)&Bhs[r][fq * 8];
      bfl[n] = *(const bf16x8*)&Bls[r][fq * 8];
    }
#pragma unroll
    for (int m = 0; m < 4; ++m)
#pragma unroll
      for (int n = 0; n < 4; ++n){
        acc[m][n] = __builtin_amdgcn_mfma_f32_16x16x32_bf16(afh[m], bfh[n], acc[m][n], 0, 0, 0);
        acc[m][n] = __builtin_amdgcn_mfma_f32_16x16x32_bf16(afl[m], bfh[n], acc[m][n], 0, 0, 0);
        acc[m][n] = __builtin_amdgcn_mfma_f32_16x16x32_bf16(afh[m], bfl[n], acc[m][n], 0, 0, 0);
      }
  }
#pragma unroll
  for (int m = 0; m < 4; ++m){
#pragma unroll
    for (int n = 0; n < 4; ++n){
      int col = n0 + wc * 64 + n * 16 + fr;
#pragma unroll
      for (int r = 0; r < 4; ++r){
        int row = m0 + wr * 64 + m * 16 + fq * 4 + r;
        if (row < M){
          Cb[(size_t)row * Ncols + col] = f2b(acc[m][n][r]);
        }
      }
    }
  }
}

// ---------------- GCN aggregation: bf16 gathers (8-wide MLP), writes h1 bf16 hi/lo pair ------------
__global__ __launch_bounds__(256) void k_gcn_agg(
    const unsigned short* __restrict__ h0b,
    const int* __restrict__ csr_src, const float* __restrict__ w_gcn,
    const int* __restrict__ row_ptr, const float* __restrict__ dis1,
    const float* __restrict__ b1,
    unsigned short* __restrict__ h1h, unsigned short* __restrict__ h1l, int N){
  int lane = threadIdx.x & 63;
  int r = blockIdx.x * 4 + (threadIdx.x >> 6);
  if (r >= N) return;
  float dr = dis1[r];
  ushort4 sv = ((const ushort4*)(h0b + (size_t)r * 256))[lane];
  float4 inner = make_float4(b2f(sv.x) * dr, b2f(sv.y) * dr, b2f(sv.z) * dr, b2f(sv.w) * dr);
  int e0 = row_ptr[r], e1 = row_ptr[r + 1];
  int e = e0;
  for (; e + 8 <= e1; e += 8){
    int   si[8]; float wi[8]; ushort4 vi[8];
#pragma unroll
    for (int q = 0; q < 8; ++q){ si[q] = csr_src[e + q]; wi[q] = w_gcn[e + q]; }
#pragma unroll
    for (int q = 0; q < 8; ++q) vi[q] = ((const ushort4*)(h0b + (size_t)si[q] * 256))[lane];
#pragma unroll
    for (int q = 0; q < 8; ++q){
      inner.x = fmaf(wi[q], b2f(vi[q].x), inner.x);
      inner.y = fmaf(wi[q], b2f(vi[q].y), inner.y);
      inner.z = fmaf(wi[q], b2f(vi[q].z), inner.z);
      inner.w = fmaf(wi[q], b2f(vi[q].w), inner.w);
    }
  }
  for (; e < e1; ++e){
    int s = csr_src[e];
    float w = w_gcn[e];
    ushort4 v = ((const ushort4*)(h0b + (size_t)s * 256))[lane];
    inner.x = fmaf(w, b2f(v.x), inner.x); inner.y = fmaf(w, b2f(v.y), inner.y);
    inner.z = fmaf(w, b2f(v.z), inner.z); inner.w = fmaf(w, b2f(v.w), inner.w);
  }
  float4 bb = ((const float4*)b1)[lane];
  float4 o;
  o.x = fmaxf(fmaf(inner.x, dr, bb.x), 0.f);
  o.y = fmaxf(fmaf(inner.y, dr, bb.y), 0.f);
  o.z = fmaxf(fmaf(inner.z, dr, bb.z), 0.f);
  o.w = fmaxf(fmaf(inner.w, dr, bb.w), 0.f);
  HL sx = split2(o.x), sy = split2(o.y), sz = split2(o.z), sw = split2(o.w);
  ushort4 hi; hi.x = (unsigned short)sx.h; hi.y = (unsigned short)sy.h; hi.z = (unsigned short)sz.h; hi.w = (unsigned short)sw.h;
  ushort4 lo; lo.x = (unsigned short)sx.l; lo.y = (unsigned short)sy.l; lo.z = (unsigned short)sz.l; lo.w = (unsigned short)sw.l;
  ((ushort4*)(h1h + (size_t)r * 256))[lane] = hi;
  ((ushort4*)(h1l + (size_t)r * 256))[lane] = lo;
}

// ---------------- Cheb spmm v2 (8-wide MLP): dst = Ck - sub + coef*dis2[r]*Σ w*src[s] -------------
__global__ __launch_bounds__(256) void k_cheb_spmm2(
    const unsigned short* __restrict__ Ck, int ckstride,
    const unsigned short* __restrict__ sub16, int substride,
    const float* __restrict__ subf,
    const unsigned short* __restrict__ srcb, int sstride,
    float* __restrict__ dst, unsigned short* __restrict__ dstb,
    const int* __restrict__ csr_src, const float* __restrict__ w_cheb,
    const int* __restrict__ row_ptr, const float* __restrict__ dis2, float coef, int N){
  int lane = threadIdx.x & 63;
  int r = blockIdx.x * 4 + (threadIdx.x >> 6);
  if (r >= N) return;
  float2 inner = make_float2(0.f, 0.f);
  int e0 = row_ptr[r], e1 = row_ptr[r + 1];
  int e = e0;
  for (; e + 8 <= e1; e += 8){
    int si[8]; float wi[8]; unsigned vi[8];
#pragma unroll
    for (int q = 0; q < 8; ++q){ si[q] = csr_src[e + q]; wi[q] = w_cheb[e + q]; }
#pragma unroll
    for (int q = 0; q < 8; ++q) vi[q] = ((const unsigned*)(srcb + (size_t)si[q] * sstride))[lane];
#pragma unroll
    for (int q = 0; q < 8; ++q){
      inner.x = fmaf(wi[q], __uint_as_float(vi[q] << 16), inner.x);
      inner.y = fmaf(wi[q], __uint_as_float(vi[q] & 0xFFFF0000u), inner.y);
    }
  }
  for (; e < e1; ++e){
    int s = csr_src[e];
    float w = w_cheb[e];
    unsigned v = ((const unsigned*)(srcb + (size_t)s * sstride))[lane];
    inner.x = fmaf(w, __uint_as_float(v << 16), inner.x);
    inner.y = fmaf(w, __uint_as_float(v & 0xFFFF0000u), inner.y);
  }
  float c = coef * dis2[r];
  unsigned ckv = ((const unsigned*)(Ck + (size_t)r * ckstride))[lane];
  float rx = fmaf(c, inner.x, __uint_as_float(ckv << 16));
  float ry = fmaf(c, inner.y, __uint_as_float(ckv & 0xFFFF0000u));
  if (sub16){
    unsigned sv = ((const unsigned*)(sub16 + (size_t)r * substride))[lane];
    rx -= __uint_as_float(sv << 16);
    ry -= __uint_as_float(sv & 0xFFFF0000u);
  }
  if (subf){
    float2 s2 = ((const float2*)(subf + (size_t)r * 128))[lane];
    rx -= s2.x;
    ry -= s2.y;
  }
  ((float2*)(dst + (size_t)r * 128))[lane] = make_float2(rx, ry);
  if (dstb){
    unsigned pk = (unsigned)f2b(rx) | ((unsigned)f2b(ry) << 16);
    ((unsigned*)(dstb + (size_t)r * 128))[lane] = pk;
  }
}

// ---------------- final spmm fused with feat epilogue (8-wide MLP) ----------------
__global__ __launch_bounds__(256) void k_spmm_final(
    const unsigned short* __restrict__ Ck, int ckstride,
    const float* __restrict__ subf,
    const unsigned short* __restrict__ srcb, int sstride,
    const float* __restrict__ bc, const float* __restrict__ W_out, const float* __restrict__ W_root,
    float* __restrict__ feat, float* __restrict__ p, float* __restrict__ wr,
    const int* __restrict__ csr_src, const float* __restrict__ w_cheb,
    const int* __restrict__ row_ptr, const float* __restrict__ dis2, float coef, int N){
  int lane = threadIdx.x & 63;
  int r = blockIdx.x * 4 + (threadIdx.x >> 6);
  if (r >= N) return;
  float2 inner = make_float2(0.f, 0.f);
  int e0 = row_ptr[r], e1 = row_ptr[r + 1];
  int e = e0;
  for (; e + 8 <= e1; e += 8){
    int si[8]; float wi[8]; unsigned vi[8];
#pragma unroll
    for (int q = 0; q < 8; ++q){ si[q] = csr_src[e + q]; wi[q] = w_cheb[e + q]; }
#pragma unroll
    for (int q = 0; q < 8; ++q) vi[q] = ((const unsigned*)(srcb + (size_t)si[q] * sstride))[lane];
#pragma unroll
    for (int q = 0; q < 8; ++q){
      inner.x = fmaf(wi[q], __uint_as_float(vi[q] << 16), inner.x);
      inner.y = fmaf(wi[q], __uint_as_float(vi[q] & 0xFFFF0000u), inner.y);
    }
  }
  for (; e < e1; ++e){
    int s = csr_src[e];
    float w = w_cheb[e];
    unsigned v = ((const unsigned*)(srcb + (size_t)s * sstride))[lane];
    inner.x = fmaf(w, __uint_as_float(v << 16), inner.x);
    inner.y = fmaf(w, __uint_as_float(v & 0xFFFF0000u), inner.y);
  }
  float c = coef * dis2[r];
  unsigned ckv = ((const unsigned*)(Ck + (size_t)r * ckstride))[lane];
  float rx = fmaf(c, inner.x, __uint_as_float(ckv << 16));
  float ry = fmaf(c, inner.y, __uint_as_float(ckv & 0xFFFF0000u));
  float2 s2 = ((const float2*)(subf + (size_t)r * 128))[lane];
  rx -= s2.x;
  ry -= s2.y;
  float2 bb = ((const float2*)bc)[lane];
  rx = fmaxf(rx + bb.x, 0.f);
  ry = fmaxf(ry + bb.y, 0.f);
  ((float2*)(feat + (size_t)r * 128))[lane] = make_float2(rx, ry);
  float2 wo = ((const float2*)W_out)[lane];
  float2 wrt = ((const float2*)W_root)[lane];
  float pp = rx * wo.x + ry * wo.y;
  float rr = rx * wrt.x + ry * wrt.y;
#pragma unroll
  for (int off = 32; off; off >>= 1){
    pp += __shfl_xor(pp, off);
    rr += __shfl_xor(rr, off);
  }
  if (lane == 0){ p[r] = pp; wr[r] = rr; }
}

// ---------------- ClusterGCN output (8-wide) ----------------
__global__ __launch_bounds__(256) void k_out(const float* __restrict__ p, const float* __restrict__ wr,
    const float* __restrict__ invw, const int* __restrict__ csr_src, const int* __restrict__ row_ptr,
    const float* __restrict__ b3, float* __restrict__ out, int N){
  int r = blockIdx.x * 256 + threadIdx.x;
  if (r >= N) return;
  float s = p[r];
  int e0 = row_ptr[r], e1 = row_ptr[r + 1];
  int e = e0;
  float acc[8] = {0.f,0.f,0.f,0.f,0.f,0.f,0.f,0.f};
  for (; e + 8 <= e1; e += 8){
    int si[8];
#pragma unroll
    for (int q = 0; q < 8; ++q) si[q] = csr_src[e + q];
#pragma unroll
    for (int q = 0; q < 8; ++q) acc[q] += p[si[q]];
  }
  for (; e < e1; ++e) acc[0] += p[csr_src[e]];
  s += ((acc[0]+acc[1])+(acc[2]+acc[3])) + ((acc[4]+acc[5])+(acc[6]+acc[7]));
  out[r] = invw[r] * s + wr[r] + b3[0];
}

extern "C" void kernel_launch(void* const* d_in, const int* in_sizes, int n_in,
                              void* d_out, int out_size, void* d_ws, size_t ws_size,
                              hipStream_t stream){
  const float* x      = (const float*)d_in[0];
  const void*  ei     = d_in[1];
  const float* ew     = (const float*)d_in[2];
  const float* W1     = (const float*)d_in[3];
  const float* b1     = (const float*)d_in[4];
  const float* Wc     = (const float*)d_in[5];
  const float* bc     = (const float*)d_in[6];
  const float* W_out  = (const float*)d_in[7];
  const float* W_root = (const float*)d_in[8];
  const float* b3     = (const float*)d_in[9];
  const int N = in_sizes[0] / 512;
  const int E = in_sizes[2];

  char* w = (char*)d_ws;
  auto alloc = [&](size_t bytes)->void*{ void* r = (void*)w; w += (bytes + 255) & ~(size_t)255; return r; };
  // h1 region (102.4 MB): first h1h|h1l bf16 split of GCN output; later B0|B1 fp32 Clenshaw
  unsigned short* h1h = (unsigned short*)alloc((size_t)N * 256 * 2 * 2);
  unsigned short* h1l = h1h + (size_t)N * 256;
  float* B0 = (float*)h1h;
  float* B1 = B0 + (size_t)N * 128;
  float* B2 = (float*)alloc((size_t)N * 128 * 4);
  unsigned short* CC  = (unsigned short*)alloc((size_t)N * 768 * 2);  // all 6 C_k, bf16
  unsigned short* h0b = (unsigned short*)alloc((size_t)N * 256 * 2);  // bf16 x@W1; later Bb0|Bb1
  unsigned short* Bb0 = h0b;
  unsigned short* Bb1 = h0b + (size_t)N * 128;
  float* csr_ew  = (float*)alloc((size_t)E * 4);
  float* w_gcn   = (float*)alloc((size_t)E * 4);
  float* w_cheb  = (float*)alloc((size_t)E * 4);
  int*   csr_src = (int*)  alloc((size_t)E * 4);
  int*   row_ptr = (int*)  alloc((size_t)(N + 1) * 4);
  int*   cursor  = (int*)  alloc((size_t)N * 4);
  int*   cnt     = (int*)  alloc((size_t)N * 4);
  int*   bsum    = (int*)  alloc((size_t)1024 * 4);
  float* dis1    = (float*)alloc((size_t)N * 4);
  float* dis2    = (float*)alloc((size_t)N * 4);
  float* invw    = (float*)alloc((size_t)N * 4);
  float* pbuf    = (float*)alloc((size_t)N * 4);
  float* wrbuf   = (float*)alloc((size_t)N * 4);
  short* W1t_h   = (short*)alloc((size_t)512 * 256 * 2);
  short* W1t_l   = (short*)alloc((size_t)512 * 256 * 2);
  short* Wct_h   = (short*)alloc((size_t)768 * 256 * 2);
  short* Wct_l   = (short*)alloc((size_t)768 * 256 * 2);
  int*   flag    = (int*)  alloc(256);

  hipMemsetAsync(cnt, 0, (size_t)N * 4, stream);
  hipMemsetAsync(flag, 0, 4, stream);

  k_detect<<<16, 256, 0, stream>>>((const int*)ei, E, flag);
  k_count<<<ceil_div(E, 256), 256, 0, stream>>>(ei, E, flag, cnt);
  int nb = ceil_div(N, 1024);
  k_scan_part<<<nb, 256, 0, stream>>>(cnt, bsum, N);
  k_scan_bsum<<<1, 1024, 0, stream>>>(bsum, nb);
  k_scan_write<<<nb, 256, 0, stream>>>(cnt, bsum, row_ptr, cursor, N, E);
  k_fill<<<ceil_div(E, 256), 256, 0, stream>>>(ei, ew, E, flag, cursor, csr_src, csr_ew);
  k_degrees<<<ceil_div(N, 256), 256, 0, stream>>>(row_ptr, csr_ew, dis1, dis2, invw, N);
  k_norm<<<ceil_div(E, 256), 256, 0, stream>>>(csr_src, csr_ew, dis1, dis2, w_gcn, w_cheb, E);

  // weight prep (transpose + bf16 split)
  k_prep_w<<<ceil_div(512 * 256, 256), 256, 0, stream>>>(W1, W1t_h, W1t_l, 512, 256);
  k_prep_wc<<<ceil_div(768 * 256, 256), 256, 0, stream>>>(Wc, Wct_h, Wct_l);

  // ---- GCNConv: h0b = bf16(x@W1); h1(hi/lo) = split(relu(agg + b1)) ----
  k_gemm_mfma<<<dim3(ceil_div(N, 128), 2), 256, 0, stream>>>(x, W1t_h, W1t_l, h0b, N, 256, 512);
  k_gcn_agg<<<ceil_div(N, 4), 256, 0, stream>>>(h0b, csr_src, w_gcn, row_ptr, dis1, b1, h1h, h1l, N);

  // ---- fused Cheb projection: CC[N][768] = bf16(h1 @ [Wc0|..|Wc5]), XCD-swizzled 1D grid ----
  int nbm = ceil_div(N, 128);
  int grid2 = 8 * 6 * ceil_div(nbm, 8);
  k_gemm_mfma2<<<grid2, 256, 0, stream>>>(h1h, h1l, Wct_h, Wct_l, CC, N, 768, 256, nbm);

  // ---- Clenshaw (width 128): b_k = C_k - b_{k+2} + 2L b_{k+1} ----
  auto spmm = [&](const unsigned short* Ck, const unsigned short* s16, int s16s, const float* sf,
                  const unsigned short* src, int ss, float* dst, unsigned short* dstb, float coef){
    k_cheb_spmm2<<<ceil_div(N, 4), 256, 0, stream>>>(Ck, 768, s16, s16s, sf, src, ss, dst, dstb,
        csr_src, w_cheb, row_ptr, dis2, coef, N);
  };
  // b4 = C4 + 2L b5   (b5 = CC5 in place)
  spmm(CC + 4*128, nullptr, 0, nullptr, CC + 5*128, 768, B0, Bb0, -2.f);
  // b3 = C3 - b5 + 2L b4
  spmm(CC + 3*128, CC + 5*128, 768, nullptr, Bb0, 128, B1, Bb1, -2.f);
  // b2 = C2 - b4 + 2L b3
  spmm(CC + 2*128, nullptr, 0, B0, Bb1, 128, B2, Bb0, -2.f);
  // b1 = C1 - b3 + 2L b2
  spmm(CC + 1*128, nullptr, 0, B1, Bb0, 128, B0, Bb1, -2.f);

  // ---- final: res = C0 - b2 + L b1, fused with feat/p/wr epilogue ----
  float* out  = (float*)d_out;
  float* feat = out + N;
  k_spmm_final<<<ceil_div(N, 4), 256, 0, stream>>>(CC + 0*128, 768, B2, Bb1, 128,
      bc, W_out, W_root, feat, pbuf, wrbuf, csr_src, w_cheb, row_ptr, dis2, -1.f, N);
  k_out<<<ceil_div(N, 256), 256, 0, stream>>>(pbuf, wrbuf, invw, csr_src, row_ptr, b3, out, N);
}

// Round 10
// 1068.716 us; speedup vs baseline: 1.9755x; 1.0155x over previous
//
#include <hip/hip_runtime.h>
#include <cstdint>
#include <cstddef>

typedef __attribute__((ext_vector_type(8))) short bf16x8;
typedef __attribute__((ext_vector_type(4))) float f32x4;

static inline int ceil_div(int a, int b){ return (a + b - 1) / b; }

struct HL { short h, l; };
__device__ inline HL split2(float a){
  unsigned u = __float_as_uint(a);
  unsigned hb = (u + 0x8000u) & 0xFFFF0000u;
  float r = a - __uint_as_float(hb);
  HL o;
  o.h = (short)(hb >> 16);
  o.l = (short)((__float_as_uint(r) + 0x8000u) >> 16);
  return o;
}

__device__ inline unsigned short f2b(float f){            // fp32 -> bf16 (RNE)
  unsigned u = __float_as_uint(f);
  unsigned r = u + 0x7FFFu + ((u >> 16) & 1u);
  return (unsigned short)(r >> 16);
}
__device__ inline float b2f(unsigned short s){
  return __uint_as_float((unsigned)s << 16);
}

// ---------------- dtype detection (int64 vs int32 edge_index) ----------------
__global__ __launch_bounds__(256) void k_detect(const int* __restrict__ ei32, int E, int* __restrict__ flag){
  int t = blockIdx.x * 256 + threadIdx.x;
  if (t < 4096) {
    long long idx = 2LL * t + 1;
    if (idx < 2LL * E && ei32[idx] != 0) atomicOr(flag, 1);
  }
}

// ---------------- CSR build ----------------
__global__ __launch_bounds__(256) void k_count(const void* __restrict__ ei, int E,
                                               const int* __restrict__ flag, int* __restrict__ cnt){
  int e = blockIdx.x * 256 + threadIdx.x;
  if (e >= E) return;
  int dst = (*flag) ? ((const int*)ei)[(size_t)E + e]
                    : (int)((const long long*)ei)[(size_t)E + e];
  atomicAdd(&cnt[dst], 1);
}

// ---- 3-pass device-wide exclusive scan over cnt[N] -> row_ptr (+cursor copy) ----
__global__ __launch_bounds__(256) void k_scan_part(const int* __restrict__ cnt, int* __restrict__ bsum, int N){
  int base = blockIdx.x * 1024 + threadIdx.x * 4;
  int s = 0;
  if (base + 4 <= N){
    int4 v = *(const int4*)(cnt + base);
    s = v.x + v.y + v.z + v.w;
  } else {
    for (int i = base; i < N; ++i) s += cnt[i];
  }
#pragma unroll
  for (int off = 32; off; off >>= 1) s += __shfl_xor(s, off);
  __shared__ int ws[4];
  if ((threadIdx.x & 63) == 0) ws[threadIdx.x >> 6] = s;
  __syncthreads();
  if (threadIdx.x == 0) bsum[blockIdx.x] = ws[0] + ws[1] + ws[2] + ws[3];
}

__global__ __launch_bounds__(1024) void k_scan_bsum(int* __restrict__ bsum, int nb){
  __shared__ int sh[1024];
  int t = threadIdx.x;
  int v = (t < nb) ? bsum[t] : 0;
  sh[t] = v; __syncthreads();
  for (int off = 1; off < 1024; off <<= 1){
    int u = (t >= off) ? sh[t - off] : 0;
    __syncthreads();
    sh[t] += u;
    __syncthreads();
  }
  if (t < nb) bsum[t] = sh[t] - v;   // exclusive
}

__global__ __launch_bounds__(256) void k_scan_write(const int* __restrict__ cnt, const int* __restrict__ bsum,
                                                    int* __restrict__ row_ptr, int* __restrict__ cursor,
                                                    int N, int E){
  int t = threadIdx.x;
  int base = blockIdx.x * 1024 + t * 4;
  int v0 = 0, v1 = 0, v2 = 0, v3 = 0;
  if (base + 4 <= N){
    int4 v = *(const int4*)(cnt + base);
    v0 = v.x; v1 = v.y; v2 = v.z; v3 = v.w;
  } else {
    if (base + 0 < N) v0 = cnt[base + 0];
    if (base + 1 < N) v1 = cnt[base + 1];
    if (base + 2 < N) v2 = cnt[base + 2];
    if (base + 3 < N) v3 = cnt[base + 3];
  }
  int s = v0 + v1 + v2 + v3;
  int lane = t & 63;
  int inc = s;
#pragma unroll
  for (int off = 1; off < 64; off <<= 1){
    int u = __shfl_up(inc, off);
    if (lane >= off) inc += u;
  }
  __shared__ int ws[4];
  if (lane == 63) ws[t >> 6] = inc;
  __syncthreads();
  int wid = t >> 6;
  int woff = 0;
  for (int i = 0; i < wid; ++i) woff += ws[i];
  int exc = bsum[blockIdx.x] + woff + inc - s;
  int p0 = exc, p1 = p0 + v0, p2 = p1 + v1, p3 = p2 + v2;
  if (base + 0 < N){ row_ptr[base + 0] = p0; cursor[base + 0] = p0; }
  if (base + 1 < N){ row_ptr[base + 1] = p1; cursor[base + 1] = p1; }
  if (base + 2 < N){ row_ptr[base + 2] = p2; cursor[base + 2] = p2; }
  if (base + 3 < N){ row_ptr[base + 3] = p3; cursor[base + 3] = p3; }
  if (blockIdx.x == 0 && t == 0) row_ptr[N] = E;
}

__global__ __launch_bounds__(256) void k_fill(const void* __restrict__ ei, const float* __restrict__ ew, int E,
                                              const int* __restrict__ flag, int* __restrict__ cursor,
                                              int* __restrict__ csr_src, float* __restrict__ csr_ew){
  int e = blockIdx.x * 256 + threadIdx.x;
  if (e >= E) return;
  int src, dst;
  if (*flag){ src = ((const int*)ei)[e]; dst = ((const int*)ei)[(size_t)E + e]; }
  else      { src = (int)((const long long*)ei)[e]; dst = (int)((const long long*)ei)[(size_t)E + e]; }
  int pos = atomicAdd(&cursor[dst], 1);
  csr_src[pos] = src;
  csr_ew[pos] = ew[e];
}

__global__ __launch_bounds__(256) void k_degrees(const int* __restrict__ row_ptr, const float* __restrict__ csr_ew,
                                                 float* __restrict__ dis1, float* __restrict__ dis2,
                                                 float* __restrict__ invw, int N){
  int r = blockIdx.x * 256 + threadIdx.x;
  if (r >= N) return;
  int e0 = row_ptr[r], e1 = row_ptr[r + 1];
  float s = 0.f;
  for (int e = e0; e < e1; ++e) s += csr_ew[e];
  dis1[r] = rsqrtf(s + 1.0f);
  dis2[r] = (s > 0.0f) ? rsqrtf(s) : 0.0f;
  invw[r] = 1.0f / (float)(e1 - e0 + 1);
}

// ---------------- edge norms ----------------
__global__ __launch_bounds__(256) void k_norm(const int* __restrict__ csr_src, const float* __restrict__ csr_ew,
                                              const float* __restrict__ dis1, const float* __restrict__ dis2,
                                              float* __restrict__ w_gcn, float* __restrict__ w_cheb, int E){
  int e = blockIdx.x * 256 + threadIdx.x;
  if (e >= E) return;
  int s = csr_src[e];
  float w = csr_ew[e];
  w_gcn[e]  = w * dis1[s];
  w_cheb[e] = w * dis2[s];
}

// ---------------- weight prep: W [K][N] fp32 -> Wh/Wl [N][K] bf16 split ----------------
__global__ __launch_bounds__(256) void k_prep_w(const float* __restrict__ W, short* __restrict__ Wh,
                                                short* __restrict__ Wl, int K, int N){
  int idx = blockIdx.x * 256 + threadIdx.x;
  if (idx >= K * N) return;
  int n = idx / K, k = idx - n * K;
  HL s = split2(W[(size_t)k * N + n]);
  Wh[idx] = s.h; Wl[idx] = s.l;
}

// ---------------- Wc prep: Wc [6][256][128] -> [768][256] bf16 (single, RNE) ----------------
__global__ __launch_bounds__(256) void k_prep_wc(const float* __restrict__ Wc, short* __restrict__ Wh){
  int idx = blockIdx.x * 256 + threadIdx.x;
  if (idx >= 768 * 256) return;
  int n = idx >> 8, k = idx & 255;
  Wh[idx] = (short)f2b(Wc[(size_t)(n >> 7) * 256 * 128 + (size_t)k * 128 + (n & 127)]);
}

// ---------------- MFMA GEMM 1: A = bf16(x) direct, B = W1 split; 2-term; bf16 C only ------------
__global__ __launch_bounds__(256) void k_gemm_mfma(
    const float* __restrict__ A,
    const short* __restrict__ Bh, const short* __restrict__ Bl,
    unsigned short* __restrict__ Cb,
    int M, int Ncols, int K)
{
  __shared__ short Ah[128][40];
  __shared__ short Bhs[128][40];
  __shared__ short Bls[128][40];
  int m0 = blockIdx.x * 128, n0 = blockIdx.y * 128;
  int t = threadIdx.x;
  int lane = t & 63, wid = t >> 6;
  int wr = wid >> 1, wc = wid & 1;
  int fr = lane & 15, fq = lane >> 4;
  int srow = t >> 1, skh = (t & 1) << 4;

  f32x4 acc[4][4];
#pragma unroll
  for (int i = 0; i < 4; ++i)
#pragma unroll
    for (int j = 0; j < 4; ++j) acc[i][j] = (f32x4){0.f, 0.f, 0.f, 0.f};

  bool aval = (m0 + srow) < M;
  const float* Aptr = A + (size_t)(m0 + srow) * K + skh;
  const short* Bhp = Bh + (size_t)(n0 + srow) * K + skh;
  const short* Blp = Bl + (size_t)(n0 + srow) * K + skh;

  for (int k0 = 0; k0 < K; k0 += 32){
    __syncthreads();
    float av[16];
    if (aval){
      const float4* ap = (const float4*)(Aptr + k0);
      float4 a0 = ap[0], a1 = ap[1], a2 = ap[2], a3 = ap[3];
      av[0]=a0.x; av[1]=a0.y; av[2]=a0.z; av[3]=a0.w;
      av[4]=a1.x; av[5]=a1.y; av[6]=a1.z; av[7]=a1.w;
      av[8]=a2.x; av[9]=a2.y; av[10]=a2.z; av[11]=a2.w;
      av[12]=a3.x; av[13]=a3.y; av[14]=a3.z; av[15]=a3.w;
    } else {
#pragma unroll
      for (int i = 0; i < 16; ++i) av[i] = 0.f;
    }
    bf16x8 h0, h1;
#pragma unroll
    for (int i = 0; i < 8; ++i) h0[i] = (short)f2b(av[i]);
#pragma unroll
    for (int i = 0; i < 8; ++i) h1[i] = (short)f2b(av[8 + i]);
    *(bf16x8*)&Ah[srow][skh]     = h0;
    *(bf16x8*)&Ah[srow][skh + 8] = h1;
    {
      const bf16x8* bp = (const bf16x8*)(Bhp + k0);
      *(bf16x8*)&Bhs[srow][skh]     = bp[0];
      *(bf16x8*)&Bhs[srow][skh + 8] = bp[1];
      const bf16x8* cp = (const bf16x8*)(Blp + k0);
      *(bf16x8*)&Bls[srow][skh]     = cp[0];
      *(bf16x8*)&Bls[srow][skh + 8] = cp[1];
    }
    __syncthreads();
    bf16x8 afh[4], bfh[4], bfl[4];
#pragma unroll
    for (int m = 0; m < 4; ++m){
      int r = wr * 64 + m * 16 + fr;
      afh[m] = *(const bf16x8*)&Ah[r][fq * 8];
    }
#pragma unroll
    for (int n = 0; n < 4; ++n){
      int r = wc * 64 + n * 16 + fr;
      bfh[n] = *(const bf16x8*)&Bhs[r][fq * 8];
      bfl[n] = *(const bf16x8*)&Bls[r][fq * 8];
    }
#pragma unroll
    for (int m = 0; m < 4; ++m)
#pragma unroll
      for (int n = 0; n < 4; ++n){
        acc[m][n] = __builtin_amdgcn_mfma_f32_16x16x32_bf16(afh[m], bfh[n], acc[m][n], 0, 0, 0);
        acc[m][n] = __builtin_amdgcn_mfma_f32_16x16x32_bf16(afh[m], bfl[n], acc[m][n], 0, 0, 0);
      }
  }
#pragma unroll
  for (int m = 0; m < 4; ++m){
#pragma unroll
    for (int n = 0; n < 4; ++n){
      int col = n0 + wc * 64 + n * 16 + fr;
#pragma unroll
      for (int r = 0; r < 4; ++r){
        int row = m0 + wr * 64 + m * 16 + fq * 4 + r;
        if (row < M){
          Cb[(size_t)row * Ncols + col] = f2b(acc[m][n][r]);
        }
      }
    }
  }
}

// ---------------- MFMA GEMM 2: A = h1 split, B = bf16(Wc); 2-term; XCD-swizzled 1D grid --------
__global__ __launch_bounds__(256) void k_gemm_mfma2(
    const unsigned short* __restrict__ Ahg, const unsigned short* __restrict__ Alg,
    const short* __restrict__ Bh,
    unsigned short* __restrict__ Cb,
    int M, int Ncols, int K, int nbm)
{
  __shared__ short Ah[128][40];
  __shared__ short Al[128][40];
  __shared__ short Bhs[128][40];
  int bid = blockIdx.x;
  int g = bid & 7, j = bid >> 3;
  int m_tile = g + 8 * (j / 6);
  int n_tile = j - 6 * (j / 6);
  if (m_tile >= nbm) return;
  int m0 = m_tile * 128, n0 = n_tile * 128;
  int t = threadIdx.x;
  int lane = t & 63, wid = t >> 6;
  int wr = wid >> 1, wc = wid & 1;
  int fr = lane & 15, fq = lane >> 4;
  int srow = t >> 1, skh = (t & 1) << 4;

  f32x4 acc[4][4];
#pragma unroll
  for (int i = 0; i < 4; ++i)
#pragma unroll
    for (int jj = 0; jj < 4; ++jj) acc[i][jj] = (f32x4){0.f, 0.f, 0.f, 0.f};

  bool aval = (m0 + srow) < M;
  const unsigned short* Ahp = Ahg + (size_t)(m0 + srow) * K + skh;
  const unsigned short* Alp = Alg + (size_t)(m0 + srow) * K + skh;
  const short* Bhp = Bh + (size_t)(n0 + srow) * K + skh;

  for (int k0 = 0; k0 < K; k0 += 32){
    __syncthreads();
    if (aval){
      const bf16x8* ah = (const bf16x8*)(Ahp + k0);
      *(bf16x8*)&Ah[srow][skh]     = ah[0];
      *(bf16x8*)&Ah[srow][skh + 8] = ah[1];
      const bf16x8* al = (const bf16x8*)(Alp + k0);
      *(bf16x8*)&Al[srow][skh]     = al[0];
      *(bf16x8*)&Al[srow][skh + 8] = al[1];
    } else {
      bf16x8 z = (bf16x8){0,0,0,0,0,0,0,0};
      *(bf16x8*)&Ah[srow][skh] = z; *(bf16x8*)&Ah[srow][skh + 8] = z;
      *(bf16x8*)&Al[srow][skh] = z; *(bf16x8*)&Al[srow][skh + 8] = z;
    }
    {
      const bf16x8* bp = (const bf16x8*)(Bhp + k0);
      *(bf16x8*)&Bhs[srow][skh]     = bp[0];
      *(bf16x8*)&Bhs[srow][skh + 8] = bp[1];
    }
    __syncthreads();
    bf16x8 afh[4], afl[4], bfh[4];
#pragma unroll
    for (int m = 0; m < 4; ++m){
      int r = wr * 64 + m * 16 + fr;
      afh[m] = *(const bf16x8*)&Ah[r][fq * 8];
      afl[m] = *(const bf16x8*)&Al[r][fq * 8];
    }
#pragma unroll
    for (int n = 0; n < 4; ++n){
      int r = wc * 64 + n * 16 + fr;
      bfh[n] = *(const bf16x8*)&Bhs[r][fq * 8];
    }
#pragma unroll
    for (int m = 0; m < 4; ++m)
#pragma unroll
      for (int n = 0; n < 4; ++n){
        acc[m][n] = __builtin_amdgcn_mfma_f32_16x16x32_bf16(afh[m], bfh[n], acc[m][n], 0, 0, 0);
        acc[m][n] = __builtin_amdgcn_mfma_f32_16x16x32_bf16(afl[m], bfh[n], acc[m][n], 0, 0, 0);
      }
  }
#pragma unroll
  for (int m = 0; m < 4; ++m){
#pragma unroll
    for (int n = 0; n < 4; ++n){
      int col = n0 + wc * 64 + n * 16 + fr;
#pragma unroll
      for (int r = 0; r < 4; ++r){
        int row = m0 + wr * 64 + m * 16 + fq * 4 + r;
        if (row < M){
          Cb[(size_t)row * Ncols + col] = f2b(acc[m][n][r]);
        }
      }
    }
  }
}

// ---------------- GCN aggregation: bf16 gathers (8-wide MLP), writes h1 bf16 hi/lo pair ------------
__global__ __launch_bounds__(256) void k_gcn_agg(
    const unsigned short* __restrict__ h0b,
    const int* __restrict__ csr_src, const float* __restrict__ w_gcn,
    const int* __restrict__ row_ptr, const float* __restrict__ dis1,
    const float* __restrict__ b1,
    unsigned short* __restrict__ h1h, unsigned short* __restrict__ h1l, int N){
  int lane = threadIdx.x & 63;
  int r = blockIdx.x * 4 + (threadIdx.x >> 6);
  if (r >= N) return;
  float dr = dis1[r];
  ushort4 sv = ((const ushort4*)(h0b + (size_t)r * 256))[lane];
  float4 inner = make_float4(b2f(sv.x) * dr, b2f(sv.y) * dr, b2f(sv.z) * dr, b2f(sv.w) * dr);
  int e0 = row_ptr[r], e1 = row_ptr[r + 1];
  int e = e0;
  for (; e + 8 <= e1; e += 8){
    int   si[8]; float wi[8]; ushort4 vi[8];
#pragma unroll
    for (int q = 0; q < 8; ++q){ si[q] = csr_src[e + q]; wi[q] = w_gcn[e + q]; }
#pragma unroll
    for (int q = 0; q < 8; ++q) vi[q] = ((const ushort4*)(h0b + (size_t)si[q] * 256))[lane];
#pragma unroll
    for (int q = 0; q < 8; ++q){
      inner.x = fmaf(wi[q], b2f(vi[q].x), inner.x);
      inner.y = fmaf(wi[q], b2f(vi[q].y), inner.y);
      inner.z = fmaf(wi[q], b2f(vi[q].z), inner.z);
      inner.w = fmaf(wi[q], b2f(vi[q].w), inner.w);
    }
  }
  for (; e < e1; ++e){
    int s = csr_src[e];
    float w = w_gcn[e];
    ushort4 v = ((const ushort4*)(h0b + (size_t)s * 256))[lane];
    inner.x = fmaf(w, b2f(v.x), inner.x); inner.y = fmaf(w, b2f(v.y), inner.y);
    inner.z = fmaf(w, b2f(v.z), inner.z); inner.w = fmaf(w, b2f(v.w), inner.w);
  }
  float4 bb = ((const float4*)b1)[lane];
  float4 o;
  o.x = fmaxf(fmaf(inner.x, dr, bb.x), 0.f);
  o.y = fmaxf(fmaf(inner.y, dr, bb.y), 0.f);
  o.z = fmaxf(fmaf(inner.z, dr, bb.z), 0.f);
  o.w = fmaxf(fmaf(inner.w, dr, bb.w), 0.f);
  HL sx = split2(o.x), sy = split2(o.y), sz = split2(o.z), sw = split2(o.w);
  ushort4 hi; hi.x = (unsigned short)sx.h; hi.y = (unsigned short)sy.h; hi.z = (unsigned short)sz.h; hi.w = (unsigned short)sw.h;
  ushort4 lo; lo.x = (unsigned short)sx.l; lo.y = (unsigned short)sy.l; lo.z = (unsigned short)sz.l; lo.w = (unsigned short)sw.l;
  ((ushort4*)(h1h + (size_t)r * 256))[lane] = hi;
  ((ushort4*)(h1l + (size_t)r * 256))[lane] = lo;
}

// ---------------- Cheb spmm v2 (8-wide MLP): dst = Ck - sub + coef*dis2[r]*Σ w*src[s] -------------
__global__ __launch_bounds__(256) void k_cheb_spmm2(
    const unsigned short* __restrict__ Ck, int ckstride,
    const unsigned short* __restrict__ sub16, int substride,
    const float* __restrict__ subf,
    const unsigned short* __restrict__ srcb, int sstride,
    float* __restrict__ dst, unsigned short* __restrict__ dstb,
    const int* __restrict__ csr_src, const float* __restrict__ w_cheb,
    const int* __restrict__ row_ptr, const float* __restrict__ dis2, float coef, int N){
  int lane = threadIdx.x & 63;
  int r = blockIdx.x * 4 + (threadIdx.x >> 6);
  if (r >= N) return;
  float2 inner = make_float2(0.f, 0.f);
  int e0 = row_ptr[r], e1 = row_ptr[r + 1];
  int e = e0;
  for (; e + 8 <= e1; e += 8){
    int si[8]; float wi[8]; unsigned vi[8];
#pragma unroll
    for (int q = 0; q < 8; ++q){ si[q] = csr_src[e + q]; wi[q] = w_cheb[e + q]; }
#pragma unroll
    for (int q = 0; q < 8; ++q) vi[q] = ((const unsigned*)(srcb + (size_t)si[q] * sstride))[lane];
#pragma unroll
    for (int q = 0; q < 8; ++q){
      inner.x = fmaf(wi[q], __uint_as_float(vi[q] << 16), inner.x);
      inner.y = fmaf(wi[q], __uint_as_float(vi[q] & 0xFFFF0000u), inner.y);
    }
  }
  for (; e < e1; ++e){
    int s = csr_src[e];
    float w = w_cheb[e];
    unsigned v = ((const unsigned*)(srcb + (size_t)s * sstride))[lane];
    inner.x = fmaf(w, __uint_as_float(v << 16), inner.x);
    inner.y = fmaf(w, __uint_as_float(v & 0xFFFF0000u), inner.y);
  }
  float c = coef * dis2[r];
  unsigned ckv = ((const unsigned*)(Ck + (size_t)r * ckstride))[lane];
  float rx = fmaf(c, inner.x, __uint_as_float(ckv << 16));
  float ry = fmaf(c, inner.y, __uint_as_float(ckv & 0xFFFF0000u));
  if (sub16){
    unsigned sv = ((const unsigned*)(sub16 + (size_t)r * substride))[lane];
    rx -= __uint_as_float(sv << 16);
    ry -= __uint_as_float(sv & 0xFFFF0000u);
  }
  if (subf){
    float2 s2 = ((const float2*)(subf + (size_t)r * 128))[lane];
    rx -= s2.x;
    ry -= s2.y;
  }
  ((float2*)(dst + (size_t)r * 128))[lane] = make_float2(rx, ry);
  if (dstb){
    unsigned pk = (unsigned)f2b(rx) | ((unsigned)f2b(ry) << 16);
    ((unsigned*)(dstb + (size_t)r * 128))[lane] = pk;
  }
}

// ---------------- final spmm fused with feat epilogue (8-wide MLP) ----------------
__global__ __launch_bounds__(256) void k_spmm_final(
    const unsigned short* __restrict__ Ck, int ckstride,
    const float* __restrict__ subf,
    const unsigned short* __restrict__ srcb, int sstride,
    const float* __restrict__ bc, const float* __restrict__ W_out, const float* __restrict__ W_root,
    float* __restrict__ feat, float* __restrict__ p, float* __restrict__ wr,
    const int* __restrict__ csr_src, const float* __restrict__ w_cheb,
    const int* __restrict__ row_ptr, const float* __restrict__ dis2, float coef, int N){
  int lane = threadIdx.x & 63;
  int r = blockIdx.x * 4 + (threadIdx.x >> 6);
  if (r >= N) return;
  float2 inner = make_float2(0.f, 0.f);
  int e0 = row_ptr[r], e1 = row_ptr[r + 1];
  int e = e0;
  for (; e + 8 <= e1; e += 8){
    int si[8]; float wi[8]; unsigned vi[8];
#pragma unroll
    for (int q = 0; q < 8; ++q){ si[q] = csr_src[e + q]; wi[q] = w_cheb[e + q]; }
#pragma unroll
    for (int q = 0; q < 8; ++q) vi[q] = ((const unsigned*)(srcb + (size_t)si[q] * sstride))[lane];
#pragma unroll
    for (int q = 0; q < 8; ++q){
      inner.x = fmaf(wi[q], __uint_as_float(vi[q] << 16), inner.x);
      inner.y = fmaf(wi[q], __uint_as_float(vi[q] & 0xFFFF0000u), inner.y);
    }
  }
  for (; e < e1; ++e){
    int s = csr_src[e];
    float w = w_cheb[e];
    unsigned v = ((const unsigned*)(srcb + (size_t)s * sstride))[lane];
    inner.x = fmaf(w, __uint_as_float(v << 16), inner.x);
    inner.y = fmaf(w, __uint_as_float(v & 0xFFFF0000u), inner.y);
  }
  float c = coef * dis2[r];
  unsigned ckv = ((const unsigned*)(Ck + (size_t)r * ckstride))[lane];
  float rx = fmaf(c, inner.x, __uint_as_float(ckv << 16));
  float ry = fmaf(c, inner.y, __uint_as_float(ckv & 0xFFFF0000u));
  float2 s2 = ((const float2*)(subf + (size_t)r * 128))[lane];
  rx -= s2.x;
  ry -= s2.y;
  float2 bb = ((const float2*)bc)[lane];
  rx = fmaxf(rx + bb.x, 0.f);
  ry = fmaxf(ry + bb.y, 0.f);
  ((float2*)(feat + (size_t)r * 128))[lane] = make_float2(rx, ry);
  float2 wo = ((const float2*)W_out)[lane];
  float2 wrt = ((const float2*)W_root)[lane];
  float pp = rx * wo.x + ry * wo.y;
  float rr = rx * wrt.x + ry * wrt.y;
#pragma unroll
  for (int off = 32; off; off >>= 1){
    pp += __shfl_xor(pp, off);
    rr += __shfl_xor(rr, off);
  }
  if (lane == 0){ p[r] = pp; wr[r] = rr; }
}

// ---------------- ClusterGCN output (8-wide) ----------------
__global__ __launch_bounds__(256) void k_out(const float* __restrict__ p, const float* __restrict__ wr,
    const float* __restrict__ invw, const int* __restrict__ csr_src, const int* __restrict__ row_ptr,
    const float* __restrict__ b3, float* __restrict__ out, int N){
  int r = blockIdx.x * 256 + threadIdx.x;
  if (r >= N) return;
  float s = p[r];
  int e0 = row_ptr[r], e1 = row_ptr[r + 1];
  int e = e0;
  float acc[8] = {0.f,0.f,0.f,0.f,0.f,0.f,0.f,0.f};
  for (; e + 8 <= e1; e += 8){
    int si[8];
#pragma unroll
    for (int q = 0; q < 8; ++q) si[q] = csr_src[e + q];
#pragma unroll
    for (int q = 0; q < 8; ++q) acc[q] += p[si[q]];
  }
  for (; e < e1; ++e) acc[0] += p[csr_src[e]];
  s += ((acc[0]+acc[1])+(acc[2]+acc[3])) + ((acc[4]+acc[5])+(acc[6]+acc[7]));
  out[r] = invw[r] * s + wr[r] + b3[0];
}

extern "C" void kernel_launch(void* const* d_in, const int* in_sizes, int n_in,
                              void* d_out, int out_size, void* d_ws, size_t ws_size,
                              hipStream_t stream){
  const float* x      = (const float*)d_in[0];
  const void*  ei     = d_in[1];
  const float* ew     = (const float*)d_in[2];
  const float* W1     = (const float*)d_in[3];
  const float* b1     = (const float*)d_in[4];
  const float* Wc     = (const float*)d_in[5];
  const float* bc     = (const float*)d_in[6];
  const float* W_out  = (const float*)d_in[7];
  const float* W_root = (const float*)d_in[8];
  const float* b3     = (const float*)d_in[9];
  const int N = in_sizes[0] / 512;
  const int E = in_sizes[2];

  char* w = (char*)d_ws;
  auto alloc = [&](size_t bytes)->void*{ void* r = (void*)w; w += (bytes + 255) & ~(size_t)255; return r; };
  // h1 region (102.4 MB): first h1h|h1l bf16 split of GCN output; later B0|B1 fp32 Clenshaw
  unsigned short* h1h = (unsigned short*)alloc((size_t)N * 256 * 2 * 2);
  unsigned short* h1l = h1h + (size_t)N * 256;
  float* B0 = (float*)h1h;
  float* B1 = B0 + (size_t)N * 128;
  float* B2 = (float*)alloc((size_t)N * 128 * 4);
  unsigned short* CC  = (unsigned short*)alloc((size_t)N * 768 * 2);  // all 6 C_k, bf16
  unsigned short* h0b = (unsigned short*)alloc((size_t)N * 256 * 2);  // bf16 x@W1; later Bb0|Bb1
  unsigned short* Bb0 = h0b;
  unsigned short* Bb1 = h0b + (size_t)N * 128;
  float* csr_ew  = (float*)alloc((size_t)E * 4);
  float* w_gcn   = (float*)alloc((size_t)E * 4);
  float* w_cheb  = (float*)alloc((size_t)E * 4);
  int*   csr_src = (int*)  alloc((size_t)E * 4);
  int*   row_ptr = (int*)  alloc((size_t)(N + 1) * 4);
  int*   cursor  = (int*)  alloc((size_t)N * 4);
  int*   cnt     = (int*)  alloc((size_t)N * 4);
  int*   bsum    = (int*)  alloc((size_t)1024 * 4);
  float* dis1    = (float*)alloc((size_t)N * 4);
  float* dis2    = (float*)alloc((size_t)N * 4);
  float* invw    = (float*)alloc((size_t)N * 4);
  float* pbuf    = (float*)alloc((size_t)N * 4);
  float* wrbuf   = (float*)alloc((size_t)N * 4);
  short* W1t_h   = (short*)alloc((size_t)512 * 256 * 2);
  short* W1t_l   = (short*)alloc((size_t)512 * 256 * 2);
  short* Wct_h   = (short*)alloc((size_t)768 * 256 * 2);
  int*   flag    = (int*)  alloc(256);

  hipMemsetAsync(cnt, 0, (size_t)N * 4, stream);
  hipMemsetAsync(flag, 0, 4, stream);

  k_detect<<<16, 256, 0, stream>>>((const int*)ei, E, flag);
  k_count<<<ceil_div(E, 256), 256, 0, stream>>>(ei, E, flag, cnt);
  int nb = ceil_div(N, 1024);
  k_scan_part<<<nb, 256, 0, stream>>>(cnt, bsum, N);
  k_scan_bsum<<<1, 1024, 0, stream>>>(bsum, nb);
  k_scan_write<<<nb, 256, 0, stream>>>(cnt, bsum, row_ptr, cursor, N, E);
  k_fill<<<ceil_div(E, 256), 256, 0, stream>>>(ei, ew, E, flag, cursor, csr_src, csr_ew);
  k_degrees<<<ceil_div(N, 256), 256, 0, stream>>>(row_ptr, csr_ew, dis1, dis2, invw, N);
  k_norm<<<ceil_div(E, 256), 256, 0, stream>>>(csr_src, csr_ew, dis1, dis2, w_gcn, w_cheb, E);

  // weight prep
  k_prep_w<<<ceil_div(512 * 256, 256), 256, 0, stream>>>(W1, W1t_h, W1t_l, 512, 256);
  k_prep_wc<<<ceil_div(768 * 256, 256), 256, 0, stream>>>(Wc, Wct_h);

  // ---- GCNConv: h0b = bf16(x@W1); h1(hi/lo) = split(relu(agg + b1)) ----
  k_gemm_mfma<<<dim3(ceil_div(N, 128), 2), 256, 0, stream>>>(x, W1t_h, W1t_l, h0b, N, 256, 512);
  k_gcn_agg<<<ceil_div(N, 4), 256, 0, stream>>>(h0b, csr_src, w_gcn, row_ptr, dis1, b1, h1h, h1l, N);

  // ---- fused Cheb projection: CC[N][768] = bf16(h1 @ [Wc0|..|Wc5]), XCD-swizzled 1D grid ----
  int nbm = ceil_div(N, 128);
  int grid2 = 8 * 6 * ceil_div(nbm, 8);
  k_gemm_mfma2<<<grid2, 256, 0, stream>>>(h1h, h1l, Wct_h, CC, N, 768, 256, nbm);

  // ---- Clenshaw (width 128): b_k = C_k - b_{k+2} + 2L b_{k+1} ----
  auto spmm = [&](const unsigned short* Ck, const unsigned short* s16, int s16s, const float* sf,
                  const unsigned short* src, int ss, float* dst, unsigned short* dstb, float coef){
    k_cheb_spmm2<<<ceil_div(N, 4), 256, 0, stream>>>(Ck, 768, s16, s16s, sf, src, ss, dst, dstb,
        csr_src, w_cheb, row_ptr, dis2, coef, N);
  };
  // b4 = C4 + 2L b5   (b5 = CC5 in place)
  spmm(CC + 4*128, nullptr, 0, nullptr, CC + 5*128, 768, B0, Bb0, -2.f);
  // b3 = C3 - b5 + 2L b4
  spmm(CC + 3*128, CC + 5*128, 768, nullptr, Bb0, 128, B1, Bb1, -2.f);
  // b2 = C2 - b4 + 2L b3
  spmm(CC + 2*128, nullptr, 0, B0, Bb1, 128, B2, Bb0, -2.f);
  // b1 = C1 - b3 + 2L b2
  spmm(CC + 1*128, nullptr, 0, B1, Bb0, 128, B0, Bb1, -2.f);

  // ---- final: res = C0 - b2 + L b1, fused with feat/p/wr epilogue ----
  float* out  = (float*)d_out;
  float* feat = out + N;
  k_spmm_final<<<ceil_div(N, 4), 256, 0, stream>>>(CC + 0*128, 768, B2, Bb1, 128,
      bc, W_out, W_root, feat, pbuf, wrbuf, csr_src, w_cheb, row_ptr, dis2, -1.f, N);
  k_out<<<ceil_div(N, 256), 256, 0, stream>>>(pbuf, wrbuf, invw, csr_src, row_ptr, b3, out, N);
}

// Round 11
// 1049.178 us; speedup vs baseline: 2.0123x; 1.0186x over previous
//
#include <hip/hip_runtime.h>
#include <cstdint>
#include <cstddef>

typedef __attribute__((ext_vector_type(8))) short bf16x8;
typedef __attribute__((ext_vector_type(4))) float f32x4;

static inline int ceil_div(int a, int b){ return (a + b - 1) / b; }

struct HL { short h, l; };
__device__ inline HL split2(float a){
  unsigned u = __float_as_uint(a);
  unsigned hb = (u + 0x8000u) & 0xFFFF0000u;
  float r = a - __uint_as_float(hb);
  HL o;
  o.h = (short)(hb >> 16);
  o.l = (short)((__float_as_uint(r) + 0x8000u) >> 16);
  return o;
}

__device__ inline unsigned short f2b(float f){            // fp32 -> bf16 (RNE)
  unsigned u = __float_as_uint(f);
  unsigned r = u + 0x7FFFu + ((u >> 16) & 1u);
  return (unsigned short)(r >> 16);
}
__device__ inline float b2f(unsigned short s){
  return __uint_as_float((unsigned)s << 16);
}

// ---------------- dtype detection (int64 vs int32 edge_index) ----------------
__global__ __launch_bounds__(256) void k_detect(const int* __restrict__ ei32, int E, int* __restrict__ flag){
  int t = blockIdx.x * 256 + threadIdx.x;
  if (t < 4096) {
    long long idx = 2LL * t + 1;
    if (idx < 2LL * E && ei32[idx] != 0) atomicOr(flag, 1);
  }
}

// ---------------- CSR build ----------------
__global__ __launch_bounds__(256) void k_count(const void* __restrict__ ei, int E,
                                               const int* __restrict__ flag, int* __restrict__ cnt){
  int e = blockIdx.x * 256 + threadIdx.x;
  if (e >= E) return;
  int dst = (*flag) ? ((const int*)ei)[(size_t)E + e]
                    : (int)((const long long*)ei)[(size_t)E + e];
  atomicAdd(&cnt[dst], 1);
}

// ---- 3-pass device-wide exclusive scan over cnt[N] -> row_ptr (+cursor copy) ----
__global__ __launch_bounds__(256) void k_scan_part(const int* __restrict__ cnt, int* __restrict__ bsum, int N){
  int base = blockIdx.x * 1024 + threadIdx.x * 4;
  int s = 0;
  if (base + 4 <= N){
    int4 v = *(const int4*)(cnt + base);
    s = v.x + v.y + v.z + v.w;
  } else {
    for (int i = base; i < N; ++i) s += cnt[i];
  }
#pragma unroll
  for (int off = 32; off; off >>= 1) s += __shfl_xor(s, off);
  __shared__ int ws[4];
  if ((threadIdx.x & 63) == 0) ws[threadIdx.x >> 6] = s;
  __syncthreads();
  if (threadIdx.x == 0) bsum[blockIdx.x] = ws[0] + ws[1] + ws[2] + ws[3];
}

__global__ __launch_bounds__(1024) void k_scan_bsum(int* __restrict__ bsum, int nb){
  __shared__ int sh[1024];
  int t = threadIdx.x;
  int v = (t < nb) ? bsum[t] : 0;
  sh[t] = v; __syncthreads();
  for (int off = 1; off < 1024; off <<= 1){
    int u = (t >= off) ? sh[t - off] : 0;
    __syncthreads();
    sh[t] += u;
    __syncthreads();
  }
  if (t < nb) bsum[t] = sh[t] - v;   // exclusive
}

__global__ __launch_bounds__(256) void k_scan_write(const int* __restrict__ cnt, const int* __restrict__ bsum,
                                                    int* __restrict__ row_ptr, int* __restrict__ cursor,
                                                    int N, int E){
  int t = threadIdx.x;
  int base = blockIdx.x * 1024 + t * 4;
  int v0 = 0, v1 = 0, v2 = 0, v3 = 0;
  if (base + 4 <= N){
    int4 v = *(const int4*)(cnt + base);
    v0 = v.x; v1 = v.y; v2 = v.z; v3 = v.w;
  } else {
    if (base + 0 < N) v0 = cnt[base + 0];
    if (base + 1 < N) v1 = cnt[base + 1];
    if (base + 2 < N) v2 = cnt[base + 2];
    if (base + 3 < N) v3 = cnt[base + 3];
  }
  int s = v0 + v1 + v2 + v3;
  int lane = t & 63;
  int inc = s;
#pragma unroll
  for (int off = 1; off < 64; off <<= 1){
    int u = __shfl_up(inc, off);
    if (lane >= off) inc += u;
  }
  __shared__ int ws[4];
  if (lane == 63) ws[t >> 6] = inc;
  __syncthreads();
  int wid = t >> 6;
  int woff = 0;
  for (int i = 0; i < wid; ++i) woff += ws[i];
  int exc = bsum[blockIdx.x] + woff + inc - s;
  int p0 = exc, p1 = p0 + v0, p2 = p1 + v1, p3 = p2 + v2;
  if (base + 0 < N){ row_ptr[base + 0] = p0; cursor[base + 0] = p0; }
  if (base + 1 < N){ row_ptr[base + 1] = p1; cursor[base + 1] = p1; }
  if (base + 2 < N){ row_ptr[base + 2] = p2; cursor[base + 2] = p2; }
  if (base + 3 < N){ row_ptr[base + 3] = p3; cursor[base + 3] = p3; }
  if (blockIdx.x == 0 && t == 0) row_ptr[N] = E;
}

__global__ __launch_bounds__(256) void k_fill(const void* __restrict__ ei, const float* __restrict__ ew, int E,
                                              const int* __restrict__ flag, int* __restrict__ cursor,
                                              int* __restrict__ csr_src, float* __restrict__ csr_ew){
  int e = blockIdx.x * 256 + threadIdx.x;
  if (e >= E) return;
  int src, dst;
  if (*flag){ src = ((const int*)ei)[e]; dst = ((const int*)ei)[(size_t)E + e]; }
  else      { src = (int)((const long long*)ei)[e]; dst = (int)((const long long*)ei)[(size_t)E + e]; }
  int pos = atomicAdd(&cursor[dst], 1);
  csr_src[pos] = src;
  csr_ew[pos] = ew[e];
}

__global__ __launch_bounds__(256) void k_degrees(const int* __restrict__ row_ptr, const float* __restrict__ csr_ew,
                                                 float* __restrict__ dis1, float* __restrict__ dis2,
                                                 float* __restrict__ invw, int N){
  int r = blockIdx.x * 256 + threadIdx.x;
  if (r >= N) return;
  int e0 = row_ptr[r], e1 = row_ptr[r + 1];
  float s = 0.f;
  for (int e = e0; e < e1; ++e) s += csr_ew[e];
  dis1[r] = rsqrtf(s + 1.0f);
  dis2[r] = (s > 0.0f) ? rsqrtf(s) : 0.0f;
  invw[r] = 1.0f / (float)(e1 - e0 + 1);
}

// ---------------- edge norms ----------------
__global__ __launch_bounds__(256) void k_norm(const int* __restrict__ csr_src, const float* __restrict__ csr_ew,
                                              const float* __restrict__ dis1, const float* __restrict__ dis2,
                                              float* __restrict__ w_gcn, float* __restrict__ w_cheb, int E){
  int e = blockIdx.x * 256 + threadIdx.x;
  if (e >= E) return;
  int s = csr_src[e];
  float w = csr_ew[e];
  w_gcn[e]  = w * dis1[s];
  w_cheb[e] = w * dis2[s];
}

// ---------------- weight prep: W [K][N] fp32 -> Wh/Wl [N][K] bf16 split ----------------
__global__ __launch_bounds__(256) void k_prep_w(const float* __restrict__ W, short* __restrict__ Wh,
                                                short* __restrict__ Wl, int K, int N){
  int idx = blockIdx.x * 256 + threadIdx.x;
  if (idx >= K * N) return;
  int n = idx / K, k = idx - n * K;
  HL s = split2(W[(size_t)k * N + n]);
  Wh[idx] = s.h; Wl[idx] = s.l;
}

// ---------------- Wc prep: Wc [6][256][128] -> [768][256] bf16 (single, RNE) ----------------
__global__ __launch_bounds__(256) void k_prep_wc(const float* __restrict__ Wc, short* __restrict__ Wh){
  int idx = blockIdx.x * 256 + threadIdx.x;
  if (idx >= 768 * 256) return;
  int n = idx >> 8, k = idx & 255;
  Wh[idx] = (short)f2b(Wc[(size_t)(n >> 7) * 256 * 128 + (size_t)k * 128 + (n & 127)]);
}

// ---------------- MFMA GEMM 1: A = bf16(x), B = W1 split; 2-term; A reg-prefetch; XCD swizzle ----
__global__ __launch_bounds__(256) void k_gemm_mfma(
    const float* __restrict__ A,
    const short* __restrict__ Bh, const short* __restrict__ Bl,
    unsigned short* __restrict__ Cb,
    int M, int Ncols, int K, int nbm)
{
  __shared__ short Ah[128][40];
  __shared__ short Bhs[128][40];
  __shared__ short Bls[128][40];
  int bid = blockIdx.x;
  int g = bid & 7, j = bid >> 3;
  int m_tile = g + 8 * (j >> 1);
  int n_tile = j & 1;
  if (m_tile >= nbm) return;
  int m0 = m_tile * 128, n0 = n_tile * 128;
  int t = threadIdx.x;
  int lane = t & 63, wid = t >> 6;
  int wr = wid >> 1, wc = wid & 1;
  int fr = lane & 15, fq = lane >> 4;
  int srow = t >> 1, skh = (t & 1) << 4;

  f32x4 acc[4][4];
#pragma unroll
  for (int i = 0; i < 4; ++i)
#pragma unroll
    for (int jj = 0; jj < 4; ++jj) acc[i][jj] = (f32x4){0.f, 0.f, 0.f, 0.f};

  bool aval = (m0 + srow) < M;
  const float* Aptr = A + (size_t)(m0 + srow) * K + skh;
  const short* Bhp = Bh + (size_t)(n0 + srow) * K + skh;
  const short* Blp = Bl + (size_t)(n0 + srow) * K + skh;

  float4 a0, a1, a2, a3;
  if (aval){
    const float4* ap = (const float4*)Aptr;
    a0 = ap[0]; a1 = ap[1]; a2 = ap[2]; a3 = ap[3];
  } else a0 = a1 = a2 = a3 = make_float4(0.f, 0.f, 0.f, 0.f);

  for (int k0 = 0; k0 < K; k0 += 32){
    // stage current A regs (convert) + B demand loads
    bf16x8 h0, h1;
    h0[0]=(short)f2b(a0.x); h0[1]=(short)f2b(a0.y); h0[2]=(short)f2b(a0.z); h0[3]=(short)f2b(a0.w);
    h0[4]=(short)f2b(a1.x); h0[5]=(short)f2b(a1.y); h0[6]=(short)f2b(a1.z); h0[7]=(short)f2b(a1.w);
    h1[0]=(short)f2b(a2.x); h1[1]=(short)f2b(a2.y); h1[2]=(short)f2b(a2.z); h1[3]=(short)f2b(a2.w);
    h1[4]=(short)f2b(a3.x); h1[5]=(short)f2b(a3.y); h1[6]=(short)f2b(a3.z); h1[7]=(short)f2b(a3.w);
    *(bf16x8*)&Ah[srow][skh]     = h0;
    *(bf16x8*)&Ah[srow][skh + 8] = h1;
    {
      const bf16x8* bp = (const bf16x8*)(Bhp + k0);
      *(bf16x8*)&Bhs[srow][skh]     = bp[0];
      *(bf16x8*)&Bhs[srow][skh + 8] = bp[1];
      const bf16x8* cp = (const bf16x8*)(Blp + k0);
      *(bf16x8*)&Bls[srow][skh]     = cp[0];
      *(bf16x8*)&Bls[srow][skh + 8] = cp[1];
    }
    __syncthreads();
    // prefetch next A tile (latency hides under MFMA below)
    bool more = (k0 + 32) < K;
    float4 n0v, n1v, n2v, n3v;
    if (more && aval){
      const float4* ap = (const float4*)(Aptr + k0 + 32);
      n0v = ap[0]; n1v = ap[1]; n2v = ap[2]; n3v = ap[3];
    } else n0v = n1v = n2v = n3v = make_float4(0.f, 0.f, 0.f, 0.f);
    // frags + MFMA
    bf16x8 afh[4], bfh[4], bfl[4];
#pragma unroll
    for (int m = 0; m < 4; ++m){
      int r = wr * 64 + m * 16 + fr;
      afh[m] = *(const bf16x8*)&Ah[r][fq * 8];
    }
#pragma unroll
    for (int n = 0; n < 4; ++n){
      int r = wc * 64 + n * 16 + fr;
      bfh[n] = *(const bf16x8*)&Bhs[r][fq * 8];
      bfl[n] = *(const bf16x8*)&Bls[r][fq * 8];
    }
#pragma unroll
    for (int m = 0; m < 4; ++m)
#pragma unroll
      for (int n = 0; n < 4; ++n){
        acc[m][n] = __builtin_amdgcn_mfma_f32_16x16x32_bf16(afh[m], bfh[n], acc[m][n], 0, 0, 0);
        acc[m][n] = __builtin_amdgcn_mfma_f32_16x16x32_bf16(afh[m], bfl[n], acc[m][n], 0, 0, 0);
      }
    __syncthreads();
    a0 = n0v; a1 = n1v; a2 = n2v; a3 = n3v;
  }
#pragma unroll
  for (int m = 0; m < 4; ++m){
#pragma unroll
    for (int n = 0; n < 4; ++n){
      int col = n0 + wc * 64 + n * 16 + fr;
#pragma unroll
      for (int r = 0; r < 4; ++r){
        int row = m0 + wr * 64 + m * 16 + fq * 4 + r;
        if (row < M){
          Cb[(size_t)row * Ncols + col] = f2b(acc[m][n][r]);
        }
      }
    }
  }
}

// ---------------- MFMA GEMM 2: A = h1 split, B = bf16(Wc); 2-term; A reg-prefetch; XCD swizzle;
// ---------------- n_tile==5 also writes compact C5c[N][128] for the first Clenshaw gather -------
__global__ __launch_bounds__(256) void k_gemm_mfma2(
    const unsigned short* __restrict__ Ahg, const unsigned short* __restrict__ Alg,
    const short* __restrict__ Bh,
    unsigned short* __restrict__ Cb, unsigned short* __restrict__ C5c,
    int M, int Ncols, int K, int nbm)
{
  __shared__ short Ah[128][40];
  __shared__ short Al[128][40];
  __shared__ short Bhs[128][40];
  int bid = blockIdx.x;
  int g = bid & 7, j = bid >> 3;
  int m_tile = g + 8 * (j / 6);
  int n_tile = j - 6 * (j / 6);
  if (m_tile >= nbm) return;
  int m0 = m_tile * 128, n0 = n_tile * 128;
  int t = threadIdx.x;
  int lane = t & 63, wid = t >> 6;
  int wr = wid >> 1, wc = wid & 1;
  int fr = lane & 15, fq = lane >> 4;
  int srow = t >> 1, skh = (t & 1) << 4;

  f32x4 acc[4][4];
#pragma unroll
  for (int i = 0; i < 4; ++i)
#pragma unroll
    for (int jj = 0; jj < 4; ++jj) acc[i][jj] = (f32x4){0.f, 0.f, 0.f, 0.f};

  bool aval = (m0 + srow) < M;
  const unsigned short* Ahp = Ahg + (size_t)(m0 + srow) * K + skh;
  const unsigned short* Alp = Alg + (size_t)(m0 + srow) * K + skh;
  const short* Bhp = Bh + (size_t)(n0 + srow) * K + skh;

  bf16x8 ch0, ch1, cl0, cl1;
  if (aval){
    const bf16x8* ah = (const bf16x8*)Ahp;
    ch0 = ah[0]; ch1 = ah[1];
    const bf16x8* al = (const bf16x8*)Alp;
    cl0 = al[0]; cl1 = al[1];
  } else {
    bf16x8 z = (bf16x8){0,0,0,0,0,0,0,0};
    ch0 = ch1 = cl0 = cl1 = z;
  }

  for (int k0 = 0; k0 < K; k0 += 32){
    *(bf16x8*)&Ah[srow][skh]     = ch0;
    *(bf16x8*)&Ah[srow][skh + 8] = ch1;
    *(bf16x8*)&Al[srow][skh]     = cl0;
    *(bf16x8*)&Al[srow][skh + 8] = cl1;
    {
      const bf16x8* bp = (const bf16x8*)(Bhp + k0);
      *(bf16x8*)&Bhs[srow][skh]     = bp[0];
      *(bf16x8*)&Bhs[srow][skh + 8] = bp[1];
    }
    __syncthreads();
    // prefetch next A tile
    bool more = (k0 + 32) < K;
    bf16x8 nh0, nh1, nl0, nl1;
    if (more && aval){
      const bf16x8* ah = (const bf16x8*)(Ahp + k0 + 32);
      nh0 = ah[0]; nh1 = ah[1];
      const bf16x8* al = (const bf16x8*)(Alp + k0 + 32);
      nl0 = al[0]; nl1 = al[1];
    } else {
      bf16x8 z = (bf16x8){0,0,0,0,0,0,0,0};
      nh0 = nh1 = nl0 = nl1 = z;
    }
    bf16x8 afh[4], afl[4], bfh[4];
#pragma unroll
    for (int m = 0; m < 4; ++m){
      int r = wr * 64 + m * 16 + fr;
      afh[m] = *(const bf16x8*)&Ah[r][fq * 8];
      afl[m] = *(const bf16x8*)&Al[r][fq * 8];
    }
#pragma unroll
    for (int n = 0; n < 4; ++n){
      int r = wc * 64 + n * 16 + fr;
      bfh[n] = *(const bf16x8*)&Bhs[r][fq * 8];
    }
#pragma unroll
    for (int m = 0; m < 4; ++m)
#pragma unroll
      for (int n = 0; n < 4; ++n){
        acc[m][n] = __builtin_amdgcn_mfma_f32_16x16x32_bf16(afh[m], bfh[n], acc[m][n], 0, 0, 0);
        acc[m][n] = __builtin_amdgcn_mfma_f32_16x16x32_bf16(afl[m], bfh[n], acc[m][n], 0, 0, 0);
      }
    __syncthreads();
    ch0 = nh0; ch1 = nh1; cl0 = nl0; cl1 = nl1;
  }
#pragma unroll
  for (int m = 0; m < 4; ++m){
#pragma unroll
    for (int n = 0; n < 4; ++n){
      int col = n0 + wc * 64 + n * 16 + fr;
#pragma unroll
      for (int r = 0; r < 4; ++r){
        int row = m0 + wr * 64 + m * 16 + fq * 4 + r;
        if (row < M){
          unsigned short v = f2b(acc[m][n][r]);
          Cb[(size_t)row * Ncols + col] = v;
          if (n_tile == 5) C5c[(size_t)row * 128 + (col - 640)] = v;
        }
      }
    }
  }
}

// ---------------- GCN aggregation: bf16 gathers (8-wide MLP), writes h1 bf16 hi/lo pair ------------
__global__ __launch_bounds__(256) void k_gcn_agg(
    const unsigned short* __restrict__ h0b,
    const int* __restrict__ csr_src, const float* __restrict__ w_gcn,
    const int* __restrict__ row_ptr, const float* __restrict__ dis1,
    const float* __restrict__ b1,
    unsigned short* __restrict__ h1h, unsigned short* __restrict__ h1l, int N){
  int lane = threadIdx.x & 63;
  int r = blockIdx.x * 4 + (threadIdx.x >> 6);
  if (r >= N) return;
  float dr = dis1[r];
  ushort4 sv = ((const ushort4*)(h0b + (size_t)r * 256))[lane];
  float4 inner = make_float4(b2f(sv.x) * dr, b2f(sv.y) * dr, b2f(sv.z) * dr, b2f(sv.w) * dr);
  int e0 = row_ptr[r], e1 = row_ptr[r + 1];
  int e = e0;
  for (; e + 8 <= e1; e += 8){
    int   si[8]; float wi[8]; ushort4 vi[8];
#pragma unroll
    for (int q = 0; q < 8; ++q){ si[q] = csr_src[e + q]; wi[q] = w_gcn[e + q]; }
#pragma unroll
    for (int q = 0; q < 8; ++q) vi[q] = ((const ushort4*)(h0b + (size_t)si[q] * 256))[lane];
#pragma unroll
    for (int q = 0; q < 8; ++q){
      inner.x = fmaf(wi[q], b2f(vi[q].x), inner.x);
      inner.y = fmaf(wi[q], b2f(vi[q].y), inner.y);
      inner.z = fmaf(wi[q], b2f(vi[q].z), inner.z);
      inner.w = fmaf(wi[q], b2f(vi[q].w), inner.w);
    }
  }
  for (; e < e1; ++e){
    int s = csr_src[e];
    float w = w_gcn[e];
    ushort4 v = ((const ushort4*)(h0b + (size_t)s * 256))[lane];
    inner.x = fmaf(w, b2f(v.x), inner.x); inner.y = fmaf(w, b2f(v.y), inner.y);
    inner.z = fmaf(w, b2f(v.z), inner.z); inner.w = fmaf(w, b2f(v.w), inner.w);
  }
  float4 bb = ((const float4*)b1)[lane];
  float4 o;
  o.x = fmaxf(fmaf(inner.x, dr, bb.x), 0.f);
  o.y = fmaxf(fmaf(inner.y, dr, bb.y), 0.f);
  o.z = fmaxf(fmaf(inner.z, dr, bb.z), 0.f);
  o.w = fmaxf(fmaf(inner.w, dr, bb.w), 0.f);
  HL sx = split2(o.x), sy = split2(o.y), sz = split2(o.z), sw = split2(o.w);
  ushort4 hi; hi.x = (unsigned short)sx.h; hi.y = (unsigned short)sy.h; hi.z = (unsigned short)sz.h; hi.w = (unsigned short)sw.h;
  ushort4 lo; lo.x = (unsigned short)sx.l; lo.y = (unsigned short)sy.l; lo.z = (unsigned short)sz.l; lo.w = (unsigned short)sw.l;
  ((ushort4*)(h1h + (size_t)r * 256))[lane] = hi;
  ((ushort4*)(h1l + (size_t)r * 256))[lane] = lo;
}

// ---------------- Cheb spmm v2 (8-wide MLP): dst = Ck - sub + coef*dis2[r]*Σ w*src[s] -------------
__global__ __launch_bounds__(256) void k_cheb_spmm2(
    const unsigned short* __restrict__ Ck, int ckstride,
    const unsigned short* __restrict__ sub16, int substride,
    const float* __restrict__ subf,
    const unsigned short* __restrict__ srcb, int sstride,
    float* __restrict__ dst, unsigned short* __restrict__ dstb,
    const int* __restrict__ csr_src, const float* __restrict__ w_cheb,
    const int* __restrict__ row_ptr, const float* __restrict__ dis2, float coef, int N){
  int lane = threadIdx.x & 63;
  int r = blockIdx.x * 4 + (threadIdx.x >> 6);
  if (r >= N) return;
  float2 inner = make_float2(0.f, 0.f);
  int e0 = row_ptr[r], e1 = row_ptr[r + 1];
  int e = e0;
  for (; e + 8 <= e1; e += 8){
    int si[8]; float wi[8]; unsigned vi[8];
#pragma unroll
    for (int q = 0; q < 8; ++q){ si[q] = csr_src[e + q]; wi[q] = w_cheb[e + q]; }
#pragma unroll
    for (int q = 0; q < 8; ++q) vi[q] = ((const unsigned*)(srcb + (size_t)si[q] * sstride))[lane];
#pragma unroll
    for (int q = 0; q < 8; ++q){
      inner.x = fmaf(wi[q], __uint_as_float(vi[q] << 16), inner.x);
      inner.y = fmaf(wi[q], __uint_as_float(vi[q] & 0xFFFF0000u), inner.y);
    }
  }
  for (; e < e1; ++e){
    int s = csr_src[e];
    float w = w_cheb[e];
    unsigned v = ((const unsigned*)(srcb + (size_t)s * sstride))[lane];
    inner.x = fmaf(w, __uint_as_float(v << 16), inner.x);
    inner.y = fmaf(w, __uint_as_float(v & 0xFFFF0000u), inner.y);
  }
  float c = coef * dis2[r];
  unsigned ckv = ((const unsigned*)(Ck + (size_t)r * ckstride))[lane];
  float rx = fmaf(c, inner.x, __uint_as_float(ckv << 16));
  float ry = fmaf(c, inner.y, __uint_as_float(ckv & 0xFFFF0000u));
  if (sub16){
    unsigned sv = ((const unsigned*)(sub16 + (size_t)r * substride))[lane];
    rx -= __uint_as_float(sv << 16);
    ry -= __uint_as_float(sv & 0xFFFF0000u);
  }
  if (subf){
    float2 s2 = ((const float2*)(subf + (size_t)r * 128))[lane];
    rx -= s2.x;
    ry -= s2.y;
  }
  ((float2*)(dst + (size_t)r * 128))[lane] = make_float2(rx, ry);
  if (dstb){
    unsigned pk = (unsigned)f2b(rx) | ((unsigned)f2b(ry) << 16);
    ((unsigned*)(dstb + (size_t)r * 128))[lane] = pk;
  }
}

// ---------------- final spmm fused with feat epilogue (8-wide MLP) ----------------
__global__ __launch_bounds__(256) void k_spmm_final(
    const unsigned short* __restrict__ Ck, int ckstride,
    const float* __restrict__ subf,
    const unsigned short* __restrict__ srcb, int sstride,
    const float* __restrict__ bc, const float* __restrict__ W_out, const float* __restrict__ W_root,
    float* __restrict__ feat, float* __restrict__ p, float* __restrict__ wr,
    const int* __restrict__ csr_src, const float* __restrict__ w_cheb,
    const int* __restrict__ row_ptr, const float* __restrict__ dis2, float coef, int N){
  int lane = threadIdx.x & 63;
  int r = blockIdx.x * 4 + (threadIdx.x >> 6);
  if (r >= N) return;
  float2 inner = make_float2(0.f, 0.f);
  int e0 = row_ptr[r], e1 = row_ptr[r + 1];
  int e = e0;
  for (; e + 8 <= e1; e += 8){
    int si[8]; float wi[8]; unsigned vi[8];
#pragma unroll
    for (int q = 0; q < 8; ++q){ si[q] = csr_src[e + q]; wi[q] = w_cheb[e + q]; }
#pragma unroll
    for (int q = 0; q < 8; ++q) vi[q] = ((const unsigned*)(srcb + (size_t)si[q] * sstride))[lane];
#pragma unroll
    for (int q = 0; q < 8; ++q){
      inner.x = fmaf(wi[q], __uint_as_float(vi[q] << 16), inner.x);
      inner.y = fmaf(wi[q], __uint_as_float(vi[q] & 0xFFFF0000u), inner.y);
    }
  }
  for (; e < e1; ++e){
    int s = csr_src[e];
    float w = w_cheb[e];
    unsigned v = ((const unsigned*)(srcb + (size_t)s * sstride))[lane];
    inner.x = fmaf(w, __uint_as_float(v << 16), inner.x);
    inner.y = fmaf(w, __uint_as_float(v & 0xFFFF0000u), inner.y);
  }
  float c = coef * dis2[r];
  unsigned ckv = ((const unsigned*)(Ck + (size_t)r * ckstride))[lane];
  float rx = fmaf(c, inner.x, __uint_as_float(ckv << 16));
  float ry = fmaf(c, inner.y, __uint_as_float(ckv & 0xFFFF0000u));
  float2 s2 = ((const float2*)(subf + (size_t)r * 128))[lane];
  rx -= s2.x;
  ry -= s2.y;
  float2 bb = ((const float2*)bc)[lane];
  rx = fmaxf(rx + bb.x, 0.f);
  ry = fmaxf(ry + bb.y, 0.f);
  ((float2*)(feat + (size_t)r * 128))[lane] = make_float2(rx, ry);
  float2 wo = ((const float2*)W_out)[lane];
  float2 wrt = ((const float2*)W_root)[lane];
  float pp = rx * wo.x + ry * wo.y;
  float rr = rx * wrt.x + ry * wrt.y;
#pragma unroll
  for (int off = 32; off; off >>= 1){
    pp += __shfl_xor(pp, off);
    rr += __shfl_xor(rr, off);
  }
  if (lane == 0){ p[r] = pp; wr[r] = rr; }
}

// ---------------- ClusterGCN output (8-wide) ----------------
__global__ __launch_bounds__(256) void k_out(const float* __restrict__ p, const float* __restrict__ wr,
    const float* __restrict__ invw, const int* __restrict__ csr_src, const int* __restrict__ row_ptr,
    const float* __restrict__ b3, float* __restrict__ out, int N){
  int r = blockIdx.x * 256 + threadIdx.x;
  if (r >= N) return;
  float s = p[r];
  int e0 = row_ptr[r], e1 = row_ptr[r + 1];
  int e = e0;
  float acc[8] = {0.f,0.f,0.f,0.f,0.f,0.f,0.f,0.f};
  for (; e + 8 <= e1; e += 8){
    int si[8];
#pragma unroll
    for (int q = 0; q < 8; ++q) si[q] = csr_src[e + q];
#pragma unroll
    for (int q = 0; q < 8; ++q) acc[q] += p[si[q]];
  }
  for (; e < e1; ++e) acc[0] += p[csr_src[e]];
  s += ((acc[0]+acc[1])+(acc[2]+acc[3])) + ((acc[4]+acc[5])+(acc[6]+acc[7]));
  out[r] = invw[r] * s + wr[r] + b3[0];
}

extern "C" void kernel_launch(void* const* d_in, const int* in_sizes, int n_in,
                              void* d_out, int out_size, void* d_ws, size_t ws_size,
                              hipStream_t stream){
  const float* x      = (const float*)d_in[0];
  const void*  ei     = d_in[1];
  const float* ew     = (const float*)d_in[2];
  const float* W1     = (const float*)d_in[3];
  const float* b1     = (const float*)d_in[4];
  const float* Wc     = (const float*)d_in[5];
  const float* bc     = (const float*)d_in[6];
  const float* W_out  = (const float*)d_in[7];
  const float* W_root = (const float*)d_in[8];
  const float* b3     = (const float*)d_in[9];
  const int N = in_sizes[0] / 512;
  const int E = in_sizes[2];

  char* w = (char*)d_ws;
  auto alloc = [&](size_t bytes)->void*{ void* r = (void*)w; w += (bytes + 255) & ~(size_t)255; return r; };
  // h1 region (102.4 MB): first h1h|h1l bf16 split of GCN output; later B0|B1 fp32 Clenshaw
  unsigned short* h1h = (unsigned short*)alloc((size_t)N * 256 * 2 * 2);
  unsigned short* h1l = h1h + (size_t)N * 256;
  float* B0 = (float*)h1h;
  float* B1 = B0 + (size_t)N * 128;
  float* B2 = (float*)alloc((size_t)N * 128 * 4);
  // C5c (compact bf16 copy of C5, 25.6 MB) aliases B2's region: dead before B2 is first written.
  unsigned short* C5c = (unsigned short*)B2;
  unsigned short* CC  = (unsigned short*)alloc((size_t)N * 768 * 2);  // all 6 C_k, bf16
  unsigned short* h0b = (unsigned short*)alloc((size_t)N * 256 * 2);  // bf16 x@W1; later Bb0|Bb1
  unsigned short* Bb0 = h0b;
  unsigned short* Bb1 = h0b + (size_t)N * 128;
  float* csr_ew  = (float*)alloc((size_t)E * 4);
  float* w_gcn   = (float*)alloc((size_t)E * 4);
  float* w_cheb  = (float*)alloc((size_t)E * 4);
  int*   csr_src = (int*)  alloc((size_t)E * 4);
  int*   row_ptr = (int*)  alloc((size_t)(N + 1) * 4);
  int*   cursor  = (int*)  alloc((size_t)N * 4);
  int*   cnt     = (int*)  alloc((size_t)N * 4);
  int*   bsum    = (int*)  alloc((size_t)1024 * 4);
  float* dis1    = (float*)alloc((size_t)N * 4);
  float* dis2    = (float*)alloc((size_t)N * 4);
  float* invw    = (float*)alloc((size_t)N * 4);
  float* pbuf    = (float*)alloc((size_t)N * 4);
  float* wrbuf   = (float*)alloc((size_t)N * 4);
  short* W1t_h   = (short*)alloc((size_t)512 * 256 * 2);
  short* W1t_l   = (short*)alloc((size_t)512 * 256 * 2);
  short* Wct_h   = (short*)alloc((size_t)768 * 256 * 2);
  int*   flag    = (int*)  alloc(256);

  hipMemsetAsync(cnt, 0, (size_t)N * 4, stream);
  hipMemsetAsync(flag, 0, 4, stream);

  k_detect<<<16, 256, 0, stream>>>((const int*)ei, E, flag);
  k_count<<<ceil_div(E, 256), 256, 0, stream>>>(ei, E, flag, cnt);
  int nb = ceil_div(N, 1024);
  k_scan_part<<<nb, 256, 0, stream>>>(cnt, bsum, N);
  k_scan_bsum<<<1, 1024, 0, stream>>>(bsum, nb);
  k_scan_write<<<nb, 256, 0, stream>>>(cnt, bsum, row_ptr, cursor, N, E);
  k_fill<<<ceil_div(E, 256), 256, 0, stream>>>(ei, ew, E, flag, cursor, csr_src, csr_ew);
  k_degrees<<<ceil_div(N, 256), 256, 0, stream>>>(row_ptr, csr_ew, dis1, dis2, invw, N);
  k_norm<<<ceil_div(E, 256), 256, 0, stream>>>(csr_src, csr_ew, dis1, dis2, w_gcn, w_cheb, E);

  // weight prep
  k_prep_w<<<ceil_div(512 * 256, 256), 256, 0, stream>>>(W1, W1t_h, W1t_l, 512, 256);
  k_prep_wc<<<ceil_div(768 * 256, 256), 256, 0, stream>>>(Wc, Wct_h);

  // ---- GCNConv: h0b = bf16(x@W1); h1(hi/lo) = split(relu(agg + b1)) ----
  int nbm = ceil_div(N, 128);
  int grid1 = 8 * 2 * ceil_div(nbm, 8);
  k_gemm_mfma<<<grid1, 256, 0, stream>>>(x, W1t_h, W1t_l, h0b, N, 256, 512, nbm);
  k_gcn_agg<<<ceil_div(N, 4), 256, 0, stream>>>(h0b, csr_src, w_gcn, row_ptr, dis1, b1, h1h, h1l, N);

  // ---- fused Cheb projection: CC[N][768] = bf16(h1 @ [Wc0|..|Wc5]), XCD-swizzled 1D grid ----
  int grid2 = 8 * 6 * ceil_div(nbm, 8);
  k_gemm_mfma2<<<grid2, 256, 0, stream>>>(h1h, h1l, Wct_h, CC, C5c, N, 768, 256, nbm);

  // ---- Clenshaw (width 128): b_k = C_k - b_{k+2} + 2L b_{k+1} ----
  auto spmm = [&](const unsigned short* Ck, const unsigned short* s16, int s16s, const float* sf,
                  const unsigned short* src, int ss, float* dst, unsigned short* dstb, float coef){
    k_cheb_spmm2<<<ceil_div(N, 4), 256, 0, stream>>>(Ck, 768, s16, s16s, sf, src, ss, dst, dstb,
        csr_src, w_cheb, row_ptr, dis2, coef, N);
  };
  // b4 = C4 + 2L b5   (b5 gathered from compact C5c)
  spmm(CC + 4*128, nullptr, 0, nullptr, C5c, 128, B0, Bb0, -2.f);
  // b3 = C3 - b5 + 2L b4   (sequential C5 read also from compact buffer)
  spmm(CC + 3*128, C5c, 128, nullptr, Bb0, 128, B1, Bb1, -2.f);
  // b2 = C2 - b4 + 2L b3   (B2 write overwrites C5c region - C5c is dead now)
  spmm(CC + 2*128, nullptr, 0, B0, Bb1, 128, B2, Bb0, -2.f);
  // b1 = C1 - b3 + 2L b2
  spmm(CC + 1*128, nullptr, 0, B1, Bb0, 128, B0, Bb1, -2.f);

  // ---- final: res = C0 - b2 + L b1, fused with feat/p/wr epilogue ----
  float* out  = (float*)d_out;
  float* feat = out + N;
  k_spmm_final<<<ceil_div(N, 4), 256, 0, stream>>>(CC + 0*128, 768, B2, Bb1, 128,
      bc, W_out, W_root, feat, pbuf, wrbuf, csr_src, w_cheb, row_ptr, dis2, -1.f, N);
  k_out<<<ceil_div(N, 256), 256, 0, stream>>>(pbuf, wrbuf, invw, csr_src, row_ptr, b3, out, N);
}

// Round 12
// 1036.808 us; speedup vs baseline: 2.0363x; 1.0119x over previous
//
#include <hip/hip_runtime.h>
#include <cstdint>
#include <cstddef>

typedef __attribute__((ext_vector_type(8))) short bf16x8;
typedef __attribute__((ext_vector_type(4))) float f32x4;

static inline int ceil_div(int a, int b){ return (a + b - 1) / b; }

struct HL { short h, l; };
__device__ inline HL split2(float a){
  unsigned u = __float_as_uint(a);
  unsigned hb = (u + 0x8000u) & 0xFFFF0000u;
  float r = a - __uint_as_float(hb);
  HL o;
  o.h = (short)(hb >> 16);
  o.l = (short)((__float_as_uint(r) + 0x8000u) >> 16);
  return o;
}

__device__ inline unsigned short f2b(float f){            // fp32 -> bf16 (RNE)
  unsigned u = __float_as_uint(f);
  unsigned r = u + 0x7FFFu + ((u >> 16) & 1u);
  return (unsigned short)(r >> 16);
}
__device__ inline float b2f(unsigned short s){
  return __uint_as_float((unsigned)s << 16);
}

// ---------------- dtype detection (int64 vs int32 edge_index) ----------------
__global__ __launch_bounds__(256) void k_detect(const int* __restrict__ ei32, int E, int* __restrict__ flag){
  int t = blockIdx.x * 256 + threadIdx.x;
  if (t < 4096) {
    long long idx = 2LL * t + 1;
    if (idx < 2LL * E && ei32[idx] != 0) atomicOr(flag, 1);
  }
}

// ---------------- CSR build ----------------
__global__ __launch_bounds__(256) void k_count(const void* __restrict__ ei, int E,
                                               const int* __restrict__ flag, int* __restrict__ cnt){
  int e = blockIdx.x * 256 + threadIdx.x;
  if (e >= E) return;
  int dst = (*flag) ? ((const int*)ei)[(size_t)E + e]
                    : (int)((const long long*)ei)[(size_t)E + e];
  atomicAdd(&cnt[dst], 1);
}

// ---- 3-pass device-wide exclusive scan over cnt[N] -> row_ptr (+cursor copy) ----
__global__ __launch_bounds__(256) void k_scan_part(const int* __restrict__ cnt, int* __restrict__ bsum, int N){
  int base = blockIdx.x * 1024 + threadIdx.x * 4;
  int s = 0;
  if (base + 4 <= N){
    int4 v = *(const int4*)(cnt + base);
    s = v.x + v.y + v.z + v.w;
  } else {
    for (int i = base; i < N; ++i) s += cnt[i];
  }
#pragma unroll
  for (int off = 32; off; off >>= 1) s += __shfl_xor(s, off);
  __shared__ int ws[4];
  if ((threadIdx.x & 63) == 0) ws[threadIdx.x >> 6] = s;
  __syncthreads();
  if (threadIdx.x == 0) bsum[blockIdx.x] = ws[0] + ws[1] + ws[2] + ws[3];
}

__global__ __launch_bounds__(1024) void k_scan_bsum(int* __restrict__ bsum, int nb){
  __shared__ int sh[1024];
  int t = threadIdx.x;
  int v = (t < nb) ? bsum[t] : 0;
  sh[t] = v; __syncthreads();
  for (int off = 1; off < 1024; off <<= 1){
    int u = (t >= off) ? sh[t - off] : 0;
    __syncthreads();
    sh[t] += u;
    __syncthreads();
  }
  if (t < nb) bsum[t] = sh[t] - v;   // exclusive
}

__global__ __launch_bounds__(256) void k_scan_write(const int* __restrict__ cnt, const int* __restrict__ bsum,
                                                    int* __restrict__ row_ptr, int* __restrict__ cursor,
                                                    int N, int E){
  int t = threadIdx.x;
  int base = blockIdx.x * 1024 + t * 4;
  int v0 = 0, v1 = 0, v2 = 0, v3 = 0;
  if (base + 4 <= N){
    int4 v = *(const int4*)(cnt + base);
    v0 = v.x; v1 = v.y; v2 = v.z; v3 = v.w;
  } else {
    if (base + 0 < N) v0 = cnt[base + 0];
    if (base + 1 < N) v1 = cnt[base + 1];
    if (base + 2 < N) v2 = cnt[base + 2];
    if (base + 3 < N) v3 = cnt[base + 3];
  }
  int s = v0 + v1 + v2 + v3;
  int lane = t & 63;
  int inc = s;
#pragma unroll
  for (int off = 1; off < 64; off <<= 1){
    int u = __shfl_up(inc, off);
    if (lane >= off) inc += u;
  }
  __shared__ int ws[4];
  if (lane == 63) ws[t >> 6] = inc;
  __syncthreads();
  int wid = t >> 6;
  int woff = 0;
  for (int i = 0; i < wid; ++i) woff += ws[i];
  int exc = bsum[blockIdx.x] + woff + inc - s;
  int p0 = exc, p1 = p0 + v0, p2 = p1 + v1, p3 = p2 + v2;
  if (base + 0 < N){ row_ptr[base + 0] = p0; cursor[base + 0] = p0; }
  if (base + 1 < N){ row_ptr[base + 1] = p1; cursor[base + 1] = p1; }
  if (base + 2 < N){ row_ptr[base + 2] = p2; cursor[base + 2] = p2; }
  if (base + 3 < N){ row_ptr[base + 3] = p3; cursor[base + 3] = p3; }
  if (blockIdx.x == 0 && t == 0) row_ptr[N] = E;
}

// ---------------- fill: packed 8B (src, ew) record per edge, single scatter ----------------
__global__ __launch_bounds__(256) void k_fill(const void* __restrict__ ei, const float* __restrict__ ew, int E,
                                              const int* __restrict__ flag, int* __restrict__ cursor,
                                              uint2* __restrict__ csr_sw){
  int e = blockIdx.x * 256 + threadIdx.x;
  if (e >= E) return;
  int src, dst;
  if (*flag){ src = ((const int*)ei)[e]; dst = ((const int*)ei)[(size_t)E + e]; }
  else      { src = (int)((const long long*)ei)[e]; dst = (int)((const long long*)ei)[(size_t)E + e]; }
  int pos = atomicAdd(&cursor[dst], 1);
  csr_sw[pos] = make_uint2((unsigned)src, __float_as_uint(ew[e]));
}

__global__ __launch_bounds__(256) void k_degrees(const int* __restrict__ row_ptr, const uint2* __restrict__ csr_sw,
                                                 float* __restrict__ dis1, float* __restrict__ dis2,
                                                 float* __restrict__ invw, int N){
  int r = blockIdx.x * 256 + threadIdx.x;
  if (r >= N) return;
  int e0 = row_ptr[r], e1 = row_ptr[r + 1];
  float s = 0.f;
  for (int e = e0; e < e1; ++e) s += __uint_as_float(csr_sw[e].y);
  dis1[r] = rsqrtf(s + 1.0f);
  dis2[r] = (s > 0.0f) ? rsqrtf(s) : 0.0f;
  invw[r] = 1.0f / (float)(e1 - e0 + 1);
}

// ---------------- edge norms: packed (src, w) streams for gcn and cheb ----------------
__global__ __launch_bounds__(256) void k_norm(const uint2* __restrict__ csr_sw,
                                              const float* __restrict__ dis1, const float* __restrict__ dis2,
                                              uint2* __restrict__ pk_gcn, uint2* __restrict__ pk_cheb, int E){
  int e = blockIdx.x * 256 + threadIdx.x;
  if (e >= E) return;
  uint2 p = csr_sw[e];
  int s = (int)p.x;
  float w = __uint_as_float(p.y);
  pk_gcn[e]  = make_uint2(p.x, __float_as_uint(w * dis1[s]));
  pk_cheb[e] = make_uint2(p.x, __float_as_uint(w * dis2[s]));
}

// ---------------- weight prep: W [K][N] fp32 -> Wh/Wl [N][K] bf16 split ----------------
__global__ __launch_bounds__(256) void k_prep_w(const float* __restrict__ W, short* __restrict__ Wh,
                                                short* __restrict__ Wl, int K, int N){
  int idx = blockIdx.x * 256 + threadIdx.x;
  if (idx >= K * N) return;
  int n = idx / K, k = idx - n * K;
  HL s = split2(W[(size_t)k * N + n]);
  Wh[idx] = s.h; Wl[idx] = s.l;
}

// ---------------- Wc prep: Wc [6][256][128] -> [768][256] bf16 (single, RNE) ----------------
__global__ __launch_bounds__(256) void k_prep_wc(const float* __restrict__ Wc, short* __restrict__ Wh){
  int idx = blockIdx.x * 256 + threadIdx.x;
  if (idx >= 768 * 256) return;
  int n = idx >> 8, k = idx & 255;
  Wh[idx] = (short)f2b(Wc[(size_t)(n >> 7) * 256 * 128 + (size_t)k * 128 + (n & 127)]);
}

// ---------------- MFMA GEMM 1: A = bf16(x), B = W1 split; 2-term; A reg-prefetch; XCD swizzle ----
__global__ __launch_bounds__(256) void k_gemm_mfma(
    const float* __restrict__ A,
    const short* __restrict__ Bh, const short* __restrict__ Bl,
    unsigned short* __restrict__ Cb,
    int M, int Ncols, int K, int nbm)
{
  __shared__ short Ah[128][40];
  __shared__ short Bhs[128][40];
  __shared__ short Bls[128][40];
  int bid = blockIdx.x;
  int g = bid & 7, j = bid >> 3;
  int m_tile = g + 8 * (j >> 1);
  int n_tile = j & 1;
  if (m_tile >= nbm) return;
  int m0 = m_tile * 128, n0 = n_tile * 128;
  int t = threadIdx.x;
  int lane = t & 63, wid = t >> 6;
  int wr = wid >> 1, wc = wid & 1;
  int fr = lane & 15, fq = lane >> 4;
  int srow = t >> 1, skh = (t & 1) << 4;

  f32x4 acc[4][4];
#pragma unroll
  for (int i = 0; i < 4; ++i)
#pragma unroll
    for (int jj = 0; jj < 4; ++jj) acc[i][jj] = (f32x4){0.f, 0.f, 0.f, 0.f};

  bool aval = (m0 + srow) < M;
  const float* Aptr = A + (size_t)(m0 + srow) * K + skh;
  const short* Bhp = Bh + (size_t)(n0 + srow) * K + skh;
  const short* Blp = Bl + (size_t)(n0 + srow) * K + skh;

  float4 a0, a1, a2, a3;
  if (aval){
    const float4* ap = (const float4*)Aptr;
    a0 = ap[0]; a1 = ap[1]; a2 = ap[2]; a3 = ap[3];
  } else a0 = a1 = a2 = a3 = make_float4(0.f, 0.f, 0.f, 0.f);

  for (int k0 = 0; k0 < K; k0 += 32){
    bf16x8 h0, h1;
    h0[0]=(short)f2b(a0.x); h0[1]=(short)f2b(a0.y); h0[2]=(short)f2b(a0.z); h0[3]=(short)f2b(a0.w);
    h0[4]=(short)f2b(a1.x); h0[5]=(short)f2b(a1.y); h0[6]=(short)f2b(a1.z); h0[7]=(short)f2b(a1.w);
    h1[0]=(short)f2b(a2.x); h1[1]=(short)f2b(a2.y); h1[2]=(short)f2b(a2.z); h1[3]=(short)f2b(a2.w);
    h1[4]=(short)f2b(a3.x); h1[5]=(short)f2b(a3.y); h1[6]=(short)f2b(a3.z); h1[7]=(short)f2b(a3.w);
    *(bf16x8*)&Ah[srow][skh]     = h0;
    *(bf16x8*)&Ah[srow][skh + 8] = h1;
    {
      const bf16x8* bp = (const bf16x8*)(Bhp + k0);
      *(bf16x8*)&Bhs[srow][skh]     = bp[0];
      *(bf16x8*)&Bhs[srow][skh + 8] = bp[1];
      const bf16x8* cp = (const bf16x8*)(Blp + k0);
      *(bf16x8*)&Bls[srow][skh]     = cp[0];
      *(bf16x8*)&Bls[srow][skh + 8] = cp[1];
    }
    __syncthreads();
    bool more = (k0 + 32) < K;
    float4 n0v, n1v, n2v, n3v;
    if (more && aval){
      const float4* ap = (const float4*)(Aptr + k0 + 32);
      n0v = ap[0]; n1v = ap[1]; n2v = ap[2]; n3v = ap[3];
    } else n0v = n1v = n2v = n3v = make_float4(0.f, 0.f, 0.f, 0.f);
    bf16x8 afh[4], bfh[4], bfl[4];
#pragma unroll
    for (int m = 0; m < 4; ++m){
      int r = wr * 64 + m * 16 + fr;
      afh[m] = *(const bf16x8*)&Ah[r][fq * 8];
    }
#pragma unroll
    for (int n = 0; n < 4; ++n){
      int r = wc * 64 + n * 16 + fr;
      bfh[n] = *(const bf16x8*)&Bhs[r][fq * 8];
      bfl[n] = *(const bf16x8*)&Bls[r][fq * 8];
    }
#pragma unroll
    for (int m = 0; m < 4; ++m)
#pragma unroll
      for (int n = 0; n < 4; ++n){
        acc[m][n] = __builtin_amdgcn_mfma_f32_16x16x32_bf16(afh[m], bfh[n], acc[m][n], 0, 0, 0);
        acc[m][n] = __builtin_amdgcn_mfma_f32_16x16x32_bf16(afh[m], bfl[n], acc[m][n], 0, 0, 0);
      }
    __syncthreads();
    a0 = n0v; a1 = n1v; a2 = n2v; a3 = n3v;
  }
#pragma unroll
  for (int m = 0; m < 4; ++m){
#pragma unroll
    for (int n = 0; n < 4; ++n){
      int col = n0 + wc * 64 + n * 16 + fr;
#pragma unroll
      for (int r = 0; r < 4; ++r){
        int row = m0 + wr * 64 + m * 16 + fq * 4 + r;
        if (row < M){
          Cb[(size_t)row * Ncols + col] = f2b(acc[m][n][r]);
        }
      }
    }
  }
}

// ---------------- MFMA GEMM 2: A = bf16(h1), B = bf16(Wc); SINGLE term; reg-prefetch; XCD swizzle;
// ---------------- n_tile==5 also writes compact C5c[N][128] ----------------
__global__ __launch_bounds__(256) void k_gemm_mfma2(
    const unsigned short* __restrict__ Ahg,
    const short* __restrict__ Bh,
    unsigned short* __restrict__ Cb, unsigned short* __restrict__ C5c,
    int M, int Ncols, int K, int nbm)
{
  __shared__ short Ah[128][40];
  __shared__ short Bhs[128][40];
  int bid = blockIdx.x;
  int g = bid & 7, j = bid >> 3;
  int m_tile = g + 8 * (j / 6);
  int n_tile = j - 6 * (j / 6);
  if (m_tile >= nbm) return;
  int m0 = m_tile * 128, n0 = n_tile * 128;
  int t = threadIdx.x;
  int lane = t & 63, wid = t >> 6;
  int wr = wid >> 1, wc = wid & 1;
  int fr = lane & 15, fq = lane >> 4;
  int srow = t >> 1, skh = (t & 1) << 4;

  f32x4 acc[4][4];
#pragma unroll
  for (int i = 0; i < 4; ++i)
#pragma unroll
    for (int jj = 0; jj < 4; ++jj) acc[i][jj] = (f32x4){0.f, 0.f, 0.f, 0.f};

  bool aval = (m0 + srow) < M;
  const unsigned short* Ahp = Ahg + (size_t)(m0 + srow) * K + skh;
  const short* Bhp = Bh + (size_t)(n0 + srow) * K + skh;

  bf16x8 ch0, ch1;
  if (aval){
    const bf16x8* ah = (const bf16x8*)Ahp;
    ch0 = ah[0]; ch1 = ah[1];
  } else {
    bf16x8 z = (bf16x8){0,0,0,0,0,0,0,0};
    ch0 = ch1 = z;
  }

  for (int k0 = 0; k0 < K; k0 += 32){
    *(bf16x8*)&Ah[srow][skh]     = ch0;
    *(bf16x8*)&Ah[srow][skh + 8] = ch1;
    {
      const bf16x8* bp = (const bf16x8*)(Bhp + k0);
      *(bf16x8*)&Bhs[srow][skh]     = bp[0];
      *(bf16x8*)&Bhs[srow][skh + 8] = bp[1];
    }
    __syncthreads();
    bool more = (k0 + 32) < K;
    bf16x8 nh0, nh1;
    if (more && aval){
      const bf16x8* ah = (const bf16x8*)(Ahp + k0 + 32);
      nh0 = ah[0]; nh1 = ah[1];
    } else {
      bf16x8 z = (bf16x8){0,0,0,0,0,0,0,0};
      nh0 = nh1 = z;
    }
    bf16x8 afh[4], bfh[4];
#pragma unroll
    for (int m = 0; m < 4; ++m){
      int r = wr * 64 + m * 16 + fr;
      afh[m] = *(const bf16x8*)&Ah[r][fq * 8];
    }
#pragma unroll
    for (int n = 0; n < 4; ++n){
      int r = wc * 64 + n * 16 + fr;
      bfh[n] = *(const bf16x8*)&Bhs[r][fq * 8];
    }
#pragma unroll
    for (int m = 0; m < 4; ++m)
#pragma unroll
      for (int n = 0; n < 4; ++n){
        acc[m][n] = __builtin_amdgcn_mfma_f32_16x16x32_bf16(afh[m], bfh[n], acc[m][n], 0, 0, 0);
      }
    __syncthreads();
    ch0 = nh0; ch1 = nh1;
  }
#pragma unroll
  for (int m = 0; m < 4; ++m){
#pragma unroll
    for (int n = 0; n < 4; ++n){
      int col = n0 + wc * 64 + n * 16 + fr;
#pragma unroll
      for (int r = 0; r < 4; ++r){
        int row = m0 + wr * 64 + m * 16 + fq * 4 + r;
        if (row < M){
          unsigned short v = f2b(acc[m][n][r]);
          Cb[(size_t)row * Ncols + col] = v;
          if (n_tile == 5) C5c[(size_t)row * 128 + (col - 640)] = v;
        }
      }
    }
  }
}

// ---------------- GCN aggregation: packed-edge bf16 gathers (8-wide MLP), writes single bf16 h1 ----
__global__ __launch_bounds__(256) void k_gcn_agg(
    const unsigned short* __restrict__ h0b,
    const uint2* __restrict__ pk, const int* __restrict__ row_ptr,
    const float* __restrict__ dis1, const float* __restrict__ b1,
    unsigned short* __restrict__ h1b, int N){
  int lane = threadIdx.x & 63;
  int r = blockIdx.x * 4 + (threadIdx.x >> 6);
  if (r >= N) return;
  float dr = dis1[r];
  ushort4 sv = ((const ushort4*)(h0b + (size_t)r * 256))[lane];
  float4 inner = make_float4(b2f(sv.x) * dr, b2f(sv.y) * dr, b2f(sv.z) * dr, b2f(sv.w) * dr);
  int e0 = row_ptr[r], e1 = row_ptr[r + 1];
  int e = e0;
  for (; e + 8 <= e1; e += 8){
    uint2 pv[8]; ushort4 vi[8];
#pragma unroll
    for (int q = 0; q < 8; ++q) pv[q] = pk[e + q];
#pragma unroll
    for (int q = 0; q < 8; ++q) vi[q] = ((const ushort4*)(h0b + (size_t)pv[q].x * 256))[lane];
#pragma unroll
    for (int q = 0; q < 8; ++q){
      float w = __uint_as_float(pv[q].y);
      inner.x = fmaf(w, b2f(vi[q].x), inner.x);
      inner.y = fmaf(w, b2f(vi[q].y), inner.y);
      inner.z = fmaf(w, b2f(vi[q].z), inner.z);
      inner.w = fmaf(w, b2f(vi[q].w), inner.w);
    }
  }
  for (; e < e1; ++e){
    uint2 p = pk[e];
    float w = __uint_as_float(p.y);
    ushort4 v = ((const ushort4*)(h0b + (size_t)p.x * 256))[lane];
    inner.x = fmaf(w, b2f(v.x), inner.x); inner.y = fmaf(w, b2f(v.y), inner.y);
    inner.z = fmaf(w, b2f(v.z), inner.z); inner.w = fmaf(w, b2f(v.w), inner.w);
  }
  float4 bb = ((const float4*)b1)[lane];
  ushort4 o;
  o.x = f2b(fmaxf(fmaf(inner.x, dr, bb.x), 0.f));
  o.y = f2b(fmaxf(fmaf(inner.y, dr, bb.y), 0.f));
  o.z = f2b(fmaxf(fmaf(inner.z, dr, bb.z), 0.f));
  o.w = f2b(fmaxf(fmaf(inner.w, dr, bb.w), 0.f));
  ((ushort4*)(h1b + (size_t)r * 256))[lane] = o;
}

// ---------------- Cheb spmm v2 (packed edges, 8-wide MLP) ----------------
__global__ __launch_bounds__(256) void k_cheb_spmm2(
    const unsigned short* __restrict__ Ck, int ckstride,
    const unsigned short* __restrict__ sub16, int substride,
    const float* __restrict__ subf,
    const unsigned short* __restrict__ srcb, int sstride,
    float* __restrict__ dst, unsigned short* __restrict__ dstb,
    const uint2* __restrict__ pk, const int* __restrict__ row_ptr,
    const float* __restrict__ dis2, float coef, int N){
  int lane = threadIdx.x & 63;
  int r = blockIdx.x * 4 + (threadIdx.x >> 6);
  if (r >= N) return;
  float2 inner = make_float2(0.f, 0.f);
  int e0 = row_ptr[r], e1 = row_ptr[r + 1];
  int e = e0;
  for (; e + 8 <= e1; e += 8){
    uint2 pv[8]; unsigned vi[8];
#pragma unroll
    for (int q = 0; q < 8; ++q) pv[q] = pk[e + q];
#pragma unroll
    for (int q = 0; q < 8; ++q) vi[q] = ((const unsigned*)(srcb + (size_t)pv[q].x * sstride))[lane];
#pragma unroll
    for (int q = 0; q < 8; ++q){
      float w = __uint_as_float(pv[q].y);
      inner.x = fmaf(w, __uint_as_float(vi[q] << 16), inner.x);
      inner.y = fmaf(w, __uint_as_float(vi[q] & 0xFFFF0000u), inner.y);
    }
  }
  for (; e < e1; ++e){
    uint2 p = pk[e];
    float w = __uint_as_float(p.y);
    unsigned v = ((const unsigned*)(srcb + (size_t)p.x * sstride))[lane];
    inner.x = fmaf(w, __uint_as_float(v << 16), inner.x);
    inner.y = fmaf(w, __uint_as_float(v & 0xFFFF0000u), inner.y);
  }
  float c = coef * dis2[r];
  unsigned ckv = ((const unsigned*)(Ck + (size_t)r * ckstride))[lane];
  float rx = fmaf(c, inner.x, __uint_as_float(ckv << 16));
  float ry = fmaf(c, inner.y, __uint_as_float(ckv & 0xFFFF0000u));
  if (sub16){
    unsigned sv = ((const unsigned*)(sub16 + (size_t)r * substride))[lane];
    rx -= __uint_as_float(sv << 16);
    ry -= __uint_as_float(sv & 0xFFFF0000u);
  }
  if (subf){
    float2 s2 = ((const float2*)(subf + (size_t)r * 128))[lane];
    rx -= s2.x;
    ry -= s2.y;
  }
  ((float2*)(dst + (size_t)r * 128))[lane] = make_float2(rx, ry);
  if (dstb){
    unsigned pkd = (unsigned)f2b(rx) | ((unsigned)f2b(ry) << 16);
    ((unsigned*)(dstb + (size_t)r * 128))[lane] = pkd;
  }
}

// ---------------- final spmm fused with feat epilogue (packed edges, 8-wide) ----------------
__global__ __launch_bounds__(256) void k_spmm_final(
    const unsigned short* __restrict__ Ck, int ckstride,
    const float* __restrict__ subf,
    const unsigned short* __restrict__ srcb, int sstride,
    const float* __restrict__ bc, const float* __restrict__ W_out, const float* __restrict__ W_root,
    float* __restrict__ feat, float* __restrict__ p, float* __restrict__ wr,
    const uint2* __restrict__ pk, const int* __restrict__ row_ptr,
    const float* __restrict__ dis2, float coef, int N){
  int lane = threadIdx.x & 63;
  int r = blockIdx.x * 4 + (threadIdx.x >> 6);
  if (r >= N) return;
  float2 inner = make_float2(0.f, 0.f);
  int e0 = row_ptr[r], e1 = row_ptr[r + 1];
  int e = e0;
  for (; e + 8 <= e1; e += 8){
    uint2 pv[8]; unsigned vi[8];
#pragma unroll
    for (int q = 0; q < 8; ++q) pv[q] = pk[e + q];
#pragma unroll
    for (int q = 0; q < 8; ++q) vi[q] = ((const unsigned*)(srcb + (size_t)pv[q].x * sstride))[lane];
#pragma unroll
    for (int q = 0; q < 8; ++q){
      float w = __uint_as_float(pv[q].y);
      inner.x = fmaf(w, __uint_as_float(vi[q] << 16), inner.x);
      inner.y = fmaf(w, __uint_as_float(vi[q] & 0xFFFF0000u), inner.y);
    }
  }
  for (; e < e1; ++e){
    uint2 pp = pk[e];
    float w = __uint_as_float(pp.y);
    unsigned v = ((const unsigned*)(srcb + (size_t)pp.x * sstride))[lane];
    inner.x = fmaf(w, __uint_as_float(v << 16), inner.x);
    inner.y = fmaf(w, __uint_as_float(v & 0xFFFF0000u), inner.y);
  }
  float c = coef * dis2[r];
  unsigned ckv = ((const unsigned*)(Ck + (size_t)r * ckstride))[lane];
  float rx = fmaf(c, inner.x, __uint_as_float(ckv << 16));
  float ry = fmaf(c, inner.y, __uint_as_float(ckv & 0xFFFF0000u));
  float2 s2 = ((const float2*)(subf + (size_t)r * 128))[lane];
  rx -= s2.x;
  ry -= s2.y;
  float2 bb = ((const float2*)bc)[lane];
  rx = fmaxf(rx + bb.x, 0.f);
  ry = fmaxf(ry + bb.y, 0.f);
  ((float2*)(feat + (size_t)r * 128))[lane] = make_float2(rx, ry);
  float2 wo = ((const float2*)W_out)[lane];
  float2 wrt = ((const float2*)W_root)[lane];
  float pp2 = rx * wo.x + ry * wo.y;
  float rr = rx * wrt.x + ry * wrt.y;
#pragma unroll
  for (int off = 32; off; off >>= 1){
    pp2 += __shfl_xor(pp2, off);
    rr += __shfl_xor(rr, off);
  }
  if (lane == 0){ p[r] = pp2; wr[r] = rr; }
}

// ---------------- ClusterGCN output (8-wide, packed edges) ----------------
__global__ __launch_bounds__(256) void k_out(const float* __restrict__ p, const float* __restrict__ wr,
    const float* __restrict__ invw, const uint2* __restrict__ pk, const int* __restrict__ row_ptr,
    const float* __restrict__ b3, float* __restrict__ out, int N){
  int r = blockIdx.x * 256 + threadIdx.x;
  if (r >= N) return;
  float s = p[r];
  int e0 = row_ptr[r], e1 = row_ptr[r + 1];
  int e = e0;
  float acc[8] = {0.f,0.f,0.f,0.f,0.f,0.f,0.f,0.f};
  for (; e + 8 <= e1; e += 8){
    int si[8];
#pragma unroll
    for (int q = 0; q < 8; ++q) si[q] = (int)pk[e + q].x;
#pragma unroll
    for (int q = 0; q < 8; ++q) acc[q] += p[si[q]];
  }
  for (; e < e1; ++e) acc[0] += p[(int)pk[e].x];
  s += ((acc[0]+acc[1])+(acc[2]+acc[3])) + ((acc[4]+acc[5])+(acc[6]+acc[7]));
  out[r] = invw[r] * s + wr[r] + b3[0];
}

extern "C" void kernel_launch(void* const* d_in, const int* in_sizes, int n_in,
                              void* d_out, int out_size, void* d_ws, size_t ws_size,
                              hipStream_t stream){
  const float* x      = (const float*)d_in[0];
  const void*  ei     = d_in[1];
  const float* ew     = (const float*)d_in[2];
  const float* W1     = (const float*)d_in[3];
  const float* b1     = (const float*)d_in[4];
  const float* Wc     = (const float*)d_in[5];
  const float* bc     = (const float*)d_in[6];
  const float* W_out  = (const float*)d_in[7];
  const float* W_root = (const float*)d_in[8];
  const float* b3     = (const float*)d_in[9];
  const int N = in_sizes[0] / 512;
  const int E = in_sizes[2];

  char* w = (char*)d_ws;
  auto alloc = [&](size_t bytes)->void*{ void* r = (void*)w; w += (bytes + 255) & ~(size_t)255; return r; };
  // region (102.4 MB): h1b bf16 (first half) -> later B0|B1 fp32 Clenshaw
  unsigned short* h1b = (unsigned short*)alloc((size_t)N * 256 * 2 * 2);
  float* B0 = (float*)h1b;
  float* B1 = B0 + (size_t)N * 128;
  float* B2 = (float*)alloc((size_t)N * 128 * 4);
  // C5c (compact bf16 copy of C5, 25.6 MB) aliases B2's region: dead before B2 is first written.
  unsigned short* C5c = (unsigned short*)B2;
  unsigned short* CC  = (unsigned short*)alloc((size_t)N * 768 * 2);  // all 6 C_k, bf16
  unsigned short* h0b = (unsigned short*)alloc((size_t)N * 256 * 2);  // bf16 x@W1; later Bb0|Bb1
  unsigned short* Bb0 = h0b;
  unsigned short* Bb1 = h0b + (size_t)N * 128;
  uint2* csr_sw  = (uint2*)alloc((size_t)E * 8);
  uint2* pk_gcn  = (uint2*)alloc((size_t)E * 8);
  uint2* pk_cheb = (uint2*)alloc((size_t)E * 8);
  int*   row_ptr = (int*)  alloc((size_t)(N + 1) * 4);
  int*   cursor  = (int*)  alloc((size_t)N * 4);
  int*   cnt     = (int*)  alloc((size_t)N * 4);
  int*   bsum    = (int*)  alloc((size_t)1024 * 4);
  float* dis1    = (float*)alloc((size_t)N * 4);
  float* dis2    = (float*)alloc((size_t)N * 4);
  float* invw    = (float*)alloc((size_t)N * 4);
  float* pbuf    = (float*)alloc((size_t)N * 4);
  float* wrbuf   = (float*)alloc((size_t)N * 4);
  short* W1t_h   = (short*)alloc((size_t)512 * 256 * 2);
  short* W1t_l   = (short*)alloc((size_t)512 * 256 * 2);
  short* Wct_h   = (short*)alloc((size_t)768 * 256 * 2);
  int*   flag    = (int*)  alloc(256);

  hipMemsetAsync(cnt, 0, (size_t)N * 4, stream);
  hipMemsetAsync(flag, 0, 4, stream);

  k_detect<<<16, 256, 0, stream>>>((const int*)ei, E, flag);
  k_count<<<ceil_div(E, 256), 256, 0, stream>>>(ei, E, flag, cnt);
  int nb = ceil_div(N, 1024);
  k_scan_part<<<nb, 256, 0, stream>>>(cnt, bsum, N);
  k_scan_bsum<<<1, 1024, 0, stream>>>(bsum, nb);
  k_scan_write<<<nb, 256, 0, stream>>>(cnt, bsum, row_ptr, cursor, N, E);
  k_fill<<<ceil_div(E, 256), 256, 0, stream>>>(ei, ew, E, flag, cursor, csr_sw);
  k_degrees<<<ceil_div(N, 256), 256, 0, stream>>>(row_ptr, csr_sw, dis1, dis2, invw, N);
  k_norm<<<ceil_div(E, 256), 256, 0, stream>>>(csr_sw, dis1, dis2, pk_gcn, pk_cheb, E);

  // weight prep
  k_prep_w<<<ceil_div(512 * 256, 256), 256, 0, stream>>>(W1, W1t_h, W1t_l, 512, 256);
  k_prep_wc<<<ceil_div(768 * 256, 256), 256, 0, stream>>>(Wc, Wct_h);

  // ---- GCNConv: h0b = bf16(x@W1); h1b = bf16(relu(agg + b1)) ----
  int nbm = ceil_div(N, 128);
  int grid1 = 8 * 2 * ceil_div(nbm, 8);
  k_gemm_mfma<<<grid1, 256, 0, stream>>>(x, W1t_h, W1t_l, h0b, N, 256, 512, nbm);
  k_gcn_agg<<<ceil_div(N, 4), 256, 0, stream>>>(h0b, pk_gcn, row_ptr, dis1, b1, h1b, N);

  // ---- fused Cheb projection: CC[N][768] = bf16(h1 @ [Wc0|..|Wc5]), single-term, XCD swizzle ----
  int grid2 = 8 * 6 * ceil_div(nbm, 8);
  k_gemm_mfma2<<<grid2, 256, 0, stream>>>(h1b, Wct_h, CC, C5c, N, 768, 256, nbm);

  // ---- Clenshaw (width 128): b_k = C_k - b_{k+2} + 2L b_{k+1} ----
  auto spmm = [&](const unsigned short* Ck, const unsigned short* s16, int s16s, const float* sf,
                  const unsigned short* src, int ss, float* dst, unsigned short* dstb, float coef){
    k_cheb_spmm2<<<ceil_div(N, 4), 256, 0, stream>>>(Ck, 768, s16, s16s, sf, src, ss, dst, dstb,
        pk_cheb, row_ptr, dis2, coef, N);
  };
  // b4 = C4 + 2L b5   (b5 gathered from compact C5c; note B0 overwrites h1b region - h1b dead)
  spmm(CC + 4*128, nullptr, 0, nullptr, C5c, 128, B0, Bb0, -2.f);
  // b3 = C3 - b5 + 2L b4
  spmm(CC + 3*128, C5c, 128, nullptr, Bb0, 128, B1, Bb1, -2.f);
  // b2 = C2 - b4 + 2L b3   (B2 write overwrites C5c region - C5c dead now)
  spmm(CC + 2*128, nullptr, 0, B0, Bb1, 128, B2, Bb0, -2.f);
  // b1 = C1 - b3 + 2L b2
  spmm(CC + 1*128, nullptr, 0, B1, Bb0, 128, B0, Bb1, -2.f);

  // ---- final: res = C0 - b2 + L b1, fused with feat/p/wr epilogue ----
  float* out  = (float*)d_out;
  float* feat = out + N;
  k_spmm_final<<<ceil_div(N, 4), 256, 0, stream>>>(CC + 0*128, 768, B2, Bb1, 128,
      bc, W_out, W_root, feat, pbuf, wrbuf, pk_cheb, row_ptr, dis2, -1.f, N);
  k_out<<<ceil_div(N, 256), 256, 0, stream>>>(pbuf, wrbuf, invw, pk_cheb, row_ptr, b3, out, N);
}

// Round 13
// 906.976 us; speedup vs baseline: 2.3278x; 1.1431x over previous
//
#include <hip/hip_runtime.h>
#include <cstdint>
#include <cstddef>

typedef __attribute__((ext_vector_type(8))) short bf16x8;
typedef __attribute__((ext_vector_type(4))) float f32x4;

static inline int ceil_div(int a, int b){ return (a + b - 1) / b; }

struct HL { short h, l; };
__device__ inline HL split2(float a){
  unsigned u = __float_as_uint(a);
  unsigned hb = (u + 0x8000u) & 0xFFFF0000u;
  float r = a - __uint_as_float(hb);
  HL o;
  o.h = (short)(hb >> 16);
  o.l = (short)((__float_as_uint(r) + 0x8000u) >> 16);
  return o;
}

__device__ inline unsigned short f2b(float f){            // fp32 -> bf16 (RNE)
  unsigned u = __float_as_uint(f);
  unsigned r = u + 0x7FFFu + ((u >> 16) & 1u);
  return (unsigned short)(r >> 16);
}
__device__ inline float b2f(unsigned short s){
  return __uint_as_float((unsigned)s << 16);
}

#define EPB 4096   // edges per histogram/partition block

// ---------------- dtype detection (int64 vs int32 edge_index) ----------------
__global__ __launch_bounds__(256) void k_detect(const int* __restrict__ ei32, int E, int* __restrict__ flag){
  int t = blockIdx.x * 256 + threadIdx.x;
  if (t < 4096) {
    long long idx = 2LL * t + 1;
    if (idx < 2LL * E && ei32[idx] != 0) atomicOr(flag, 1);
  }
}

// ---------------- CSR build v2: counting sort by dst bucket (dst>>8) ----------------
// pass 1: per-block LDS histogram over 512 buckets
__global__ __launch_bounds__(256) void k_hist(const void* __restrict__ ei, int E,
                                              const int* __restrict__ flag, int* __restrict__ block_hist){
  __shared__ int h[512];
  for (int i = threadIdx.x; i < 512; i += 256) h[i] = 0;
  __syncthreads();
  int base = blockIdx.x * EPB;
  bool is32 = (*flag != 0);
  for (int i = 0; i < 16; ++i){
    int e = base + i * 256 + threadIdx.x;
    if (e < E){
      int dst = is32 ? ((const int*)ei)[(size_t)E + e] : (int)((const long long*)ei)[(size_t)E + e];
      atomicAdd(&h[dst >> 8], 1);
    }
  }
  __syncthreads();
  for (int i = threadIdx.x; i < 512; i += 256) block_hist[blockIdx.x * 512 + i] = h[i];
}

// pass 2a: per-bucket exclusive scan across blocks (one wave per bucket)
__global__ __launch_bounds__(64) void k_colscan(const int* __restrict__ block_hist, int* __restrict__ off_hist,
                                                int* __restrict__ bucket_total, int nblk){
  int k = blockIdx.x;
  int lane = threadIdx.x;
  int carry = 0;
  for (int c = 0; c * 64 < nblk; ++c){
    int b = c * 64 + lane;
    int v = (b < nblk) ? block_hist[b * 512 + k] : 0;
    int inc = v;
#pragma unroll
    for (int off = 1; off < 64; off <<= 1){
      int u = __shfl_up(inc, off);
      if (lane >= off) inc += u;
    }
    if (b < nblk) off_hist[b * 512 + k] = carry + inc - v;
    carry += __shfl(inc, 63);
  }
  if (lane == 0) bucket_total[k] = carry;
}

// pass 2b: scan 512 bucket totals -> bucket_base (exclusive); also row_ptr[N]=E
__global__ __launch_bounds__(512) void k_bucketbase(const int* __restrict__ bucket_total,
                                                    int* __restrict__ bucket_base,
                                                    int* __restrict__ row_ptr, int N, int E){
  __shared__ int sh[512];
  int t = threadIdx.x;
  int v = bucket_total[t];
  sh[t] = v; __syncthreads();
  for (int off = 1; off < 512; off <<= 1){
    int u = (t >= off) ? sh[t - off] : 0;
    __syncthreads();
    sh[t] += u;
    __syncthreads();
  }
  bucket_base[t] = sh[t] - v;
  if (t == 511) bucket_base[512] = sh[511];
  if (t == 0) row_ptr[N] = E;
}

// pass 3: partition edges into bucket-contiguous regions; record packs (src | dstlow<<20, ew)
__global__ __launch_bounds__(256) void k_partition(const void* __restrict__ ei, const float* __restrict__ ew,
                                                   int E, const int* __restrict__ flag,
                                                   const int* __restrict__ off_hist,
                                                   const int* __restrict__ bucket_base,
                                                   uint2* __restrict__ part){
  __shared__ int cur[512];
  for (int i = threadIdx.x; i < 512; i += 256)
    cur[i] = off_hist[blockIdx.x * 512 + i] + bucket_base[i];
  __syncthreads();
  int base = blockIdx.x * EPB;
  bool is32 = (*flag != 0);
  for (int i = 0; i < 16; ++i){
    int e = base + i * 256 + threadIdx.x;
    if (e < E){
      int src, dst;
      if (is32){ src = ((const int*)ei)[e]; dst = ((const int*)ei)[(size_t)E + e]; }
      else     { src = (int)((const long long*)ei)[e]; dst = (int)((const long long*)ei)[(size_t)E + e]; }
      int pos = atomicAdd(&cur[dst >> 8], 1);
      part[pos] = make_uint2((unsigned)src | ((unsigned)(dst & 255) << 20), __float_as_uint(ew[e]));
    }
  }
}

// pass 4: one workgroup per bucket: count+scan -> row_ptr/dis/invw, then in-bucket dst-ordered fill
__global__ __launch_bounds__(256) void k_bucket_csr(const uint2* __restrict__ part,
                                                    const int* __restrict__ bucket_base,
                                                    uint2* __restrict__ csr_sw, int* __restrict__ row_ptr,
                                                    float* __restrict__ dis1, float* __restrict__ dis2,
                                                    float* __restrict__ invw, int N){
  __shared__ int cnt[256];
  __shared__ float wsum[256];
  __shared__ int cursor[256];
  __shared__ int ws[4];
  int k = blockIdx.x;
  int t = threadIdx.x;
  int base = bucket_base[k], end = bucket_base[k + 1];
  cnt[t] = 0; wsum[t] = 0.f;
  __syncthreads();
  for (int i = base + t; i < end; i += 256){
    uint2 rec = part[i];
    int dstl = (rec.x >> 20) & 255;
    atomicAdd(&cnt[dstl], 1);
    atomicAdd(&wsum[dstl], __uint_as_float(rec.y));
  }
  __syncthreads();
  int v = cnt[t];
  int lane = t & 63;
  int inc = v;
#pragma unroll
  for (int off = 1; off < 64; off <<= 1){
    int u = __shfl_up(inc, off);
    if (lane >= off) inc += u;
  }
  if (lane == 63) ws[t >> 6] = inc;
  __syncthreads();
  int woff = 0;
  for (int i = 0; i < (t >> 6); ++i) woff += ws[i];
  int exc = woff + inc - v;
  int node = k * 256 + t;
  if (node < N){
    row_ptr[node] = base + exc;
    float s = wsum[t];
    dis1[node] = rsqrtf(s + 1.0f);
    dis2[node] = (s > 0.f) ? rsqrtf(s) : 0.f;
    invw[node] = 1.0f / (float)(v + 1);
  }
  cursor[t] = exc;
  __syncthreads();
  for (int i = base + t; i < end; i += 256){
    uint2 rec = part[i];
    int dstl = (rec.x >> 20) & 255;
    int pos = base + atomicAdd(&cursor[dstl], 1);
    csr_sw[pos] = make_uint2(rec.x & 0xFFFFFu, rec.y);
  }
}

// ---------------- edge norms: packed (src, w) streams for gcn and cheb ----------------
__global__ __launch_bounds__(256) void k_norm(const uint2* __restrict__ csr_sw,
                                              const float* __restrict__ dis1, const float* __restrict__ dis2,
                                              uint2* __restrict__ pk_gcn, uint2* __restrict__ pk_cheb, int E){
  int e = blockIdx.x * 256 + threadIdx.x;
  if (e >= E) return;
  uint2 p = csr_sw[e];
  int s = (int)p.x;
  float w = __uint_as_float(p.y);
  pk_gcn[e]  = make_uint2(p.x, __float_as_uint(w * dis1[s]));
  pk_cheb[e] = make_uint2(p.x, __float_as_uint(w * dis2[s]));
}

// ---------------- weight prep: W [K][N] fp32 -> Wh/Wl [N][K] bf16 split ----------------
__global__ __launch_bounds__(256) void k_prep_w(const float* __restrict__ W, short* __restrict__ Wh,
                                                short* __restrict__ Wl, int K, int N){
  int idx = blockIdx.x * 256 + threadIdx.x;
  if (idx >= K * N) return;
  int n = idx / K, k = idx - n * K;
  HL s = split2(W[(size_t)k * N + n]);
  Wh[idx] = s.h; Wl[idx] = s.l;
}

// ---------------- Wc prep: Wc [6][256][128] -> [768][256] bf16 (single, RNE) ----------------
__global__ __launch_bounds__(256) void k_prep_wc(const float* __restrict__ Wc, short* __restrict__ Wh){
  int idx = blockIdx.x * 256 + threadIdx.x;
  if (idx >= 768 * 256) return;
  int n = idx >> 8, k = idx & 255;
  Wh[idx] = (short)f2b(Wc[(size_t)(n >> 7) * 256 * 128 + (size_t)k * 128 + (n & 127)]);
}

// ---------------- MFMA GEMM 1: A = bf16(x), B = W1 split; 2-term; A reg-prefetch; XCD swizzle ----
__global__ __launch_bounds__(256) void k_gemm_mfma(
    const float* __restrict__ A,
    const short* __restrict__ Bh, const short* __restrict__ Bl,
    unsigned short* __restrict__ Cb,
    int M, int Ncols, int K, int nbm)
{
  __shared__ short Ah[128][40];
  __shared__ short Bhs[128][40];
  __shared__ short Bls[128][40];
  int bid = blockIdx.x;
  int g = bid & 7, j = bid >> 3;
  int m_tile = g + 8 * (j >> 1);
  int n_tile = j & 1;
  if (m_tile >= nbm) return;
  int m0 = m_tile * 128, n0 = n_tile * 128;
  int t = threadIdx.x;
  int lane = t & 63, wid = t >> 6;
  int wr = wid >> 1, wc = wid & 1;
  int fr = lane & 15, fq = lane >> 4;
  int srow = t >> 1, skh = (t & 1) << 4;

  f32x4 acc[4][4];
#pragma unroll
  for (int i = 0; i < 4; ++i)
#pragma unroll
    for (int jj = 0; jj < 4; ++jj) acc[i][jj] = (f32x4){0.f, 0.f, 0.f, 0.f};

  bool aval = (m0 + srow) < M;
  const float* Aptr = A + (size_t)(m0 + srow) * K + skh;
  const short* Bhp = Bh + (size_t)(n0 + srow) * K + skh;
  const short* Blp = Bl + (size_t)(n0 + srow) * K + skh;

  float4 a0, a1, a2, a3;
  if (aval){
    const float4* ap = (const float4*)Aptr;
    a0 = ap[0]; a1 = ap[1]; a2 = ap[2]; a3 = ap[3];
  } else a0 = a1 = a2 = a3 = make_float4(0.f, 0.f, 0.f, 0.f);

  for (int k0 = 0; k0 < K; k0 += 32){
    bf16x8 h0, h1;
    h0[0]=(short)f2b(a0.x); h0[1]=(short)f2b(a0.y); h0[2]=(short)f2b(a0.z); h0[3]=(short)f2b(a0.w);
    h0[4]=(short)f2b(a1.x); h0[5]=(short)f2b(a1.y); h0[6]=(short)f2b(a1.z); h0[7]=(short)f2b(a1.w);
    h1[0]=(short)f2b(a2.x); h1[1]=(short)f2b(a2.y); h1[2]=(short)f2b(a2.z); h1[3]=(short)f2b(a2.w);
    h1[4]=(short)f2b(a3.x); h1[5]=(short)f2b(a3.y); h1[6]=(short)f2b(a3.z); h1[7]=(short)f2b(a3.w);
    *(bf16x8*)&Ah[srow][skh]     = h0;
    *(bf16x8*)&Ah[srow][skh + 8] = h1;
    {
      const bf16x8* bp = (const bf16x8*)(Bhp + k0);
      *(bf16x8*)&Bhs[srow][skh]     = bp[0];
      *(bf16x8*)&Bhs[srow][skh + 8] = bp[1];
      const bf16x8* cp = (const bf16x8*)(Blp + k0);
      *(bf16x8*)&Bls[srow][skh]     = cp[0];
      *(bf16x8*)&Bls[srow][skh + 8] = cp[1];
    }
    __syncthreads();
    bool more = (k0 + 32) < K;
    float4 n0v, n1v, n2v, n3v;
    if (more && aval){
      const float4* ap = (const float4*)(Aptr + k0 + 32);
      n0v = ap[0]; n1v = ap[1]; n2v = ap[2]; n3v = ap[3];
    } else n0v = n1v = n2v = n3v = make_float4(0.f, 0.f, 0.f, 0.f);
    bf16x8 afh[4], bfh[4], bfl[4];
#pragma unroll
    for (int m = 0; m < 4; ++m){
      int r = wr * 64 + m * 16 + fr;
      afh[m] = *(const bf16x8*)&Ah[r][fq * 8];
    }
#pragma unroll
    for (int n = 0; n < 4; ++n){
      int r = wc * 64 + n * 16 + fr;
      bfh[n] = *(const bf16x8*)&Bhs[r][fq * 8];
      bfl[n] = *(const bf16x8*)&Bls[r][fq * 8];
    }
#pragma unroll
    for (int m = 0; m < 4; ++m)
#pragma unroll
      for (int n = 0; n < 4; ++n){
        acc[m][n] = __builtin_amdgcn_mfma_f32_16x16x32_bf16(afh[m], bfh[n], acc[m][n], 0, 0, 0);
        acc[m][n] = __builtin_amdgcn_mfma_f32_16x16x32_bf16(afh[m], bfl[n], acc[m][n], 0, 0, 0);
      }
    __syncthreads();
    a0 = n0v; a1 = n1v; a2 = n2v; a3 = n3v;
  }
#pragma unroll
  for (int m = 0; m < 4; ++m){
#pragma unroll
    for (int n = 0; n < 4; ++n){
      int col = n0 + wc * 64 + n * 16 + fr;
#pragma unroll
      for (int r = 0; r < 4; ++r){
        int row = m0 + wr * 64 + m * 16 + fq * 4 + r;
        if (row < M){
          Cb[(size_t)row * Ncols + col] = f2b(acc[m][n][r]);
        }
      }
    }
  }
}

// ---------------- MFMA GEMM 2: A = bf16(h1), B = bf16(Wc); single term; reg-prefetch; XCD swizzle;
// ---------------- n_tile==5 also writes compact C5c[N][128] ----------------
__global__ __launch_bounds__(256) void k_gemm_mfma2(
    const unsigned short* __restrict__ Ahg,
    const short* __restrict__ Bh,
    unsigned short* __restrict__ Cb, unsigned short* __restrict__ C5c,
    int M, int Ncols, int K, int nbm)
{
  __shared__ short Ah[128][40];
  __shared__ short Bhs[128][40];
  int bid = blockIdx.x;
  int g = bid & 7, j = bid >> 3;
  int m_tile = g + 8 * (j / 6);
  int n_tile = j - 6 * (j / 6);
  if (m_tile >= nbm) return;
  int m0 = m_tile * 128, n0 = n_tile * 128;
  int t = threadIdx.x;
  int lane = t & 63, wid = t >> 6;
  int wr = wid >> 1, wc = wid & 1;
  int fr = lane & 15, fq = lane >> 4;
  int srow = t >> 1, skh = (t & 1) << 4;

  f32x4 acc[4][4];
#pragma unroll
  for (int i = 0; i < 4; ++i)
#pragma unroll
    for (int jj = 0; jj < 4; ++jj) acc[i][jj] = (f32x4){0.f, 0.f, 0.f, 0.f};

  bool aval = (m0 + srow) < M;
  const unsigned short* Ahp = Ahg + (size_t)(m0 + srow) * K + skh;
  const short* Bhp = Bh + (size_t)(n0 + srow) * K + skh;

  bf16x8 ch0, ch1;
  if (aval){
    const bf16x8* ah = (const bf16x8*)Ahp;
    ch0 = ah[0]; ch1 = ah[1];
  } else {
    bf16x8 z = (bf16x8){0,0,0,0,0,0,0,0};
    ch0 = ch1 = z;
  }

  for (int k0 = 0; k0 < K; k0 += 32){
    *(bf16x8*)&Ah[srow][skh]     = ch0;
    *(bf16x8*)&Ah[srow][skh + 8] = ch1;
    {
      const bf16x8* bp = (const bf16x8*)(Bhp + k0);
      *(bf16x8*)&Bhs[srow][skh]     = bp[0];
      *(bf16x8*)&Bhs[srow][skh + 8] = bp[1];
    }
    __syncthreads();
    bool more = (k0 + 32) < K;
    bf16x8 nh0, nh1;
    if (more && aval){
      const bf16x8* ah = (const bf16x8*)(Ahp + k0 + 32);
      nh0 = ah[0]; nh1 = ah[1];
    } else {
      bf16x8 z = (bf16x8){0,0,0,0,0,0,0,0};
      nh0 = nh1 = z;
    }
    bf16x8 afh[4], bfh[4];
#pragma unroll
    for (int m = 0; m < 4; ++m){
      int r = wr * 64 + m * 16 + fr;
      afh[m] = *(const bf16x8*)&Ah[r][fq * 8];
    }
#pragma unroll
    for (int n = 0; n < 4; ++n){
      int r = wc * 64 + n * 16 + fr;
      bfh[n] = *(const bf16x8*)&Bhs[r][fq * 8];
    }
#pragma unroll
    for (int m = 0; m < 4; ++m)
#pragma unroll
      for (int n = 0; n < 4; ++n){
        acc[m][n] = __builtin_amdgcn_mfma_f32_16x16x32_bf16(afh[m], bfh[n], acc[m][n], 0, 0, 0);
      }
    __syncthreads();
    ch0 = nh0; ch1 = nh1;
  }
#pragma unroll
  for (int m = 0; m < 4; ++m){
#pragma unroll
    for (int n = 0; n < 4; ++n){
      int col = n0 + wc * 64 + n * 16 + fr;
#pragma unroll
      for (int r = 0; r < 4; ++r){
        int row = m0 + wr * 64 + m * 16 + fq * 4 + r;
        if (row < M){
          unsigned short v = f2b(acc[m][n][r]);
          Cb[(size_t)row * Ncols + col] = v;
          if (n_tile == 5) C5c[(size_t)row * 128 + (col - 640)] = v;
        }
      }
    }
  }
}

// ---------------- GCN aggregation: packed-edge bf16 gathers (8-wide MLP), writes single bf16 h1 ----
__global__ __launch_bounds__(256) void k_gcn_agg(
    const unsigned short* __restrict__ h0b,
    const uint2* __restrict__ pk, const int* __restrict__ row_ptr,
    const float* __restrict__ dis1, const float* __restrict__ b1,
    unsigned short* __restrict__ h1b, int N){
  int lane = threadIdx.x & 63;
  int r = blockIdx.x * 4 + (threadIdx.x >> 6);
  if (r >= N) return;
  float dr = dis1[r];
  ushort4 sv = ((const ushort4*)(h0b + (size_t)r * 256))[lane];
  float4 inner = make_float4(b2f(sv.x) * dr, b2f(sv.y) * dr, b2f(sv.z) * dr, b2f(sv.w) * dr);
  int e0 = row_ptr[r], e1 = row_ptr[r + 1];
  int e = e0;
  for (; e + 8 <= e1; e += 8){
    uint2 pv[8]; ushort4 vi[8];
#pragma unroll
    for (int q = 0; q < 8; ++q) pv[q] = pk[e + q];
#pragma unroll
    for (int q = 0; q < 8; ++q) vi[q] = ((const ushort4*)(h0b + (size_t)pv[q].x * 256))[lane];
#pragma unroll
    for (int q = 0; q < 8; ++q){
      float w = __uint_as_float(pv[q].y);
      inner.x = fmaf(w, b2f(vi[q].x), inner.x);
      inner.y = fmaf(w, b2f(vi[q].y), inner.y);
      inner.z = fmaf(w, b2f(vi[q].z), inner.z);
      inner.w = fmaf(w, b2f(vi[q].w), inner.w);
    }
  }
  for (; e < e1; ++e){
    uint2 p = pk[e];
    float w = __uint_as_float(p.y);
    ushort4 v = ((const ushort4*)(h0b + (size_t)p.x * 256))[lane];
    inner.x = fmaf(w, b2f(v.x), inner.x); inner.y = fmaf(w, b2f(v.y), inner.y);
    inner.z = fmaf(w, b2f(v.z), inner.z); inner.w = fmaf(w, b2f(v.w), inner.w);
  }
  float4 bb = ((const float4*)b1)[lane];
  ushort4 o;
  o.x = f2b(fmaxf(fmaf(inner.x, dr, bb.x), 0.f));
  o.y = f2b(fmaxf(fmaf(inner.y, dr, bb.y), 0.f));
  o.z = f2b(fmaxf(fmaf(inner.z, dr, bb.z), 0.f));
  o.w = f2b(fmaxf(fmaf(inner.w, dr, bb.w), 0.f));
  ((ushort4*)(h1b + (size_t)r * 256))[lane] = o;
}

// ---------------- Cheb spmm v2 (packed edges, 8-wide MLP) ----------------
__global__ __launch_bounds__(256) void k_cheb_spmm2(
    const unsigned short* __restrict__ Ck, int ckstride,
    const unsigned short* __restrict__ sub16, int substride,
    const float* __restrict__ subf,
    const unsigned short* __restrict__ srcb, int sstride,
    float* __restrict__ dst, unsigned short* __restrict__ dstb,
    const uint2* __restrict__ pk, const int* __restrict__ row_ptr,
    const float* __restrict__ dis2, float coef, int N){
  int lane = threadIdx.x & 63;
  int r = blockIdx.x * 4 + (threadIdx.x >> 6);
  if (r >= N) return;
  float2 inner = make_float2(0.f, 0.f);
  int e0 = row_ptr[r], e1 = row_ptr[r + 1];
  int e = e0;
  for (; e + 8 <= e1; e += 8){
    uint2 pv[8]; unsigned vi[8];
#pragma unroll
    for (int q = 0; q < 8; ++q) pv[q] = pk[e + q];
#pragma unroll
    for (int q = 0; q < 8; ++q) vi[q] = ((const unsigned*)(srcb + (size_t)pv[q].x * sstride))[lane];
#pragma unroll
    for (int q = 0; q < 8; ++q){
      float w = __uint_as_float(pv[q].y);
      inner.x = fmaf(w, __uint_as_float(vi[q] << 16), inner.x);
      inner.y = fmaf(w, __uint_as_float(vi[q] & 0xFFFF0000u), inner.y);
    }
  }
  for (; e < e1; ++e){
    uint2 p = pk[e];
    float w = __uint_as_float(p.y);
    unsigned v = ((const unsigned*)(srcb + (size_t)p.x * sstride))[lane];
    inner.x = fmaf(w, __uint_as_float(v << 16), inner.x);
    inner.y = fmaf(w, __uint_as_float(v & 0xFFFF0000u), inner.y);
  }
  float c = coef * dis2[r];
  unsigned ckv = ((const unsigned*)(Ck + (size_t)r * ckstride))[lane];
  float rx = fmaf(c, inner.x, __uint_as_float(ckv << 16));
  float ry = fmaf(c, inner.y, __uint_as_float(ckv & 0xFFFF0000u));
  if (sub16){
    unsigned sv = ((const unsigned*)(sub16 + (size_t)r * substride))[lane];
    rx -= __uint_as_float(sv << 16);
    ry -= __uint_as_float(sv & 0xFFFF0000u);
  }
  if (subf){
    float2 s2 = ((const float2*)(subf + (size_t)r * 128))[lane];
    rx -= s2.x;
    ry -= s2.y;
  }
  ((float2*)(dst + (size_t)r * 128))[lane] = make_float2(rx, ry);
  if (dstb){
    unsigned pkd = (unsigned)f2b(rx) | ((unsigned)f2b(ry) << 16);
    ((unsigned*)(dstb + (size_t)r * 128))[lane] = pkd;
  }
}

// ---------------- final spmm fused with feat epilogue (packed edges, 8-wide) ----------------
__global__ __launch_bounds__(256) void k_spmm_final(
    const unsigned short* __restrict__ Ck, int ckstride,
    const float* __restrict__ subf,
    const unsigned short* __restrict__ srcb, int sstride,
    const float* __restrict__ bc, const float* __restrict__ W_out, const float* __restrict__ W_root,
    float* __restrict__ feat, float* __restrict__ p, float* __restrict__ wr,
    const uint2* __restrict__ pk, const int* __restrict__ row_ptr,
    const float* __restrict__ dis2, float coef, int N){
  int lane = threadIdx.x & 63;
  int r = blockIdx.x * 4 + (threadIdx.x >> 6);
  if (r >= N) return;
  float2 inner = make_float2(0.f, 0.f);
  int e0 = row_ptr[r], e1 = row_ptr[r + 1];
  int e = e0;
  for (; e + 8 <= e1; e += 8){
    uint2 pv[8]; unsigned vi[8];
#pragma unroll
    for (int q = 0; q < 8; ++q) pv[q] = pk[e + q];
#pragma unroll
    for (int q = 0; q < 8; ++q) vi[q] = ((const unsigned*)(srcb + (size_t)pv[q].x * sstride))[lane];
#pragma unroll
    for (int q = 0; q < 8; ++q){
      float w = __uint_as_float(pv[q].y);
      inner.x = fmaf(w, __uint_as_float(vi[q] << 16), inner.x);
      inner.y = fmaf(w, __uint_as_float(vi[q] & 0xFFFF0000u), inner.y);
    }
  }
  for (; e < e1; ++e){
    uint2 pp = pk[e];
    float w = __uint_as_float(pp.y);
    unsigned v = ((const unsigned*)(srcb + (size_t)pp.x * sstride))[lane];
    inner.x = fmaf(w, __uint_as_float(v << 16), inner.x);
    inner.y = fmaf(w, __uint_as_float(v & 0xFFFF0000u), inner.y);
  }
  float c = coef * dis2[r];
  unsigned ckv = ((const unsigned*)(Ck + (size_t)r * ckstride))[lane];
  float rx = fmaf(c, inner.x, __uint_as_float(ckv << 16));
  float ry = fmaf(c, inner.y, __uint_as_float(ckv & 0xFFFF0000u));
  float2 s2 = ((const float2*)(subf + (size_t)r * 128))[lane];
  rx -= s2.x;
  ry -= s2.y;
  float2 bb = ((const float2*)bc)[lane];
  rx = fmaxf(rx + bb.x, 0.f);
  ry = fmaxf(ry + bb.y, 0.f);
  ((float2*)(feat + (size_t)r * 128))[lane] = make_float2(rx, ry);
  float2 wo = ((const float2*)W_out)[lane];
  float2 wrt = ((const float2*)W_root)[lane];
  float pp2 = rx * wo.x + ry * wo.y;
  float rr = rx * wrt.x + ry * wrt.y;
#pragma unroll
  for (int off = 32; off; off >>= 1){
    pp2 += __shfl_xor(pp2, off);
    rr += __shfl_xor(rr, off);
  }
  if (lane == 0){ p[r] = pp2; wr[r] = rr; }
}

// ---------------- ClusterGCN output (8-wide, packed edges) ----------------
__global__ __launch_bounds__(256) void k_out(const float* __restrict__ p, const float* __restrict__ wr,
    const float* __restrict__ invw, const uint2* __restrict__ pk, const int* __restrict__ row_ptr,
    const float* __restrict__ b3, float* __restrict__ out, int N){
  int r = blockIdx.x * 256 + threadIdx.x;
  if (r >= N) return;
  float s = p[r];
  int e0 = row_ptr[r], e1 = row_ptr[r + 1];
  int e = e0;
  float acc[8] = {0.f,0.f,0.f,0.f,0.f,0.f,0.f,0.f};
  for (; e + 8 <= e1; e += 8){
    int si[8];
#pragma unroll
    for (int q = 0; q < 8; ++q) si[q] = (int)pk[e + q].x;
#pragma unroll
    for (int q = 0; q < 8; ++q) acc[q] += p[si[q]];
  }
  for (; e < e1; ++e) acc[0] += p[(int)pk[e].x];
  s += ((acc[0]+acc[1])+(acc[2]+acc[3])) + ((acc[4]+acc[5])+(acc[6]+acc[7]));
  out[r] = invw[r] * s + wr[r] + b3[0];
}

extern "C" void kernel_launch(void* const* d_in, const int* in_sizes, int n_in,
                              void* d_out, int out_size, void* d_ws, size_t ws_size,
                              hipStream_t stream){
  const float* x      = (const float*)d_in[0];
  const void*  ei     = d_in[1];
  const float* ew     = (const float*)d_in[2];
  const float* W1     = (const float*)d_in[3];
  const float* b1     = (const float*)d_in[4];
  const float* Wc     = (const float*)d_in[5];
  const float* bc     = (const float*)d_in[6];
  const float* W_out  = (const float*)d_in[7];
  const float* W_root = (const float*)d_in[8];
  const float* b3     = (const float*)d_in[9];
  const int N = in_sizes[0] / 512;
  const int E = in_sizes[2];

  char* w = (char*)d_ws;
  auto alloc = [&](size_t bytes)->void*{ void* r = (void*)w; w += (bytes + 255) & ~(size_t)255; return r; };
  // region (102.4 MB): h1b bf16 (first half) -> later B0|B1 fp32 Clenshaw
  unsigned short* h1b = (unsigned short*)alloc((size_t)N * 256 * 2 * 2);
  float* B0 = (float*)h1b;
  float* B1 = B0 + (size_t)N * 128;
  float* B2 = (float*)alloc((size_t)N * 128 * 4);
  // C5c (compact bf16 copy of C5) aliases B2's region: dead before B2 is first written.
  unsigned short* C5c = (unsigned short*)B2;
  unsigned short* CC  = (unsigned short*)alloc((size_t)N * 768 * 2);  // all 6 C_k, bf16
  unsigned short* h0b = (unsigned short*)alloc((size_t)N * 256 * 2);  // bf16 x@W1; later Bb0|Bb1
  unsigned short* Bb0 = h0b;
  unsigned short* Bb1 = h0b + (size_t)N * 128;
  uint2* csr_sw  = (uint2*)alloc((size_t)E * 8);
  uint2* pk_gcn  = (uint2*)alloc((size_t)E * 8);
  uint2* pk_cheb = (uint2*)alloc((size_t)E * 8);
  uint2* part    = (uint2*)alloc((size_t)E * 8);
  int nblk = ceil_div(E, EPB);
  int*   block_hist  = (int*)alloc((size_t)nblk * 512 * 4);
  int*   off_hist    = (int*)alloc((size_t)nblk * 512 * 4);
  int*   bucket_total= (int*)alloc(512 * 4);
  int*   bucket_base = (int*)alloc(513 * 4);
  int*   row_ptr = (int*)  alloc((size_t)(N + 1) * 4);
  float* dis1    = (float*)alloc((size_t)N * 4);
  float* dis2    = (float*)alloc((size_t)N * 4);
  float* invw    = (float*)alloc((size_t)N * 4);
  float* pbuf    = (float*)alloc((size_t)N * 4);
  float* wrbuf   = (float*)alloc((size_t)N * 4);
  short* W1t_h   = (short*)alloc((size_t)512 * 256 * 2);
  short* W1t_l   = (short*)alloc((size_t)512 * 256 * 2);
  short* Wct_h   = (short*)alloc((size_t)768 * 256 * 2);
  int*   flag    = (int*)  alloc(256);

  hipMemsetAsync(flag, 0, 4, stream);

  k_detect<<<16, 256, 0, stream>>>((const int*)ei, E, flag);
  // CSR build v2 (counting sort by dst>>8)
  k_hist<<<nblk, 256, 0, stream>>>(ei, E, flag, block_hist);
  k_colscan<<<512, 64, 0, stream>>>(block_hist, off_hist, bucket_total, nblk);
  k_bucketbase<<<1, 512, 0, stream>>>(bucket_total, bucket_base, row_ptr, N, E);
  k_partition<<<nblk, 256, 0, stream>>>(ei, ew, E, flag, off_hist, bucket_base, part);
  int nbkt = ceil_div(N, 256);
  k_bucket_csr<<<nbkt, 256, 0, stream>>>(part, bucket_base, csr_sw, row_ptr, dis1, dis2, invw, N);
  k_norm<<<ceil_div(E, 256), 256, 0, stream>>>(csr_sw, dis1, dis2, pk_gcn, pk_cheb, E);

  // weight prep
  k_prep_w<<<ceil_div(512 * 256, 256), 256, 0, stream>>>(W1, W1t_h, W1t_l, 512, 256);
  k_prep_wc<<<ceil_div(768 * 256, 256), 256, 0, stream>>>(Wc, Wct_h);

  // ---- GCNConv: h0b = bf16(x@W1); h1b = bf16(relu(agg + b1)) ----
  int nbm = ceil_div(N, 128);
  int grid1 = 8 * 2 * ceil_div(nbm, 8);
  k_gemm_mfma<<<grid1, 256, 0, stream>>>(x, W1t_h, W1t_l, h0b, N, 256, 512, nbm);
  k_gcn_agg<<<ceil_div(N, 4), 256, 0, stream>>>(h0b, pk_gcn, row_ptr, dis1, b1, h1b, N);

  // ---- fused Cheb projection: CC[N][768] = bf16(h1 @ [Wc0|..|Wc5]), single-term, XCD swizzle ----
  int grid2 = 8 * 6 * ceil_div(nbm, 8);
  k_gemm_mfma2<<<grid2, 256, 0, stream>>>(h1b, Wct_h, CC, C5c, N, 768, 256, nbm);

  // ---- Clenshaw (width 128): b_k = C_k - b_{k+2} + 2L b_{k+1} ----
  auto spmm = [&](const unsigned short* Ck, const unsigned short* s16, int s16s, const float* sf,
                  const unsigned short* src, int ss, float* dst, unsigned short* dstb, float coef){
    k_cheb_spmm2<<<ceil_div(N, 4), 256, 0, stream>>>(Ck, 768, s16, s16s, sf, src, ss, dst, dstb,
        pk_cheb, row_ptr, dis2, coef, N);
  };
  // b4 = C4 + 2L b5   (b5 gathered from compact C5c; B0 overwrites h1b region - h1b dead)
  spmm(CC + 4*128, nullptr, 0, nullptr, C5c, 128, B0, Bb0, -2.f);
  // b3 = C3 - b5 + 2L b4
  spmm(CC + 3*128, C5c, 128, nullptr, Bb0, 128, B1, Bb1, -2.f);
  // b2 = C2 - b4 + 2L b3   (B2 write overwrites C5c region - C5c dead now)
  spmm(CC + 2*128, nullptr, 0, B0, Bb1, 128, B2, Bb0, -2.f);
  // b1 = C1 - b3 + 2L b2
  spmm(CC + 1*128, nullptr, 0, B1, Bb0, 128, B0, Bb1, -2.f);

  // ---- final: res = C0 - b2 + L b1, fused with feat/p/wr epilogue ----
  float* out  = (float*)d_out;
  float* feat = out + N;
  k_spmm_final<<<ceil_div(N, 4), 256, 0, stream>>>(CC + 0*128, 768, B2, Bb1, 128,
      bc, W_out, W_root, feat, pbuf, wrbuf, pk_cheb, row_ptr, dis2, -1.f, N);
  k_out<<<ceil_div(N, 256), 256, 0, stream>>>(pbuf, wrbuf, invw, pk_cheb, row_ptr, b3, out, N);
}

// Round 14
// 863.313 us; speedup vs baseline: 2.4455x; 1.0506x over previous
//
#include <hip/hip_runtime.h>
#include <cstdint>
#include <cstddef>

typedef __attribute__((ext_vector_type(8))) short bf16x8;
typedef __attribute__((ext_vector_type(8))) unsigned short u16x8;
typedef __attribute__((ext_vector_type(4))) float f32x4;

static inline int ceil_div(int a, int b){ return (a + b - 1) / b; }

struct HL { short h, l; };
__device__ inline HL split2(float a){
  unsigned u = __float_as_uint(a);
  unsigned hb = (u + 0x8000u) & 0xFFFF0000u;
  float r = a - __uint_as_float(hb);
  HL o;
  o.h = (short)(hb >> 16);
  o.l = (short)((__float_as_uint(r) + 0x8000u) >> 16);
  return o;
}

__device__ inline unsigned short f2b(float f){            // fp32 -> bf16 (RNE)
  unsigned u = __float_as_uint(f);
  unsigned r = u + 0x7FFFu + ((u >> 16) & 1u);
  return (unsigned short)(r >> 16);
}
__device__ inline float b2f(unsigned short s){
  return __uint_as_float((unsigned)s << 16);
}
__device__ inline float b2f_lo(unsigned v){ return __uint_as_float(v << 16); }
__device__ inline float b2f_hi(unsigned v){ return __uint_as_float(v & 0xFFFF0000u); }

#define EPB 4096   // edges per histogram/partition block

// ---------------- dtype detection (int64 vs int32 edge_index) ----------------
__global__ __launch_bounds__(256) void k_detect(const int* __restrict__ ei32, int E, int* __restrict__ flag){
  int t = blockIdx.x * 256 + threadIdx.x;
  if (t < 4096) {
    long long idx = 2LL * t + 1;
    if (idx < 2LL * E && ei32[idx] != 0) atomicOr(flag, 1);
  }
}

// ---------------- CSR build v2: counting sort by dst bucket (dst>>8) ----------------
__global__ __launch_bounds__(256) void k_hist(const void* __restrict__ ei, int E,
                                              const int* __restrict__ flag, int* __restrict__ block_hist){
  __shared__ int h[512];
  for (int i = threadIdx.x; i < 512; i += 256) h[i] = 0;
  __syncthreads();
  int base = blockIdx.x * EPB;
  bool is32 = (*flag != 0);
  for (int i = 0; i < 16; ++i){
    int e = base + i * 256 + threadIdx.x;
    if (e < E){
      int dst = is32 ? ((const int*)ei)[(size_t)E + e] : (int)((const long long*)ei)[(size_t)E + e];
      atomicAdd(&h[dst >> 8], 1);
    }
  }
  __syncthreads();
  for (int i = threadIdx.x; i < 512; i += 256) block_hist[blockIdx.x * 512 + i] = h[i];
}

__global__ __launch_bounds__(64) void k_colscan(const int* __restrict__ block_hist, int* __restrict__ off_hist,
                                                int* __restrict__ bucket_total, int nblk){
  int k = blockIdx.x;
  int lane = threadIdx.x;
  int carry = 0;
  for (int c = 0; c * 64 < nblk; ++c){
    int b = c * 64 + lane;
    int v = (b < nblk) ? block_hist[b * 512 + k] : 0;
    int inc = v;
#pragma unroll
    for (int off = 1; off < 64; off <<= 1){
      int u = __shfl_up(inc, off);
      if (lane >= off) inc += u;
    }
    if (b < nblk) off_hist[b * 512 + k] = carry + inc - v;
    carry += __shfl(inc, 63);
  }
  if (lane == 0) bucket_total[k] = carry;
}

__global__ __launch_bounds__(512) void k_bucketbase(const int* __restrict__ bucket_total,
                                                    int* __restrict__ bucket_base,
                                                    int* __restrict__ row_ptr, int N, int E){
  __shared__ int sh[512];
  int t = threadIdx.x;
  int v = bucket_total[t];
  sh[t] = v; __syncthreads();
  for (int off = 1; off < 512; off <<= 1){
    int u = (t >= off) ? sh[t - off] : 0;
    __syncthreads();
    sh[t] += u;
    __syncthreads();
  }
  bucket_base[t] = sh[t] - v;
  if (t == 511) bucket_base[512] = sh[511];
  if (t == 0) row_ptr[N] = E;
}

__global__ __launch_bounds__(256) void k_partition(const void* __restrict__ ei, const float* __restrict__ ew,
                                                   int E, const int* __restrict__ flag,
                                                   const int* __restrict__ off_hist,
                                                   const int* __restrict__ bucket_base,
                                                   uint2* __restrict__ part){
  __shared__ int cur[512];
  for (int i = threadIdx.x; i < 512; i += 256)
    cur[i] = off_hist[blockIdx.x * 512 + i] + bucket_base[i];
  __syncthreads();
  int base = blockIdx.x * EPB;
  bool is32 = (*flag != 0);
  for (int i = 0; i < 16; ++i){
    int e = base + i * 256 + threadIdx.x;
    if (e < E){
      int src, dst;
      if (is32){ src = ((const int*)ei)[e]; dst = ((const int*)ei)[(size_t)E + e]; }
      else     { src = (int)((const long long*)ei)[e]; dst = (int)((const long long*)ei)[(size_t)E + e]; }
      int pos = atomicAdd(&cur[dst >> 8], 1);
      part[pos] = make_uint2((unsigned)src | ((unsigned)(dst & 255) << 20), __float_as_uint(ew[e]));
    }
  }
}

__global__ __launch_bounds__(256) void k_bucket_csr(const uint2* __restrict__ part,
                                                    const int* __restrict__ bucket_base,
                                                    uint2* __restrict__ csr_sw, int* __restrict__ row_ptr,
                                                    float* __restrict__ dis1, float* __restrict__ dis2,
                                                    float* __restrict__ invw, int N){
  __shared__ int cnt[256];
  __shared__ float wsum[256];
  __shared__ int cursor[256];
  __shared__ int ws[4];
  int k = blockIdx.x;
  int t = threadIdx.x;
  int base = bucket_base[k], end = bucket_base[k + 1];
  cnt[t] = 0; wsum[t] = 0.f;
  __syncthreads();
  for (int i = base + t; i < end; i += 256){
    uint2 rec = part[i];
    int dstl = (rec.x >> 20) & 255;
    atomicAdd(&cnt[dstl], 1);
    atomicAdd(&wsum[dstl], __uint_as_float(rec.y));
  }
  __syncthreads();
  int v = cnt[t];
  int lane = t & 63;
  int inc = v;
#pragma unroll
  for (int off = 1; off < 64; off <<= 1){
    int u = __shfl_up(inc, off);
    if (lane >= off) inc += u;
  }
  if (lane == 63) ws[t >> 6] = inc;
  __syncthreads();
  int woff = 0;
  for (int i = 0; i < (t >> 6); ++i) woff += ws[i];
  int exc = woff + inc - v;
  int node = k * 256 + t;
  if (node < N){
    row_ptr[node] = base + exc;
    float s = wsum[t];
    dis1[node] = rsqrtf(s + 1.0f);
    dis2[node] = (s > 0.f) ? rsqrtf(s) : 0.f;
    invw[node] = 1.0f / (float)(v + 1);
  }
  cursor[t] = exc;
  __syncthreads();
  for (int i = base + t; i < end; i += 256){
    uint2 rec = part[i];
    int dstl = (rec.x >> 20) & 255;
    int pos = base + atomicAdd(&cursor[dstl], 1);
    csr_sw[pos] = make_uint2(rec.x & 0xFFFFFu, rec.y);
  }
}

// ---------------- edge norms: packed (src, w) streams for gcn and cheb ----------------
__global__ __launch_bounds__(256) void k_norm(const uint2* __restrict__ csr_sw,
                                              const float* __restrict__ dis1, const float* __restrict__ dis2,
                                              uint2* __restrict__ pk_gcn, uint2* __restrict__ pk_cheb, int E){
  int e = blockIdx.x * 256 + threadIdx.x;
  if (e >= E) return;
  uint2 p = csr_sw[e];
  int s = (int)p.x;
  float w = __uint_as_float(p.y);
  pk_gcn[e]  = make_uint2(p.x, __float_as_uint(w * dis1[s]));
  pk_cheb[e] = make_uint2(p.x, __float_as_uint(w * dis2[s]));
}

// ---------------- weight prep ----------------
__global__ __launch_bounds__(256) void k_prep_w(const float* __restrict__ W, short* __restrict__ Wh,
                                                short* __restrict__ Wl, int K, int N){
  int idx = blockIdx.x * 256 + threadIdx.x;
  if (idx >= K * N) return;
  int n = idx / K, k = idx - n * K;
  HL s = split2(W[(size_t)k * N + n]);
  Wh[idx] = s.h; Wl[idx] = s.l;
}

__global__ __launch_bounds__(256) void k_prep_wc(const float* __restrict__ Wc, short* __restrict__ Wh){
  int idx = blockIdx.x * 256 + threadIdx.x;
  if (idx >= 768 * 256) return;
  int n = idx >> 8, k = idx & 255;
  Wh[idx] = (short)f2b(Wc[(size_t)(n >> 7) * 256 * 128 + (size_t)k * 128 + (n & 127)]);
}

// ---------------- MFMA GEMM 1: A = bf16(x), B = W1 split; 2-term; A reg-prefetch; XCD swizzle ----
__global__ __launch_bounds__(256) void k_gemm_mfma(
    const float* __restrict__ A,
    const short* __restrict__ Bh, const short* __restrict__ Bl,
    unsigned short* __restrict__ Cb,
    int M, int Ncols, int K, int nbm)
{
  __shared__ short Ah[128][40];
  __shared__ short Bhs[128][40];
  __shared__ short Bls[128][40];
  int bid = blockIdx.x;
  int g = bid & 7, j = bid >> 3;
  int m_tile = g + 8 * (j >> 1);
  int n_tile = j & 1;
  if (m_tile >= nbm) return;
  int m0 = m_tile * 128, n0 = n_tile * 128;
  int t = threadIdx.x;
  int lane = t & 63, wid = t >> 6;
  int wr = wid >> 1, wc = wid & 1;
  int fr = lane & 15, fq = lane >> 4;
  int srow = t >> 1, skh = (t & 1) << 4;

  f32x4 acc[4][4];
#pragma unroll
  for (int i = 0; i < 4; ++i)
#pragma unroll
    for (int jj = 0; jj < 4; ++jj) acc[i][jj] = (f32x4){0.f, 0.f, 0.f, 0.f};

  bool aval = (m0 + srow) < M;
  const float* Aptr = A + (size_t)(m0 + srow) * K + skh;
  const short* Bhp = Bh + (size_t)(n0 + srow) * K + skh;
  const short* Blp = Bl + (size_t)(n0 + srow) * K + skh;

  float4 a0, a1, a2, a3;
  if (aval){
    const float4* ap = (const float4*)Aptr;
    a0 = ap[0]; a1 = ap[1]; a2 = ap[2]; a3 = ap[3];
  } else a0 = a1 = a2 = a3 = make_float4(0.f, 0.f, 0.f, 0.f);

  for (int k0 = 0; k0 < K; k0 += 32){
    bf16x8 h0, h1;
    h0[0]=(short)f2b(a0.x); h0[1]=(short)f2b(a0.y); h0[2]=(short)f2b(a0.z); h0[3]=(short)f2b(a0.w);
    h0[4]=(short)f2b(a1.x); h0[5]=(short)f2b(a1.y); h0[6]=(short)f2b(a1.z); h0[7]=(short)f2b(a1.w);
    h1[0]=(short)f2b(a2.x); h1[1]=(short)f2b(a2.y); h1[2]=(short)f2b(a2.z); h1[3]=(short)f2b(a2.w);
    h1[4]=(short)f2b(a3.x); h1[5]=(short)f2b(a3.y); h1[6]=(short)f2b(a3.z); h1[7]=(short)f2b(a3.w);
    *(bf16x8*)&Ah[srow][skh]     = h0;
    *(bf16x8*)&Ah[srow][skh + 8] = h1;
    {
      const bf16x8* bp = (const bf16x8*)(Bhp + k0);
      *(bf16x8*)&Bhs[srow][skh]     = bp[0];
      *(bf16x8*)&Bhs[srow][skh + 8] = bp[1];
      const bf16x8* cp = (const bf16x8*)(Blp + k0);
      *(bf16x8*)&Bls[srow][skh]     = cp[0];
      *(bf16x8*)&Bls[srow][skh + 8] = cp[1];
    }
    __syncthreads();
    bool more = (k0 + 32) < K;
    float4 n0v, n1v, n2v, n3v;
    if (more && aval){
      const float4* ap = (const float4*)(Aptr + k0 + 32);
      n0v = ap[0]; n1v = ap[1]; n2v = ap[2]; n3v = ap[3];
    } else n0v = n1v = n2v = n3v = make_float4(0.f, 0.f, 0.f, 0.f);
    bf16x8 afh[4], bfh[4], bfl[4];
#pragma unroll
    for (int m = 0; m < 4; ++m){
      int r = wr * 64 + m * 16 + fr;
      afh[m] = *(const bf16x8*)&Ah[r][fq * 8];
    }
#pragma unroll
    for (int n = 0; n < 4; ++n){
      int r = wc * 64 + n * 16 + fr;
      bfh[n] = *(const bf16x8*)&Bhs[r][fq * 8];
      bfl[n] = *(const bf16x8*)&Bls[r][fq * 8];
    }
#pragma unroll
    for (int m = 0; m < 4; ++m)
#pragma unroll
      for (int n = 0; n < 4; ++n){
        acc[m][n] = __builtin_amdgcn_mfma_f32_16x16x32_bf16(afh[m], bfh[n], acc[m][n], 0, 0, 0);
        acc[m][n] = __builtin_amdgcn_mfma_f32_16x16x32_bf16(afh[m], bfl[n], acc[m][n], 0, 0, 0);
      }
    __syncthreads();
    a0 = n0v; a1 = n1v; a2 = n2v; a3 = n3v;
  }
#pragma unroll
  for (int m = 0; m < 4; ++m){
#pragma unroll
    for (int n = 0; n < 4; ++n){
      int col = n0 + wc * 64 + n * 16 + fr;
#pragma unroll
      for (int r = 0; r < 4; ++r){
        int row = m0 + wr * 64 + m * 16 + fq * 4 + r;
        if (row < M){
          Cb[(size_t)row * Ncols + col] = f2b(acc[m][n][r]);
        }
      }
    }
  }
}

// ---------------- MFMA GEMM 2: A = bf16(h1), B = bf16(Wc); single term; reg-prefetch; XCD swizzle ----
__global__ __launch_bounds__(256) void k_gemm_mfma2(
    const unsigned short* __restrict__ Ahg,
    const short* __restrict__ Bh,
    unsigned short* __restrict__ Cb, unsigned short* __restrict__ C5c,
    int M, int Ncols, int K, int nbm)
{
  __shared__ short Ah[128][40];
  __shared__ short Bhs[128][40];
  int bid = blockIdx.x;
  int g = bid & 7, j = bid >> 3;
  int m_tile = g + 8 * (j / 6);
  int n_tile = j - 6 * (j / 6);
  if (m_tile >= nbm) return;
  int m0 = m_tile * 128, n0 = n_tile * 128;
  int t = threadIdx.x;
  int lane = t & 63, wid = t >> 6;
  int wr = wid >> 1, wc = wid & 1;
  int fr = lane & 15, fq = lane >> 4;
  int srow = t >> 1, skh = (t & 1) << 4;

  f32x4 acc[4][4];
#pragma unroll
  for (int i = 0; i < 4; ++i)
#pragma unroll
    for (int jj = 0; jj < 4; ++jj) acc[i][jj] = (f32x4){0.f, 0.f, 0.f, 0.f};

  bool aval = (m0 + srow) < M;
  const unsigned short* Ahp = Ahg + (size_t)(m0 + srow) * K + skh;
  const short* Bhp = Bh + (size_t)(n0 + srow) * K + skh;

  bf16x8 ch0, ch1;
  if (aval){
    const bf16x8* ah = (const bf16x8*)Ahp;
    ch0 = ah[0]; ch1 = ah[1];
  } else {
    bf16x8 z = (bf16x8){0,0,0,0,0,0,0,0};
    ch0 = ch1 = z;
  }

  for (int k0 = 0; k0 < K; k0 += 32){
    *(bf16x8*)&Ah[srow][skh]     = ch0;
    *(bf16x8*)&Ah[srow][skh + 8] = ch1;
    {
      const bf16x8* bp = (const bf16x8*)(Bhp + k0);
      *(bf16x8*)&Bhs[srow][skh]     = bp[0];
      *(bf16x8*)&Bhs[srow][skh + 8] = bp[1];
    }
    __syncthreads();
    bool more = (k0 + 32) < K;
    bf16x8 nh0, nh1;
    if (more && aval){
      const bf16x8* ah = (const bf16x8*)(Ahp + k0 + 32);
      nh0 = ah[0]; nh1 = ah[1];
    } else {
      bf16x8 z = (bf16x8){0,0,0,0,0,0,0,0};
      nh0 = nh1 = z;
    }
    bf16x8 afh[4], bfh[4];
#pragma unroll
    for (int m = 0; m < 4; ++m){
      int r = wr * 64 + m * 16 + fr;
      afh[m] = *(const bf16x8*)&Ah[r][fq * 8];
    }
#pragma unroll
    for (int n = 0; n < 4; ++n){
      int r = wc * 64 + n * 16 + fr;
      bfh[n] = *(const bf16x8*)&Bhs[r][fq * 8];
    }
#pragma unroll
    for (int m = 0; m < 4; ++m)
#pragma unroll
      for (int n = 0; n < 4; ++n){
        acc[m][n] = __builtin_amdgcn_mfma_f32_16x16x32_bf16(afh[m], bfh[n], acc[m][n], 0, 0, 0);
      }
    __syncthreads();
    ch0 = nh0; ch1 = nh1;
  }
#pragma unroll
  for (int m = 0; m < 4; ++m){
#pragma unroll
    for (int n = 0; n < 4; ++n){
      int col = n0 + wc * 64 + n * 16 + fr;
#pragma unroll
      for (int r = 0; r < 4; ++r){
        int row = m0 + wr * 64 + m * 16 + fq * 4 + r;
        if (row < M){
          unsigned short v = f2b(acc[m][n][r]);
          Cb[(size_t)row * Ncols + col] = v;
          if (n_tile == 5) C5c[(size_t)row * 128 + (col - 640)] = v;
        }
      }
    }
  }
}

// ---------------- GCN aggregation: half-wave edges, 16B/lane gathers ----------------
__global__ __launch_bounds__(256) void k_gcn_agg(
    const unsigned short* __restrict__ h0b,
    const uint2* __restrict__ pk, const int* __restrict__ row_ptr,
    const float* __restrict__ dis1, const float* __restrict__ b1,
    unsigned short* __restrict__ h1b, int N){
  int lane = threadIdx.x & 63;
  int r = blockIdx.x * 4 + (threadIdx.x >> 6);
  if (r >= N) return;
  int half = lane >> 5;
  int sub  = lane & 31;              // cols sub*8 .. sub*8+7
  float dr = dis1[r];
  u16x8 sv = ((const u16x8*)(h0b + (size_t)r * 256))[sub];
  float hsc = (half == 0) ? dr : 0.f;
  float acc[8];
#pragma unroll
  for (int j = 0; j < 8; ++j) acc[j] = hsc * b2f(sv[j]);
  int e0 = row_ptr[r], e1 = row_ptr[r + 1];
  int e = e0;
  for (; e + 8 <= e1; e += 8){
    uint2 pv[4]; u16x8 vi[4];
#pragma unroll
    for (int q = 0; q < 4; ++q) pv[q] = pk[e + 2 * q + half];
#pragma unroll
    for (int q = 0; q < 4; ++q) vi[q] = ((const u16x8*)(h0b + (size_t)pv[q].x * 256))[sub];
#pragma unroll
    for (int q = 0; q < 4; ++q){
      float w = __uint_as_float(pv[q].y);
#pragma unroll
      for (int j = 0; j < 8; ++j) acc[j] = fmaf(w, b2f(vi[q][j]), acc[j]);
    }
  }
  for (; e < e1; e += 2){
    int ee = e + half;
    if (ee < e1){
      uint2 p = pk[ee];
      float w = __uint_as_float(p.y);
      u16x8 v = ((const u16x8*)(h0b + (size_t)p.x * 256))[sub];
#pragma unroll
      for (int j = 0; j < 8; ++j) acc[j] = fmaf(w, b2f(v[j]), acc[j]);
    }
  }
#pragma unroll
  for (int j = 0; j < 8; ++j) acc[j] += __shfl_xor(acc[j], 32);
  const float4* bp = (const float4*)b1;
  float4 bb0 = bp[sub * 2], bb1 = bp[sub * 2 + 1];
  float bv[8] = {bb0.x, bb0.y, bb0.z, bb0.w, bb1.x, bb1.y, bb1.z, bb1.w};
  u16x8 o;
#pragma unroll
  for (int j = 0; j < 8; ++j) o[j] = f2b(fmaxf(fmaf(acc[j], dr, bv[j]), 0.f));
  if (half == 0) ((u16x8*)(h1b + (size_t)r * 256))[sub] = o;
}

// ---------------- Cheb spmm v3: half-wave edges, 8B/lane gathers ----------------
__global__ __launch_bounds__(256) void k_cheb_spmm2(
    const unsigned short* __restrict__ Ck, int ckstride,
    const unsigned short* __restrict__ sub16, int substride,
    const float* __restrict__ subf,
    const unsigned short* __restrict__ srcb, int sstride,
    float* __restrict__ dst, unsigned short* __restrict__ dstb,
    const uint2* __restrict__ pk, const int* __restrict__ row_ptr,
    const float* __restrict__ dis2, float coef, int N){
  int lane = threadIdx.x & 63;
  int r = blockIdx.x * 4 + (threadIdx.x >> 6);
  if (r >= N) return;
  int half = lane >> 5;
  int sub  = lane & 31;              // cols sub*4 .. sub*4+3
  float a0 = 0.f, a1 = 0.f, a2 = 0.f, a3 = 0.f;
  int e0 = row_ptr[r], e1 = row_ptr[r + 1];
  int e = e0;
  for (; e + 8 <= e1; e += 8){
    uint2 pv[4]; uint2 vi[4];
#pragma unroll
    for (int q = 0; q < 4; ++q) pv[q] = pk[e + 2 * q + half];
#pragma unroll
    for (int q = 0; q < 4; ++q) vi[q] = ((const uint2*)(srcb + (size_t)pv[q].x * sstride))[sub];
#pragma unroll
    for (int q = 0; q < 4; ++q){
      float w = __uint_as_float(pv[q].y);
      a0 = fmaf(w, b2f_lo(vi[q].x), a0);
      a1 = fmaf(w, b2f_hi(vi[q].x), a1);
      a2 = fmaf(w, b2f_lo(vi[q].y), a2);
      a3 = fmaf(w, b2f_hi(vi[q].y), a3);
    }
  }
  for (; e < e1; e += 2){
    int ee = e + half;
    if (ee < e1){
      uint2 p = pk[ee];
      float w = __uint_as_float(p.y);
      uint2 v = ((const uint2*)(srcb + (size_t)p.x * sstride))[sub];
      a0 = fmaf(w, b2f_lo(v.x), a0);
      a1 = fmaf(w, b2f_hi(v.x), a1);
      a2 = fmaf(w, b2f_lo(v.y), a2);
      a3 = fmaf(w, b2f_hi(v.y), a3);
    }
  }
  a0 += __shfl_xor(a0, 32); a1 += __shfl_xor(a1, 32);
  a2 += __shfl_xor(a2, 32); a3 += __shfl_xor(a3, 32);
  float c = coef * dis2[r];
  uint2 ckv = ((const uint2*)(Ck + (size_t)r * ckstride))[sub];
  float r0 = fmaf(c, a0, b2f_lo(ckv.x));
  float r1 = fmaf(c, a1, b2f_hi(ckv.x));
  float r2 = fmaf(c, a2, b2f_lo(ckv.y));
  float r3 = fmaf(c, a3, b2f_hi(ckv.y));
  if (sub16){
    uint2 sv = ((const uint2*)(sub16 + (size_t)r * substride))[sub];
    r0 -= b2f_lo(sv.x); r1 -= b2f_hi(sv.x);
    r2 -= b2f_lo(sv.y); r3 -= b2f_hi(sv.y);
  }
  if (subf){
    float4 s4 = ((const float4*)(subf + (size_t)r * 128))[sub];
    r0 -= s4.x; r1 -= s4.y; r2 -= s4.z; r3 -= s4.w;
  }
  if (half == 0){
    ((float4*)(dst + (size_t)r * 128))[sub] = make_float4(r0, r1, r2, r3);
    if (dstb){
      uint2 pkd;
      pkd.x = (unsigned)f2b(r0) | ((unsigned)f2b(r1) << 16);
      pkd.y = (unsigned)f2b(r2) | ((unsigned)f2b(r3) << 16);
      ((uint2*)(dstb + (size_t)r * 128))[sub] = pkd;
    }
  }
}

// ---------------- final spmm fused with feat epilogue (half-wave) ----------------
__global__ __launch_bounds__(256) void k_spmm_final(
    const unsigned short* __restrict__ Ck, int ckstride,
    const float* __restrict__ subf,
    const unsigned short* __restrict__ srcb, int sstride,
    const float* __restrict__ bc, const float* __restrict__ W_out, const float* __restrict__ W_root,
    float* __restrict__ feat, float* __restrict__ p, float* __restrict__ wr,
    const uint2* __restrict__ pk, const int* __restrict__ row_ptr,
    const float* __restrict__ dis2, float coef, int N){
  int lane = threadIdx.x & 63;
  int r = blockIdx.x * 4 + (threadIdx.x >> 6);
  if (r >= N) return;
  int half = lane >> 5;
  int sub  = lane & 31;
  float a0 = 0.f, a1 = 0.f, a2 = 0.f, a3 = 0.f;
  int e0 = row_ptr[r], e1 = row_ptr[r + 1];
  int e = e0;
  for (; e + 8 <= e1; e += 8){
    uint2 pv[4]; uint2 vi[4];
#pragma unroll
    for (int q = 0; q < 4; ++q) pv[q] = pk[e + 2 * q + half];
#pragma unroll
    for (int q = 0; q < 4; ++q) vi[q] = ((const uint2*)(srcb + (size_t)pv[q].x * sstride))[sub];
#pragma unroll
    for (int q = 0; q < 4; ++q){
      float w = __uint_as_float(pv[q].y);
      a0 = fmaf(w, b2f_lo(vi[q].x), a0);
      a1 = fmaf(w, b2f_hi(vi[q].x), a1);
      a2 = fmaf(w, b2f_lo(vi[q].y), a2);
      a3 = fmaf(w, b2f_hi(vi[q].y), a3);
    }
  }
  for (; e < e1; e += 2){
    int ee = e + half;
    if (ee < e1){
      uint2 pp = pk[ee];
      float w = __uint_as_float(pp.y);
      uint2 v = ((const uint2*)(srcb + (size_t)pp.x * sstride))[sub];
      a0 = fmaf(w, b2f_lo(v.x), a0);
      a1 = fmaf(w, b2f_hi(v.x), a1);
      a2 = fmaf(w, b2f_lo(v.y), a2);
      a3 = fmaf(w, b2f_hi(v.y), a3);
    }
  }
  a0 += __shfl_xor(a0, 32); a1 += __shfl_xor(a1, 32);
  a2 += __shfl_xor(a2, 32); a3 += __shfl_xor(a3, 32);
  float c = coef * dis2[r];
  uint2 ckv = ((const uint2*)(Ck + (size_t)r * ckstride))[sub];
  float r0 = fmaf(c, a0, b2f_lo(ckv.x));
  float r1 = fmaf(c, a1, b2f_hi(ckv.x));
  float r2 = fmaf(c, a2, b2f_lo(ckv.y));
  float r3 = fmaf(c, a3, b2f_hi(ckv.y));
  float4 s4 = ((const float4*)(subf + (size_t)r * 128))[sub];
  r0 -= s4.x; r1 -= s4.y; r2 -= s4.z; r3 -= s4.w;
  float4 bb = ((const float4*)bc)[sub];
  r0 = fmaxf(r0 + bb.x, 0.f);
  r1 = fmaxf(r1 + bb.y, 0.f);
  r2 = fmaxf(r2 + bb.z, 0.f);
  r3 = fmaxf(r3 + bb.w, 0.f);
  if (half == 0)
    ((float4*)(feat + (size_t)r * 128))[sub] = make_float4(r0, r1, r2, r3);
  float4 wo = ((const float4*)W_out)[sub];
  float4 wrt = ((const float4*)W_root)[sub];
  float pp2 = r0 * wo.x + r1 * wo.y + r2 * wo.z + r3 * wo.w;
  float rr  = r0 * wrt.x + r1 * wrt.y + r2 * wrt.z + r3 * wrt.w;
  // both halves hold identical values; reduce within 32-lane half, write from lane 0
#pragma unroll
  for (int off = 1; off < 32; off <<= 1){
    pp2 += __shfl_xor(pp2, off);
    rr  += __shfl_xor(rr, off);
  }
  if (lane == 0){ p[r] = pp2; wr[r] = rr; }
}

// ---------------- ClusterGCN output (8-wide, packed edges) ----------------
__global__ __launch_bounds__(256) void k_out(const float* __restrict__ p, const float* __restrict__ wr,
    const float* __restrict__ invw, const uint2* __restrict__ pk, const int* __restrict__ row_ptr,
    const float* __restrict__ b3, float* __restrict__ out, int N){
  int r = blockIdx.x * 256 + threadIdx.x;
  if (r >= N) return;
  float s = p[r];
  int e0 = row_ptr[r], e1 = row_ptr[r + 1];
  int e = e0;
  float acc[8] = {0.f,0.f,0.f,0.f,0.f,0.f,0.f,0.f};
  for (; e + 8 <= e1; e += 8){
    int si[8];
#pragma unroll
    for (int q = 0; q < 8; ++q) si[q] = (int)pk[e + q].x;
#pragma unroll
    for (int q = 0; q < 8; ++q) acc[q] += p[si[q]];
  }
  for (; e < e1; ++e) acc[0] += p[(int)pk[e].x];
  s += ((acc[0]+acc[1])+(acc[2]+acc[3])) + ((acc[4]+acc[5])+(acc[6]+acc[7]));
  out[r] = invw[r] * s + wr[r] + b3[0];
}

extern "C" void kernel_launch(void* const* d_in, const int* in_sizes, int n_in,
                              void* d_out, int out_size, void* d_ws, size_t ws_size,
                              hipStream_t stream){
  const float* x      = (const float*)d_in[0];
  const void*  ei     = d_in[1];
  const float* ew     = (const float*)d_in[2];
  const float* W1     = (const float*)d_in[3];
  const float* b1     = (const float*)d_in[4];
  const float* Wc     = (const float*)d_in[5];
  const float* bc     = (const float*)d_in[6];
  const float* W_out  = (const float*)d_in[7];
  const float* W_root = (const float*)d_in[8];
  const float* b3     = (const float*)d_in[9];
  const int N = in_sizes[0] / 512;
  const int E = in_sizes[2];

  char* w = (char*)d_ws;
  auto alloc = [&](size_t bytes)->void*{ void* r = (void*)w; w += (bytes + 255) & ~(size_t)255; return r; };
  unsigned short* h1b = (unsigned short*)alloc((size_t)N * 256 * 2 * 2);
  float* B0 = (float*)h1b;
  float* B1 = B0 + (size_t)N * 128;
  float* B2 = (float*)alloc((size_t)N * 128 * 4);
  unsigned short* C5c = (unsigned short*)B2;
  unsigned short* CC  = (unsigned short*)alloc((size_t)N * 768 * 2);
  unsigned short* h0b = (unsigned short*)alloc((size_t)N * 256 * 2);
  unsigned short* Bb0 = h0b;
  unsigned short* Bb1 = h0b + (size_t)N * 128;
  uint2* csr_sw  = (uint2*)alloc((size_t)E * 8);
  uint2* pk_gcn  = (uint2*)alloc((size_t)E * 8);
  uint2* pk_cheb = (uint2*)alloc((size_t)E * 8);
  uint2* part    = (uint2*)alloc((size_t)E * 8);
  int nblk = ceil_div(E, EPB);
  int*   block_hist  = (int*)alloc((size_t)nblk * 512 * 4);
  int*   off_hist    = (int*)alloc((size_t)nblk * 512 * 4);
  int*   bucket_total= (int*)alloc(512 * 4);
  int*   bucket_base = (int*)alloc(513 * 4);
  int*   row_ptr = (int*)  alloc((size_t)(N + 1) * 4);
  float* dis1    = (float*)alloc((size_t)N * 4);
  float* dis2    = (float*)alloc((size_t)N * 4);
  float* invw    = (float*)alloc((size_t)N * 4);
  float* pbuf    = (float*)alloc((size_t)N * 4);
  float* wrbuf   = (float*)alloc((size_t)N * 4);
  short* W1t_h   = (short*)alloc((size_t)512 * 256 * 2);
  short* W1t_l   = (short*)alloc((size_t)512 * 256 * 2);
  short* Wct_h   = (short*)alloc((size_t)768 * 256 * 2);
  int*   flag    = (int*)  alloc(256);

  hipMemsetAsync(flag, 0, 4, stream);

  k_detect<<<16, 256, 0, stream>>>((const int*)ei, E, flag);
  k_hist<<<nblk, 256, 0, stream>>>(ei, E, flag, block_hist);
  k_colscan<<<512, 64, 0, stream>>>(block_hist, off_hist, bucket_total, nblk);
  k_bucketbase<<<1, 512, 0, stream>>>(bucket_total, bucket_base, row_ptr, N, E);
  k_partition<<<nblk, 256, 0, stream>>>(ei, ew, E, flag, off_hist, bucket_base, part);
  int nbkt = ceil_div(N, 256);
  k_bucket_csr<<<nbkt, 256, 0, stream>>>(part, bucket_base, csr_sw, row_ptr, dis1, dis2, invw, N);
  k_norm<<<ceil_div(E, 256), 256, 0, stream>>>(csr_sw, dis1, dis2, pk_gcn, pk_cheb, E);

  k_prep_w<<<ceil_div(512 * 256, 256), 256, 0, stream>>>(W1, W1t_h, W1t_l, 512, 256);
  k_prep_wc<<<ceil_div(768 * 256, 256), 256, 0, stream>>>(Wc, Wct_h);

  // ---- GCNConv ----
  int nbm = ceil_div(N, 128);
  int grid1 = 8 * 2 * ceil_div(nbm, 8);
  k_gemm_mfma<<<grid1, 256, 0, stream>>>(x, W1t_h, W1t_l, h0b, N, 256, 512, nbm);
  k_gcn_agg<<<ceil_div(N, 4), 256, 0, stream>>>(h0b, pk_gcn, row_ptr, dis1, b1, h1b, N);

  // ---- fused Cheb projection ----
  int grid2 = 8 * 6 * ceil_div(nbm, 8);
  k_gemm_mfma2<<<grid2, 256, 0, stream>>>(h1b, Wct_h, CC, C5c, N, 768, 256, nbm);

  // ---- Clenshaw ----
  auto spmm = [&](const unsigned short* Ck, const unsigned short* s16, int s16s, const float* sf,
                  const unsigned short* src, int ss, float* dst, unsigned short* dstb, float coef){
    k_cheb_spmm2<<<ceil_div(N, 4), 256, 0, stream>>>(Ck, 768, s16, s16s, sf, src, ss, dst, dstb,
        pk_cheb, row_ptr, dis2, coef, N);
  };
  spmm(CC + 4*128, nullptr, 0, nullptr, C5c, 128, B0, Bb0, -2.f);
  spmm(CC + 3*128, C5c, 128, nullptr, Bb0, 128, B1, Bb1, -2.f);
  spmm(CC + 2*128, nullptr, 0, B0, Bb1, 128, B2, Bb0, -2.f);
  spmm(CC + 1*128, nullptr, 0, B1, Bb0, 128, B0, Bb1, -2.f);

  // ---- final ----
  float* out  = (float*)d_out;
  float* feat = out + N;
  k_spmm_final<<<ceil_div(N, 4), 256, 0, stream>>>(CC + 0*128, 768, B2, Bb1, 128,
      bc, W_out, W_root, feat, pbuf, wrbuf, pk_cheb, row_ptr, dis2, -1.f, N);
  k_out<<<ceil_div(N, 256), 256, 0, stream>>>(pbuf, wrbuf, invw, pk_cheb, row_ptr, b3, out, N);
}